// Round 9
// baseline (504.501 us; speedup 1.0000x reference)
//
#include <hip/hip_runtime.h>
#include <math.h>

#define DEV __device__ __forceinline__
using u16 = unsigned short;
typedef __bf16 bh8 __attribute__((ext_vector_type(8)));
typedef float f32x4 __attribute__((ext_vector_type(4)));
typedef u16 u16x8 __attribute__((ext_vector_type(8)));
typedef u16 u16x4 __attribute__((ext_vector_type(4)));

DEV float b2f(u16 x){ unsigned u = ((unsigned)x) << 16; float f; __builtin_memcpy(&f, &u, 4); return f; }
DEV u16 f2b(float f){ unsigned u; __builtin_memcpy(&u, &f, 4); return (u16)((u + 0x7fffu + ((u >> 16) & 1u)) >> 16); }
DEV float sigm(float x){ return 1.f / (1.f + __expf(-x)); }
DEV float ldf(const void* p, size_t i, bool f32){ return f32 ? ((const float*)p)[i] : b2f(((const u16*)p)[i]); }

typedef __attribute__((address_space(1))) const void* gptr_t;
typedef __attribute__((address_space(3))) void* lptr_t;
DEV void gload16(const void* g, void* l){
  __builtin_amdgcn_global_load_lds((gptr_t)g, (lptr_t)l, 16, 0, 0);
}

// ---------------- dtype detect ----------------
__global__ __launch_bounds__(256) void detect_kernel(const void* x, unsigned* flag)
{
  const int tid = threadIdx.x;
  const u16* p = (const u16*)x;
  int sane = 0;
  #pragma unroll
  for (int j = 0; j < 8; j++){
    u16 v = p[(size_t)(tid * 8 + j) * 2];
    int e = (v >> 7) & 0xFF;
    sane += (e >= 0x60 && e <= 0x8F) ? 1 : 0;
  }
  __shared__ int red[256];
  red[tid] = sane; __syncthreads();
  for (int s = 128; s > 0; s >>= 1){ if (tid < s) red[tid] += red[tid + s]; __syncthreads(); }
  if (tid == 0) flag[0] = (red[0] < 1200) ? 1u : 0u;
}

// ---------------- batch convert external -> bf16 ws ----------------
#define NCVT 17
struct CvtJobs {
  const void* src[NCVT];
  u16* dst[NCVT];
  int n[NCVT];
  int blk_off[NCVT + 1];
};
__global__ __launch_bounds__(256) void convert_kernel(CvtJobs jobs, const unsigned* __restrict__ Fg)
{
  const bool f32 = Fg[0] != 0;
  const int bx = blockIdx.x;
  int j = 0;
  while (bx >= jobs.blk_off[j + 1]) j++;
  const int e = (bx - jobs.blk_off[j]) * 2048 + threadIdx.x * 8;
  if (e >= jobs.n[j]) return;
  if (f32){
    const float* s = (const float*)jobs.src[j] + e;
    u16x8 o;
    #pragma unroll
    for (int i = 0; i < 8; i++) o[i] = f2b(s[i]);
    *(u16x8*)(jobs.dst[j] + e) = o;
  } else {
    *(u16x8*)(jobs.dst[j] + e) = *(const u16x8*)((const u16*)jobs.src[j] + e);
  }
}

// ======== m97-structure GEMM: BK=32, linear LDS, global_load_lds(16B) staging ========
// C[M,N] = A[M,K] @ W[N,K]^T. 256 thr, 4 waves 2x2. BM=2*FM*16, BN=2*FN*16.
// EPI: 0 bf16   1 bf16+bias   2 f32+bias   3 f32
//      4 bf16=gelu(acc*rs*ws+bias)   5 f32=acc*rs*ws+bias
template<int EPI, int FM, int FN>
__global__ __launch_bounds__(256) void gemm_lds(
    const u16* __restrict__ A, const u16* __restrict__ W, void* __restrict__ Cv,
    int M, int N, int K, int lda, int ldb, int ldc,
    const u16* __restrict__ bias, const float* __restrict__ rowscale,
    const float* __restrict__ wscale)
{
  constexpr int BM = 2 * FM * 16, BN = 2 * FN * 16;
  __shared__ __align__(16) u16 As[BM][32];
  __shared__ __align__(16) u16 Bs[BN][32];
  const int tid = threadIdx.x, wave = tid >> 6, lane = tid & 63;
  const int wr = wave >> 1, wc = wave & 1, fr = lane & 15, ko = (lane >> 4) << 3;
  const size_t bm = (size_t)blockIdx.y * BM, bn = (size_t)blockIdx.x * BN;
  f32x4 acc[FM][FN] = {};
  for (int k0 = 0; k0 < K; k0 += 32){
    __syncthreads();
    // stage A,B -> LDS (linear; dest = wave-uniform base + lane*16)
    #pragma unroll
    for (int c = 0; c < BM / 64; c++){
      int li = c * 256 + tid;
      gload16(&A[(bm + (li >> 2)) * (size_t)lda + k0 + ((li & 3) << 3)],
              (char*)&As[0][0] + c * 4096 + wave * 1024);
    }
    #pragma unroll
    for (int c = 0; c < BN / 64; c++){
      int li = c * 256 + tid;
      gload16(&W[(bn + (li >> 2)) * (size_t)ldb + k0 + ((li & 3) << 3)],
              (char*)&Bs[0][0] + c * 4096 + wave * 1024);
    }
    __syncthreads();   // compiler drains vmcnt(0) before barrier
    bh8 af[FM], bf[FN];
    #pragma unroll
    for (int i = 0; i < FM; i++) af[i] = *(const bh8*)&As[wr * (FM * 16) + i * 16 + fr][ko];
    #pragma unroll
    for (int j = 0; j < FN; j++) bf[j] = *(const bh8*)&Bs[wc * (FN * 16) + j * 16 + fr][ko];
    #pragma unroll
    for (int i = 0; i < FM; i++)
      #pragma unroll
      for (int j = 0; j < FN; j++)
        acc[i][j] = __builtin_amdgcn_mfma_f32_16x16x32_bf16(af[i], bf[j], acc[i][j], 0, 0, 0);
  }
  float wsc = 0.f;
  if constexpr (EPI == 4 || EPI == 5) wsc = wscale[0];
  u16* Cb = (u16*)Cv;
  float* Cf = (float*)Cv;
  const int g = lane >> 4;
  #pragma unroll
  for (int i = 0; i < FM; i++){
    #pragma unroll
    for (int r = 0; r < 4; r++){
      const size_t row = bm + wr * (FM * 16) + i * 16 + g * 4 + r;
      float rs = 0.f;
      if constexpr (EPI == 4 || EPI == 5) rs = rowscale[row] * wsc;
      #pragma unroll
      for (int j = 0; j < FN; j++){
        const size_t col = bn + wc * (FN * 16) + j * 16 + fr;
        float v = acc[i][j][r];
        if constexpr (EPI == 1 || EPI == 2) v += b2f(bias[col]);
        if constexpr (EPI == 4 || EPI == 5) v = v * rs + b2f(bias[col]);
        if constexpr (EPI == 4){ float x = v; v = 0.5f * x * (1.f + tanhf(0.7978845608f * (x + 0.044715f * x * x * x))); }
        if constexpr (EPI == 0 || EPI == 1 || EPI == 4) Cb[row * ldc + col] = f2b(v);
        else Cf[row * ldc + col] = v;
      }
    }
  }
}

// ---------------- reg-staged BK=64 swizzled GEMM (kept for dt / xproj) ----------------
template<int EPI, int FM, int FN, int WR, int WC>
__global__ __launch_bounds__(256) void gemm16(
    const u16* __restrict__ A, const u16* __restrict__ W, void* __restrict__ Cv,
    int M, int N, int K, int lda, int ldb, int ldc,
    const u16* __restrict__ bias, const float* __restrict__ rowscale,
    const float* __restrict__ wscale)
{
  constexpr int BM = WR * FM * 16, BN = WC * FN * 16;
  __shared__ __align__(16) char As[BM * 128];
  __shared__ __align__(16) char Bs[BN * 128];
  const int tid = threadIdx.x, wave = tid >> 6, lane = tid & 63;
  const int wr = wave / WC, wc = wave % WC, fr = lane & 15, g = lane >> 4;
  const size_t bm = (size_t)blockIdx.y * BM, bn = (size_t)blockIdx.x * BN;
  const int kbase = blockIdx.z * K;
  f32x4 acc[FM][FN] = {};
  constexpr int ACH = BM / 32, BCH = BN / 32;
  u16x8 areg[ACH], breg[BCH];
  auto fetch = [&](int k0){
    #pragma unroll
    for (int c = 0; c < ACH; c++){
      int li = tid + c * 256;
      areg[c] = *(const u16x8*)&A[(bm + (li >> 3)) * (size_t)lda + kbase + k0 + ((li & 7) << 3)];
    }
    #pragma unroll
    for (int c = 0; c < BCH; c++){
      int li = tid + c * 256;
      breg[c] = *(const u16x8*)&W[(bn + (li >> 3)) * (size_t)ldb + kbase + k0 + ((li & 7) << 3)];
    }
  };
  fetch(0);
  for (int k0 = 0; k0 < K; k0 += 64){
    __syncthreads();
    #pragma unroll
    for (int c = 0; c < ACH; c++){
      int li = tid + c * 256, row = li >> 3, j = li & 7;
      *(u16x8*)&As[row * 128 + ((j * 16) ^ ((row & 7) << 4))] = areg[c];
    }
    #pragma unroll
    for (int c = 0; c < BCH; c++){
      int li = tid + c * 256, row = li >> 3, j = li & 7;
      *(u16x8*)&Bs[row * 128 + ((j * 16) ^ ((row & 7) << 4))] = breg[c];
    }
    __syncthreads();
    if (k0 + 64 < K) fetch(k0 + 64);
    bh8 af[2][FM], bf[2][FN];
    #pragma unroll
    for (int ks = 0; ks < 2; ks++){
      #pragma unroll
      for (int i = 0; i < FM; i++){
        int row = wr * (FM * 16) + i * 16 + fr;
        af[ks][i] = *(const bh8*)&As[row * 128 + ((ks * 64 + g * 16) ^ ((row & 7) << 4))];
      }
      #pragma unroll
      for (int j = 0; j < FN; j++){
        int row = wc * (FN * 16) + j * 16 + fr;
        bf[ks][j] = *(const bh8*)&Bs[row * 128 + ((ks * 64 + g * 16) ^ ((row & 7) << 4))];
      }
    }
    #pragma unroll
    for (int ks = 0; ks < 2; ks++)
      #pragma unroll
      for (int i = 0; i < FM; i++)
        #pragma unroll
        for (int j = 0; j < FN; j++)
          acc[i][j] = __builtin_amdgcn_mfma_f32_16x16x32_bf16(af[ks][i], bf[ks][j], acc[i][j], 0, 0, 0);
  }
  u16* Cb = (u16*)Cv;
  float* Cf = (float*)Cv + (size_t)blockIdx.z * M * ldc;
  #pragma unroll
  for (int i = 0; i < FM; i++){
    #pragma unroll
    for (int r = 0; r < 4; r++){
      const size_t row = bm + wr * (FM * 16) + i * 16 + g * 4 + r;
      #pragma unroll
      for (int j = 0; j < FN; j++){
        const size_t col = bn + wc * (FN * 16) + j * 16 + fr;
        float v = acc[i][j][r];
        if constexpr (EPI == 6){ float x = v + b2f(bias[col]); v = fmaxf(x, 0.f) + log1pf(__expf(-fabsf(x))); }
        if constexpr (EPI == 0 || EPI == 1) Cb[row * ldc + col] = f2b(v);
        else Cf[row * ldc + col] = v;
      }
    }
  }
}

// ---------------- xproj split-K reduce ----------------
__global__ __launch_bounds__(256) void xproj_reduce_kernel(
    const float* __restrict__ Pp, float* __restrict__ proj, u16* __restrict__ projb)
{
  const int idx = blockIdx.x * 256 + threadIdx.x;
  const int m = idx / 96, n = idx % 96;
  float s = 0.f;
  #pragma unroll
  for (int z = 0; z < 8; z++) s += Pp[(size_t)z * 2048 * 96 + idx];
  proj[idx] = s;
  if (n < 64) projb[(size_t)m * 64 + n] = f2b(s);
}

// ---------------- causal depthwise conv (D_CONV=4) + SiLU ----------------
__global__ __launch_bounds__(256) void conv_silu_kernel(
    const u16* __restrict__ xz, const void* __restrict__ cw, const void* __restrict__ cb,
    u16* __restrict__ u, const unsigned* __restrict__ Fg)
{
  const bool f32 = Fg[0] != 0;
  const int idx = blockIdx.x * 256 + threadIdx.x;
  const int c = idx & 2047;
  const int bt = idx >> 11;
  const int t = bt & 1023, b = bt >> 10;
  float acc = ldf(cb, c, f32);
  #pragma unroll
  for (int j = 0; j < 4; j++){
    int tt = t - 3 + j;
    if (tt >= 0) acc += b2f(xz[(size_t)(b * 1024 + tt) * 4096 + c]) * ldf(cw, c * 4 + j, f32);
  }
  u[(size_t)bt * 2048 + c] = f2b(acc * sigm(acc));
}

// ---------------- chunked selective scan ----------------
#define SCH 32
#define SNCH 32

__global__ __launch_bounds__(256) void scan_part1(
    const float* __restrict__ delta, const u16* __restrict__ u,
    const float* __restrict__ proj, const void* __restrict__ Alog,
    float* __restrict__ S, float* __restrict__ sumdl_o, const unsigned* __restrict__ Fg)
{
  const bool f32 = Fg[0] != 0;
  const int b = blockIdx.z, ch = blockIdx.y, d = blockIdx.x * 256 + threadIdx.x;
  float A[16], h[16];
  #pragma unroll
  for (int s = 0; s < 16; s++){ A[s] = -__expf(ldf(Alog, d * 16 + s, f32)); h[s] = 0.f; }
  __shared__ __align__(16) float Bsh[SCH][16];
  {
    int tc = threadIdx.x >> 3, j = (threadIdx.x & 7) * 2;
    *(float2*)&Bsh[tc][j] = *(const float2*)&proj[(size_t)(b * 1024 + ch * SCH + tc) * 96 + 64 + j];
  }
  __syncthreads();
  float sumdl = 0.f;
  for (int tt = 0; tt < SCH; tt++){
    const size_t m = (size_t)(b * 1024 + ch * SCH + tt);
    const float dl = delta[m * 2048 + d];
    const float du = dl * b2f(u[m * 2048 + d]);
    sumdl += dl;
    #pragma unroll
    for (int s = 0; s < 16; s++) h[s] = __expf(dl * A[s]) * h[s] + du * Bsh[tt][s];
  }
  #pragma unroll
  for (int s = 0; s < 16; s++) S[((size_t)(b * SNCH + ch) * 16 + s) * 2048 + d] = h[s];
  sumdl_o[(size_t)(b * SNCH + ch) * 2048 + d] = sumdl;
}

__global__ __launch_bounds__(256) void scan_combine(
    const float* __restrict__ S, const float* __restrict__ sumdl,
    const void* __restrict__ Alog, float* __restrict__ Hin, const unsigned* __restrict__ Fg)
{
  const bool f32 = Fg[0] != 0;
  const int idx = blockIdx.x * 256 + threadIdx.x;
  const int b = idx >> 11, d = idx & 2047;
  float A[16], h[16];
  #pragma unroll
  for (int s = 0; s < 16; s++){ A[s] = -__expf(ldf(Alog, d * 16 + s, f32)); h[s] = 0.f; }
  for (int ch = 0; ch < SNCH; ch++){
    const float sd = sumdl[(size_t)(b * SNCH + ch) * 2048 + d];
    #pragma unroll
    for (int s = 0; s < 16; s++){
      const size_t off = ((size_t)(b * SNCH + ch) * 16 + s) * 2048 + d;
      Hin[off] = h[s];
      h[s] = __expf(A[s] * sd) * h[s] + S[off];
    }
  }
}

__global__ __launch_bounds__(256) void scan_part2(
    const float* __restrict__ delta, const u16* __restrict__ u,
    const float* __restrict__ proj, const void* __restrict__ Alog,
    const void* __restrict__ Dp, const u16* __restrict__ xz,
    const float* __restrict__ Hin, u16* __restrict__ G, const unsigned* __restrict__ Fg)
{
  const bool f32 = Fg[0] != 0;
  const int b = blockIdx.z, ch = blockIdx.y, d = blockIdx.x * 256 + threadIdx.x;
  float A[16], h[16];
  #pragma unroll
  for (int s = 0; s < 16; s++){
    A[s] = -__expf(ldf(Alog, d * 16 + s, f32));
    h[s] = Hin[((size_t)(b * SNCH + ch) * 16 + s) * 2048 + d];
  }
  const float Dv = ldf(Dp, d, f32);
  __shared__ __align__(16) float BCs[SCH][32];
  {
    int tc = threadIdx.x >> 3, j = (threadIdx.x & 7) * 4;
    *(float4*)&BCs[tc][j] = *(const float4*)&proj[(size_t)(b * 1024 + ch * SCH + tc) * 96 + 64 + j];
  }
  __syncthreads();
  for (int tt = 0; tt < SCH; tt++){
    const size_t m = (size_t)(b * 1024 + ch * SCH + tt);
    const float dl = delta[m * 2048 + d];
    const float uv = b2f(u[m * 2048 + d]);
    const float du = dl * uv;
    float y = 0.f;
    #pragma unroll
    for (int s = 0; s < 16; s++){
      h[s] = __expf(dl * A[s]) * h[s] + du * BCs[tt][s];
      y += h[s] * BCs[tt][16 + s];
    }
    y += uv * Dv;
    const float r = b2f(xz[m * 4096 + 2048 + d]);
    G[m * 2048 + d] = f2b(y * (r * sigm(r)));
  }
}

// ---------------- V transpose: vb[token][1024ch] -> vtb[bh][64d][1024s] ----------------
__global__ __launch_bounds__(256) void vtrans_kernel(const u16* __restrict__ V, u16* __restrict__ Vt)
{
  __shared__ __align__(16) u16 T[64 * 64];
  const int bh = blockIdx.y, b = bh >> 4, hh = bh & 15;
  const int s0 = blockIdx.x * 64;
  const int tid = threadIdx.x;
  {
    int s = tid & 63, d0 = (tid >> 6) * 16;
    const u16* src = V + ((size_t)(b * 1024 + s0 + s)) * 1024 + hh * 64 + d0;
    u16x8 v0 = *(const u16x8*)src, v1 = *(const u16x8*)(src + 8);
    int byte0 = (s * 128 + d0 * 2) ^ ((s & 7) << 4);
    int byte1 = (s * 128 + d0 * 2 + 16) ^ ((s & 7) << 4);
    *(u16x8*)((char*)T + byte0) = v0;
    *(u16x8*)((char*)T + byte1) = v1;
  }
  __syncthreads();
  {
    int d = tid & 63, t0 = (tid >> 6) * 16;
    u16x8 w0, w1;
    #pragma unroll
    for (int j = 0; j < 8; j++){
      int r0 = t0 + j, r1 = t0 + 8 + j;
      w0[j] = *(const u16*)((char*)T + ((r0 * 128 + d * 2) ^ ((r0 & 7) << 4)));
      w1[j] = *(const u16*)((char*)T + ((r1 * 128 + d * 2) ^ ((r1 & 7) << 4)));
    }
    u16* dst = Vt + ((size_t)bh * 64 + d) * 1024 + s0 + t0;
    *(u16x8*)dst = w0;
    *(u16x8*)(dst + 8) = w1;
  }
}

// ---------------- multi-wave MFMA flash cross-attention, LDS-staged K/V ----------------
#define ASPL 2
__global__ __launch_bounds__(256) void attn_mw_kernel(
    const u16* __restrict__ Q, const u16* __restrict__ Kb, const u16* __restrict__ Vt,
    u16* __restrict__ Opart, float* __restrict__ Lpart)
{
  const int bh = blockIdx.y, b = bh >> 4, hh = bh & 15;
  const int z = blockIdx.z;
  const int tid = threadIdx.x, wave = tid >> 6, lane = tid & 63;
  const int fr = lane & 15, g = lane >> 4;
  const int q0 = blockIdx.x * 64 + wave * 16;
  __shared__ __align__(16) char Ks[64 * 128];
  __shared__ __align__(16) char Vs[64 * 128];
  __shared__ __align__(16) u16 Pl[4][1024];
  const u16* qp = Q + ((size_t)(b * 1024 + q0 + fr)) * 1024 + hh * 64 + g * 8;
  const bh8 aq0 = *(const bh8*)qp;
  const bh8 aq1 = *(const bh8*)(qp + 32);
  f32x4 oacc[4] = {};
  float lsum[4] = {};
  const u16* kbase = Kb + ((size_t)(b * 1024)) * 1024 + hh * 64;
  const u16* vbase = Vt + ((size_t)bh * 64) * 1024;
  const int srow = tid >> 2, sj = (tid & 3) * 2;
  for (int s0 = z * (1024 / ASPL); s0 < (z + 1) * (1024 / ASPL); s0 += 64){
    __syncthreads();
    {
      const u16* kr = kbase + (size_t)(s0 + srow) * 1024 + sj * 8;
      u16x8 k0 = *(const u16x8*)kr, k1 = *(const u16x8*)(kr + 8);
      *(u16x8*)&Ks[srow * 128 + ((sj * 16) ^ ((srow & 7) << 4))] = k0;
      *(u16x8*)&Ks[srow * 128 + (((sj + 1) * 16) ^ ((srow & 7) << 4))] = k1;
      const u16* vr = vbase + (size_t)srow * 1024 + s0 + sj * 8;
      u16x8 v0 = *(const u16x8*)vr, v1 = *(const u16x8*)(vr + 8);
      *(u16x8*)&Vs[srow * 128 + ((sj * 16) ^ ((srow & 7) << 4))] = v0;
      *(u16x8*)&Vs[srow * 128 + (((sj + 1) * 16) ^ ((srow & 7) << 4))] = v1;
    }
    __syncthreads();
    bh8 bk[4][2], bv[2][4];
    #pragma unroll
    for (int ct = 0; ct < 4; ct++){
      int row = 16 * ct + fr;
      #pragma unroll
      for (int ks = 0; ks < 2; ks++)
        bk[ct][ks] = *(const bh8*)&Ks[row * 128 + ((ks * 64 + g * 16) ^ ((row & 7) << 4))];
    }
    #pragma unroll
    for (int dt = 0; dt < 4; dt++){
      int row = 16 * dt + fr;
      #pragma unroll
      for (int ks = 0; ks < 2; ks++)
        bv[ks][dt] = *(const bh8*)&Vs[row * 128 + ((ks * 64 + g * 16) ^ ((row & 7) << 4))];
    }
    #pragma unroll
    for (int ct = 0; ct < 4; ct++){
      f32x4 zz = {};
      zz = __builtin_amdgcn_mfma_f32_16x16x32_bf16(aq0, bk[ct][0], zz, 0, 0, 0);
      zz = __builtin_amdgcn_mfma_f32_16x16x32_bf16(aq1, bk[ct][1], zz, 0, 0, 0);
      #pragma unroll
      for (int r = 0; r < 4; r++){
        float p = __expf(zz[r] * 0.125f);
        u16 pb = f2b(p);
        lsum[r] += b2f(pb);
        int row = 4 * g + r, col = 16 * ct + fr;
        *(u16*)((char*)&Pl[wave][0] + ((row * 128 + col * 2) ^ ((row & 7) << 4))) = pb;
      }
    }
    bh8 pa[2];
    #pragma unroll
    for (int ks = 0; ks < 2; ks++)
      pa[ks] = *(const bh8*)((char*)&Pl[wave][0] + ((fr * 128 + (ks * 32 + g * 8) * 2) ^ ((fr & 7) << 4)));
    #pragma unroll
    for (int dt = 0; dt < 4; dt++){
      oacc[dt] = __builtin_amdgcn_mfma_f32_16x16x32_bf16(pa[0], bv[0][dt], oacc[dt], 0, 0, 0);
      oacc[dt] = __builtin_amdgcn_mfma_f32_16x16x32_bf16(pa[1], bv[1][dt], oacc[dt], 0, 0, 0);
    }
  }
  #pragma unroll
  for (int r = 0; r < 4; r++){
    #pragma unroll
    for (int d2 = 1; d2 < 16; d2 <<= 1) lsum[r] += __shfl_xor(lsum[r], d2);
  }
  u16* opz = Opart + (size_t)z * 2097152;
  #pragma unroll
  for (int r = 0; r < 4; r++){
    const int tok = b * 1024 + q0 + 4 * g + r;
    #pragma unroll
    for (int dt = 0; dt < 4; dt++)
      opz[(size_t)tok * 1024 + hh * 64 + 16 * dt + fr] = f2b(oacc[dt][r]);
    if (fr == 0) Lpart[(size_t)z * 32768 + tok * 16 + hh] = lsum[r];
  }
}

__global__ __launch_bounds__(256) void attn_combine_kernel(
    const u16* __restrict__ Opart, const float* __restrict__ Lpart, u16* __restrict__ O)
{
  const int tok = blockIdx.x, tid = threadIdx.x;
  const int c = tid * 4, hh = c >> 6;
  float l = 0.f;
  #pragma unroll
  for (int z = 0; z < ASPL; z++) l += Lpart[(size_t)z * 32768 + tok * 16 + hh];
  float acc[4] = {};
  #pragma unroll
  for (int z = 0; z < ASPL; z++){
    u16x4 v = *(const u16x4*)&Opart[(size_t)z * 2097152 + (size_t)tok * 1024 + c];
    #pragma unroll
    for (int j = 0; j < 4; j++) acc[j] += b2f(v[j]);
  }
  const float inv = 1.f / l;
  u16x4 ov;
  #pragma unroll
  for (int j = 0; j < 4; j++) ov[j] = f2b(acc[j] * inv);
  *(u16x4*)&O[(size_t)tok * 1024 + c] = ov;
}

// ---------------- rmsnorm(a + b) * w ----------------
__global__ __launch_bounds__(256) void rmsnorm_kernel(
    const void* __restrict__ a, int aIn, const float* __restrict__ bsrc,
    const void* __restrict__ w, u16* __restrict__ outb, float* __restrict__ outf,
    void* __restrict__ dout, const unsigned* __restrict__ Fg)
{
  const bool f32 = Fg[0] != 0;
  const bool a32 = aIn ? f32 : true;
  const int row = blockIdx.x, tid = threadIdx.x;
  const size_t base = (size_t)row * 1024 + tid * 4;
  float v[4];
  if (a32){
    float4 t = *(const float4*)&((const float*)a)[base];
    v[0] = t.x; v[1] = t.y; v[2] = t.z; v[3] = t.w;
  } else {
    u16x4 t = *(const u16x4*)&((const u16*)a)[base];
    v[0] = b2f(t[0]); v[1] = b2f(t[1]); v[2] = b2f(t[2]); v[3] = b2f(t[3]);
  }
  float4 t2 = *(const float4*)&bsrc[base];
  v[0] += t2.x; v[1] += t2.y; v[2] += t2.z; v[3] += t2.w;
  float ss = v[0]*v[0] + v[1]*v[1] + v[2]*v[2] + v[3]*v[3];
  __shared__ float red[256];
  red[tid] = ss; __syncthreads();
  for (int s = 128; s > 0; s >>= 1){ if (tid < s) red[tid] += red[tid + s]; __syncthreads(); }
  const float scale = rsqrtf(red[0] * (1.f / 1024.f) + 1e-6f);
  float o[4];
  #pragma unroll
  for (int i = 0; i < 4; i++) o[i] = v[i] * scale * ldf(w, tid * 4 + i, f32);
  if (outb){
    u16x4 ov;
    #pragma unroll
    for (int i = 0; i < 4; i++) ov[i] = f2b(o[i]);
    *(u16x4*)&outb[base] = ov;
  }
  if (outf) *(float4*)&outf[base] = make_float4(o[0], o[1], o[2], o[3]);
  if (dout){
    if (f32) ((float*)dout)[base] = o[0], ((float*)dout)[base+1] = o[1], ((float*)dout)[base+2] = o[2], ((float*)dout)[base+3] = o[3];
    else {
      u16x4 ov;
      #pragma unroll
      for (int i = 0; i < 4; i++) ov[i] = f2b(o[i]);
      *(u16x4*)&((u16*)dout)[base] = ov;
    }
  }
}

// ---------------- per-token 8-bit absmax act quant ----------------
__global__ __launch_bounds__(256) void actquant_kernel(
    const void* __restrict__ in, int inF32, u16* __restrict__ q, float* __restrict__ srow, int N)
{
  const int row = blockIdx.x, tid = threadIdx.x;
  float amax = 0.f;
  for (int c = tid * 4; c < N; c += 1024){
    #pragma unroll
    for (int j = 0; j < 4; j++){
      float x = inF32 ? ((const float*)in)[(size_t)row * N + c + j] : b2f(((const u16*)in)[(size_t)row * N + c + j]);
      amax = fmaxf(amax, fabsf(x));
    }
  }
  __shared__ float red[256];
  red[tid] = amax; __syncthreads();
  for (int s = 128; s > 0; s >>= 1){ if (tid < s) red[tid] = fmaxf(red[tid], red[tid + s]); __syncthreads(); }
  const float s = fmaxf(red[0], 1e-5f) * (1.f / 127.f);
  if (tid == 0) srow[row] = s;
  for (int c = tid * 4; c < N; c += 1024){
    u16x4 ov;
    #pragma unroll
    for (int j = 0; j < 4; j++){
      float x = inF32 ? ((const float*)in)[(size_t)row * N + c + j] : b2f(((const u16*)in)[(size_t)row * N + c + j]);
      ov[j] = f2b(fminf(fmaxf(rintf(x / s), -128.f), 127.f));
    }
    *(u16x4*)&q[(size_t)row * N + c] = ov;
  }
}

// ---------------- BitNet weight quant ----------------
__global__ __launch_bounds__(256) void absmean_partial_kernel(
    const void* __restrict__ w, float* __restrict__ part, const unsigned* __restrict__ Fg)
{
  const bool f32 = Fg[0] != 0;
  const int tid = threadIdx.x;
  const size_t base = (size_t)blockIdx.x * 1024 + tid * 4;
  float ssum = 0.f;
  #pragma unroll
  for (int j = 0; j < 4; j++) ssum += fabsf(ldf(w, base + j, f32));
  __shared__ float red[256];
  red[tid] = ssum; __syncthreads();
  for (int s = 128; s > 0; s >>= 1){ if (tid < s) red[tid] += red[tid + s]; __syncthreads(); }
  if (tid == 0) part[blockIdx.x] = red[0];
}

__global__ __launch_bounds__(256) void absmean_final_kernel(
    const float* __restrict__ part, int n, float invc, float* __restrict__ out)
{
  const int tid = threadIdx.x;
  float ssum = 0.f;
  for (int i = tid; i < n; i += 256) ssum += part[i];
  __shared__ float red[256];
  red[tid] = ssum; __syncthreads();
  for (int s = 128; s > 0; s >>= 1){ if (tid < s) red[tid] += red[tid + s]; __syncthreads(); }
  if (tid == 0) out[0] = fmaxf(red[0] * invc, 1e-5f);
}

__global__ __launch_bounds__(256) void ternarize_kernel(
    const void* __restrict__ w, const float* __restrict__ sp, u16* __restrict__ t,
    const unsigned* __restrict__ Fg)
{
  const bool f32 = Fg[0] != 0;
  const float s = sp[0];
  const size_t base = ((size_t)blockIdx.x * 256 + threadIdx.x) * 4;
  u16x4 o;
  #pragma unroll
  for (int i = 0; i < 4; i++){
    float vv = fminf(fmaxf(rintf(ldf(w, base + i, f32) / s), -1.f), 1.f);
    o[i] = f2b(vv);
  }
  *(u16x4*)&t[base] = o;
}

extern "C" void kernel_launch(void* const* d_in, const int* in_sizes, int n_in,
                              void* d_out, int out_size, void* d_ws, size_t ws_size,
                              hipStream_t stream)
{
  const void* x      = d_in[0];
  const void* enc    = d_in[1];
  const void* in_w   = d_in[3];
  const void* conv_w = d_in[4];
  const void* conv_b = d_in[5];
  const void* xproj_w= d_in[6];
  const void* dt_w   = d_in[7];
  const void* dt_b   = d_in[8];
  const void* A_log  = d_in[9];
  const void* Dp     = d_in[10];
  const void* out_w  = d_in[11];
  const void* n1w    = d_in[12];
  const void* q_w = d_in[13]; const void* q_b = d_in[14];
  const void* k_w = d_in[15]; const void* k_b = d_in[16];
  const void* v_w = d_in[17]; const void* v_b = d_in[18];
  const void* o_w = d_in[19]; const void* o_b = d_in[20];
  const void* n2w = d_in[21];
  const void* w1  = d_in[22]; const void* b1 = d_in[23];
  const void* w2  = d_in[24]; const void* b2 = d_in[25];
  const void* n3w = d_in[26];

  char* ws = (char*)d_ws;
  const size_t MB = 1ull << 20;
  const size_t KB = 1024;
  float*    sw1  = (float*)(ws + 0);
  float*    sw2  = (float*)(ws + 16);
  unsigned* Fg   = (unsigned*)(ws + 64);
  float*    s1   = (float*)(ws + 4096);
  float*    s2   = (float*)(ws + 12288);
  float*    part = (float*)(ws + 20480);
  // phase A transients
  u16*   xz   = (u16*)  (ws + 1 * MB);    // 1-17
  u16*   u    = (u16*)  (ws + 17 * MB);   // 17-25
  float* proj = (float*)(ws + 25 * MB);   // 25-26
  float* delta= (float*)(ws + 26 * MB);   // 26-42
  float* Pp   = (float*)(ws + 42 * MB);   // 42-48
  u16*   projb= (u16*)  (ws + 48 * MB);   // 48-48.5
  u16*   G    = (u16*)  (ws + 42 * MB);   // 42-50
  float* Ssc  = (float*)(ws + 50 * MB);   // 50-58
  float* Hin  = (float*)(ws + 58 * MB);   // 58-66
  float* sdl  = (float*)(ws + 66 * MB);   // 66-66.5
  float* mout = (float*)(ws + 50 * MB);   // 50-58
  u16*   h1b  = (u16*)  (ws + 26 * MB);   // 26-30
  float* h1f  = (float*)(ws + 30 * MB);   // 30-38
  // phase B transients
  u16*   qb   = (u16*)  (ws + 1 * MB);    // 1-5
  u16*   kb   = (u16*)  (ws + 5 * MB);    // 5-9
  u16*   vb   = (u16*)  (ws + 9 * MB);    // 9-13
  u16*   vtb  = (u16*)  (ws + 38 * MB);   // 38-42
  u16*   Opart= (u16*)  (ws + 42 * MB);   // 42-50
  float* Lpart= (float*)(ws + 66 * MB);   // 66-66.25
  u16*   ao   = (u16*)  (ws + 13 * MB);   // 13-17
  float* aof  = (float*)(ws + 17 * MB);   // 17-25
  float* h2f  = (float*)(ws + 58 * MB);   // 58-66
  // phase C transients
  u16*   q1   = (u16*)  (ws + 1 * MB);    // 1-5
  u16*   t1   = (u16*)  (ws + 5 * MB);    // 5-13
  u16*   t2   = (u16*)  (ws + 50 * MB);   // 50-58
  u16*   gh   = (u16*)  (ws + 13 * MB);   // 13-29
  u16*   q2   = (u16*)  (ws + 29 * MB);   // 29-45
  float* fo   = (float*)(ws + 1 * MB);    // 1-9
  // persistent bf16 copies (68-97)
  u16* xb       = (u16*)(ws + 68 * MB);
  u16* encb     = (u16*)(ws + 72 * MB);
  u16* in_wb    = (u16*)(ws + 76 * MB);
  u16* out_wb   = (u16*)(ws + 84 * MB);
  u16* q_wb     = (u16*)(ws + 88 * MB);
  u16* k_wb     = (u16*)(ws + 90 * MB);
  u16* v_wb     = (u16*)(ws + 92 * MB);
  u16* o_wb     = (u16*)(ws + 94 * MB);
  u16* xproj_wb = (u16*)(ws + 96 * MB);
  u16* dt_wb    = (u16*)(ws + 96 * MB + 512 * KB);
  u16* dt_bb    = (u16*)(ws + 96 * MB + 768 * KB);
  u16* q_bb     = (u16*)(ws + 96 * MB + 776 * KB);
  u16* k_bb     = (u16*)(ws + 96 * MB + 780 * KB);
  u16* v_bb     = (u16*)(ws + 96 * MB + 784 * KB);
  u16* o_bb     = (u16*)(ws + 96 * MB + 788 * KB);
  u16* b1b      = (u16*)(ws + 96 * MB + 792 * KB);
  u16* b2b      = (u16*)(ws + 96 * MB + 808 * KB);

  dim3 blk(256);
  detect_kernel<<<dim3(1), blk, 0, stream>>>(x, Fg);

  // 0b. convert all GEMM-facing externals to bf16
  {
    CvtJobs jobs;
    const void* srcs[NCVT] = { x, enc, in_w, out_w, q_w, k_w, v_w, o_w, xproj_w, dt_w,
                               dt_b, q_b, k_b, v_b, o_b, b1, b2 };
    u16* dsts[NCVT] = { xb, encb, in_wb, out_wb, q_wb, k_wb, v_wb, o_wb, xproj_wb, dt_wb,
                        dt_bb, q_bb, k_bb, v_bb, o_bb, b1b, b2b };
    int ns[NCVT] = { 2097152, 2097152, 4194304, 2097152, 1048576, 1048576, 1048576, 1048576,
                     196608, 131072, 2048, 1024, 1024, 1024, 1024, 4096, 1024 };
    int bo = 0;
    for (int j = 0; j < NCVT; j++){
      jobs.src[j] = srcs[j]; jobs.dst[j] = dsts[j]; jobs.n[j] = ns[j];
      jobs.blk_off[j] = bo;
      bo += (ns[j] / 8 + 255) / 256;
    }
    jobs.blk_off[NCVT] = bo;
    convert_kernel<<<dim3(bo), blk, 0, stream>>>(jobs, Fg);
  }

  // 1. xz = x @ in_w^T  (m97-structure, 128x128)
  gemm_lds<0,4,4><<<dim3(32, 16), blk, 0, stream>>>(xb, in_wb, xz, 2048, 4096, 1024, 1024, 1024, 4096, nullptr, nullptr, nullptr);
  // 2. conv + SiLU
  conv_silu_kernel<<<dim3(16384), blk, 0, stream>>>(xz, conv_w, conv_b, u, Fg);
  // 3. proj = u @ xproj_w^T (split-K=8) + reduce
  gemm16<3,2,3,2,2><<<dim3(1, 32, 8), blk, 0, stream>>>(u, xproj_wb, Pp, 2048, 96, 256, 2048, 2048, 96, nullptr, nullptr, nullptr);
  xproj_reduce_kernel<<<dim3(768), blk, 0, stream>>>(Pp, proj, projb);
  // 4. delta = softplus(projb @ dt_w^T + dt_b)
  gemm16<6,2,2,2,2><<<dim3(32, 32), blk, 0, stream>>>(projb, dt_wb, delta, 2048, 2048, 64, 64, 64, 2048, dt_bb, nullptr, nullptr);
  // 5. chunked scan
  scan_part1<<<dim3(8, SNCH, 2), blk, 0, stream>>>(delta, u, proj, A_log, Ssc, sdl, Fg);
  scan_combine<<<dim3(16), blk, 0, stream>>>(Ssc, sdl, A_log, Hin, Fg);
  scan_part2<<<dim3(8, SNCH, 2), blk, 0, stream>>>(delta, u, proj, A_log, Dp, xz, Hin, G, Fg);
  // 6. mamba_out = G @ out_w^T  (128x64)
  gemm_lds<3,4,2><<<dim3(16, 16), blk, 0, stream>>>(G, out_wb, mout, 2048, 1024, 2048, 2048, 2048, 1024, nullptr, nullptr, nullptr);
  // 7. h1 = rmsnorm(x + mamba_out)
  rmsnorm_kernel<<<dim3(2048), blk, 0, stream>>>(x, 1, mout, n1w, h1b, h1f, nullptr, Fg);
  // 8. q/k/v projections (128x64)
  gemm_lds<1,4,2><<<dim3(16, 16), blk, 0, stream>>>(h1b, q_wb, qb, 2048, 1024, 1024, 1024, 1024, 1024, q_bb, nullptr, nullptr);
  gemm_lds<1,4,2><<<dim3(16, 16), blk, 0, stream>>>(encb, k_wb, kb, 2048, 1024, 1024, 1024, 1024, 1024, k_bb, nullptr, nullptr);
  gemm_lds<1,4,2><<<dim3(16, 16), blk, 0, stream>>>(encb, v_wb, vb, 2048, 1024, 1024, 1024, 1024, 1024, v_bb, nullptr, nullptr);
  // 8b. V transpose
  vtrans_kernel<<<dim3(16, 32), blk, 0, stream>>>(vb, vtb);
  // 9. multi-wave LDS-staged flash attention + combine
  attn_mw_kernel<<<dim3(16, 32, ASPL), blk, 0, stream>>>(qb, kb, vtb, Opart, Lpart);
  attn_combine_kernel<<<dim3(2048), blk, 0, stream>>>(Opart, Lpart, ao);
  // 10. o projection (128x64)
  gemm_lds<2,4,2><<<dim3(16, 16), blk, 0, stream>>>(ao, o_wb, aof, 2048, 1024, 1024, 1024, 1024, 1024, o_bb, nullptr, nullptr);
  // 11. h2 = rmsnorm(h1 + attn)
  rmsnorm_kernel<<<dim3(2048), blk, 0, stream>>>(h1f, 0, aof, n2w, nullptr, h2f, nullptr, Fg);
  // 12. act_quant(h2)
  actquant_kernel<<<dim3(2048), blk, 0, stream>>>(h2f, 1, q1, s1, 1024);
  // 13. weight_quant(w1), weight_quant(w2)
  absmean_partial_kernel<<<dim3(4096), blk, 0, stream>>>(w1, part, Fg);
  absmean_final_kernel<<<dim3(1), blk, 0, stream>>>(part, 4096, 1.f / 4194304.f, sw1);
  ternarize_kernel<<<dim3(4096), blk, 0, stream>>>(w1, sw1, t1, Fg);
  absmean_partial_kernel<<<dim3(4096), blk, 0, stream>>>(w2, part, Fg);
  absmean_final_kernel<<<dim3(1), blk, 0, stream>>>(part, 4096, 1.f / 4194304.f, sw2);
  ternarize_kernel<<<dim3(4096), blk, 0, stream>>>(w2, sw2, t2, Fg);
  // 14. ffn hidden = gelu(q1 @ t1^T * s1*sw1 + b1) -> bf16  (128x128)
  gemm_lds<4,4,4><<<dim3(32, 16), blk, 0, stream>>>(q1, t1, gh, 2048, 4096, 1024, 1024, 1024, 4096, b1b, s1, sw1);
  // 15. act_quant(gh)
  actquant_kernel<<<dim3(2048), blk, 0, stream>>>(gh, 0, q2, s2, 4096);
  // 16. ffn out = q2 @ t2^T * s2*sw2 + b2  (128x64)
  gemm_lds<5,4,2><<<dim3(16, 16), blk, 0, stream>>>(q2, t2, fo, 2048, 1024, 4096, 4096, 4096, 1024, b2b, s2, sw2);
  // 17. out = rmsnorm(h2 + ffn) -> d_out
  rmsnorm_kernel<<<dim3(2048), blk, 0, stream>>>(h2f, 0, fo, n3w, nullptr, nullptr, d_out, Fg);
}

// Round 10
// 433.410 us; speedup vs baseline: 1.1640x; 1.1640x over previous
//
#include <hip/hip_runtime.h>
#include <math.h>

#define DEV __device__ __forceinline__
using u16 = unsigned short;
typedef __bf16 bh8 __attribute__((ext_vector_type(8)));
typedef float f32x4 __attribute__((ext_vector_type(4)));
typedef u16 u16x8 __attribute__((ext_vector_type(8)));
typedef u16 u16x4 __attribute__((ext_vector_type(4)));

DEV float b2f(u16 x){ unsigned u = ((unsigned)x) << 16; float f; __builtin_memcpy(&f, &u, 4); return f; }
DEV u16 f2b(float f){ unsigned u; __builtin_memcpy(&u, &f, 4); return (u16)((u + 0x7fffu + ((u >> 16) & 1u)) >> 16); }
DEV float sigm(float x){ return 1.f / (1.f + __expf(-x)); }
DEV float ldf(const void* p, size_t i, bool f32){ return f32 ? ((const float*)p)[i] : b2f(((const u16*)p)[i]); }

typedef __attribute__((address_space(1))) const void* gptr_t;
typedef __attribute__((address_space(3))) void* lptr_t;
DEV void gload16(const void* g, void* l){
  __builtin_amdgcn_global_load_lds((gptr_t)g, (lptr_t)l, 16, 0, 0);
}

// ---------------- dtype detect ----------------
__global__ __launch_bounds__(256) void detect_kernel(const void* x, unsigned* flag)
{
  const int tid = threadIdx.x;
  const u16* p = (const u16*)x;
  int sane = 0;
  #pragma unroll
  for (int j = 0; j < 8; j++){
    u16 v = p[(size_t)(tid * 8 + j) * 2];
    int e = (v >> 7) & 0xFF;
    sane += (e >= 0x60 && e <= 0x8F) ? 1 : 0;
  }
  __shared__ int red[256];
  red[tid] = sane; __syncthreads();
  for (int s = 128; s > 0; s >>= 1){ if (tid < s) red[tid] += red[tid + s]; __syncthreads(); }
  if (tid == 0) flag[0] = (red[0] < 1200) ? 1u : 0u;
}

// ---------------- batch convert external -> bf16 ws ----------------
#define NCVT 17
struct CvtJobs {
  const void* src[NCVT];
  u16* dst[NCVT];
  int n[NCVT];
  int blk_off[NCVT + 1];
};
__global__ __launch_bounds__(256) void convert_kernel(CvtJobs jobs, const unsigned* __restrict__ Fg)
{
  const bool f32 = Fg[0] != 0;
  const int bx = blockIdx.x;
  int j = 0;
  while (bx >= jobs.blk_off[j + 1]) j++;
  const int e = (bx - jobs.blk_off[j]) * 2048 + threadIdx.x * 8;
  if (e >= jobs.n[j]) return;
  if (f32){
    const float* s = (const float*)jobs.src[j] + e;
    u16x8 o;
    #pragma unroll
    for (int i = 0; i < 8; i++) o[i] = f2b(s[i]);
    *(u16x8*)(jobs.dst[j] + e) = o;
  } else {
    *(u16x8*)(jobs.dst[j] + e) = *(const u16x8*)((const u16*)jobs.src[j] + e);
  }
}

// ======== global_load_lds GEMM, BK=64, XOR-swizzled LDS via PRE-SWIZZLED SOURCE ========
// Linear LDS dest (HW requirement) + source addr permuted so data lands at the
// swizzled location P(row,j) = row*128 + ((j*16) ^ ((row&7)<<4)); read side uses P.
// li*16 == P(li>>3, (li&7)^(row&7))  ->  source j = (li&7) ^ (row&7).
// 4 waves 2x2; BM=32*FM, BN=32*FN.
// EPI: 0 bf16  1 bf16+bias  2 f32+bias  3 f32  4 bf16=gelu(acc*rs*ws+bias)  5 f32=acc*rs*ws+bias
template<int EPI, int FM, int FN>
__global__ __launch_bounds__(256) void gemm_gl(
    const u16* __restrict__ A, const u16* __restrict__ W, void* __restrict__ Cv,
    int M, int N, int K, int lda, int ldb, int ldc,
    const u16* __restrict__ bias, const float* __restrict__ rowscale,
    const float* __restrict__ wscale)
{
  constexpr int BM = 32 * FM, BN = 32 * FN;
  __shared__ __align__(16) char As[BM * 128];
  __shared__ __align__(16) char Bs[BN * 128];
  const int tid = threadIdx.x, wave = tid >> 6, lane = tid & 63;
  const int wr = wave >> 1, wc = wave & 1, fr = lane & 15, g = lane >> 4;
  const size_t bm = (size_t)blockIdx.y * BM, bn = (size_t)blockIdx.x * BN;
  f32x4 acc[FM][FN] = {};
  for (int k0 = 0; k0 < K; k0 += 64){
    __syncthreads();
    #pragma unroll
    for (int c = 0; c < BM / 32; c++){
      int li = c * 256 + tid;
      int row = li >> 3, j = (li & 7) ^ (row & 7);
      gload16(&A[(bm + row) * (size_t)lda + k0 + j * 8],
              (char*)As + c * 4096 + wave * 1024);
    }
    #pragma unroll
    for (int c = 0; c < BN / 32; c++){
      int li = c * 256 + tid;
      int row = li >> 3, j = (li & 7) ^ (row & 7);
      gload16(&W[(bn + row) * (size_t)ldb + k0 + j * 8],
              (char*)Bs + c * 4096 + wave * 1024);
    }
    __syncthreads();   // compiler drains vmcnt(0) before barrier
    bh8 af[2][FM], bf[2][FN];
    #pragma unroll
    for (int ks = 0; ks < 2; ks++){
      #pragma unroll
      for (int i = 0; i < FM; i++){
        int row = wr * (FM * 16) + i * 16 + fr;
        af[ks][i] = *(const bh8*)&As[row * 128 + ((ks * 64 + g * 16) ^ ((row & 7) << 4))];
      }
      #pragma unroll
      for (int j = 0; j < FN; j++){
        int row = wc * (FN * 16) + j * 16 + fr;
        bf[ks][j] = *(const bh8*)&Bs[row * 128 + ((ks * 64 + g * 16) ^ ((row & 7) << 4))];
      }
    }
    #pragma unroll
    for (int ks = 0; ks < 2; ks++)
      #pragma unroll
      for (int i = 0; i < FM; i++)
        #pragma unroll
        for (int j = 0; j < FN; j++)
          acc[i][j] = __builtin_amdgcn_mfma_f32_16x16x32_bf16(af[ks][i], bf[ks][j], acc[i][j], 0, 0, 0);
  }
  float wsc = 0.f;
  if constexpr (EPI == 4 || EPI == 5) wsc = wscale[0];
  u16* Cb = (u16*)Cv;
  float* Cf = (float*)Cv;
  #pragma unroll
  for (int i = 0; i < FM; i++){
    #pragma unroll
    for (int r = 0; r < 4; r++){
      const size_t row = bm + wr * (FM * 16) + i * 16 + g * 4 + r;
      float rs = 0.f;
      if constexpr (EPI == 4 || EPI == 5) rs = rowscale[row] * wsc;
      #pragma unroll
      for (int j = 0; j < FN; j++){
        const size_t col = bn + wc * (FN * 16) + j * 16 + fr;
        float v = acc[i][j][r];
        if constexpr (EPI == 1 || EPI == 2) v += b2f(bias[col]);
        if constexpr (EPI == 4 || EPI == 5) v = v * rs + b2f(bias[col]);
        if constexpr (EPI == 4){ float x = v; v = 0.5f * x * (1.f + tanhf(0.7978845608f * (x + 0.044715f * x * x * x))); }
        if constexpr (EPI == 0 || EPI == 1 || EPI == 4) Cb[row * ldc + col] = f2b(v);
        else Cf[row * ldc + col] = v;
      }
    }
  }
}

// ---------------- reg-staged BK=64 swizzled GEMM (dt / xproj) ----------------
template<int EPI, int FM, int FN, int WR, int WC>
__global__ __launch_bounds__(256) void gemm16(
    const u16* __restrict__ A, const u16* __restrict__ W, void* __restrict__ Cv,
    int M, int N, int K, int lda, int ldb, int ldc,
    const u16* __restrict__ bias, const float* __restrict__ rowscale,
    const float* __restrict__ wscale)
{
  constexpr int BM = WR * FM * 16, BN = WC * FN * 16;
  __shared__ __align__(16) char As[BM * 128];
  __shared__ __align__(16) char Bs[BN * 128];
  const int tid = threadIdx.x, wave = tid >> 6, lane = tid & 63;
  const int wr = wave / WC, wc = wave % WC, fr = lane & 15, g = lane >> 4;
  const size_t bm = (size_t)blockIdx.y * BM, bn = (size_t)blockIdx.x * BN;
  const int kbase = blockIdx.z * K;
  f32x4 acc[FM][FN] = {};
  constexpr int ACH = BM / 32, BCH = BN / 32;
  u16x8 areg[ACH], breg[BCH];
  auto fetch = [&](int k0){
    #pragma unroll
    for (int c = 0; c < ACH; c++){
      int li = tid + c * 256;
      areg[c] = *(const u16x8*)&A[(bm + (li >> 3)) * (size_t)lda + kbase + k0 + ((li & 7) << 3)];
    }
    #pragma unroll
    for (int c = 0; c < BCH; c++){
      int li = tid + c * 256;
      breg[c] = *(const u16x8*)&W[(bn + (li >> 3)) * (size_t)ldb + kbase + k0 + ((li & 7) << 3)];
    }
  };
  fetch(0);
  for (int k0 = 0; k0 < K; k0 += 64){
    __syncthreads();
    #pragma unroll
    for (int c = 0; c < ACH; c++){
      int li = tid + c * 256, row = li >> 3, j = li & 7;
      *(u16x8*)&As[row * 128 + ((j * 16) ^ ((row & 7) << 4))] = areg[c];
    }
    #pragma unroll
    for (int c = 0; c < BCH; c++){
      int li = tid + c * 256, row = li >> 3, j = li & 7;
      *(u16x8*)&Bs[row * 128 + ((j * 16) ^ ((row & 7) << 4))] = breg[c];
    }
    __syncthreads();
    if (k0 + 64 < K) fetch(k0 + 64);
    bh8 af[2][FM], bf[2][FN];
    #pragma unroll
    for (int ks = 0; ks < 2; ks++){
      #pragma unroll
      for (int i = 0; i < FM; i++){
        int row = wr * (FM * 16) + i * 16 + fr;
        af[ks][i] = *(const bh8*)&As[row * 128 + ((ks * 64 + g * 16) ^ ((row & 7) << 4))];
      }
      #pragma unroll
      for (int j = 0; j < FN; j++){
        int row = wc * (FN * 16) + j * 16 + fr;
        bf[ks][j] = *(const bh8*)&Bs[row * 128 + ((ks * 64 + g * 16) ^ ((row & 7) << 4))];
      }
    }
    #pragma unroll
    for (int ks = 0; ks < 2; ks++)
      #pragma unroll
      for (int i = 0; i < FM; i++)
        #pragma unroll
        for (int j = 0; j < FN; j++)
          acc[i][j] = __builtin_amdgcn_mfma_f32_16x16x32_bf16(af[ks][i], bf[ks][j], acc[i][j], 0, 0, 0);
  }
  u16* Cb = (u16*)Cv;
  float* Cf = (float*)Cv + (size_t)blockIdx.z * M * ldc;
  #pragma unroll
  for (int i = 0; i < FM; i++){
    #pragma unroll
    for (int r = 0; r < 4; r++){
      const size_t row = bm + wr * (FM * 16) + i * 16 + g * 4 + r;
      #pragma unroll
      for (int j = 0; j < FN; j++){
        const size_t col = bn + wc * (FN * 16) + j * 16 + fr;
        float v = acc[i][j][r];
        if constexpr (EPI == 6){ float x = v + b2f(bias[col]); v = fmaxf(x, 0.f) + log1pf(__expf(-fabsf(x))); }
        if constexpr (EPI == 0 || EPI == 1) Cb[row * ldc + col] = f2b(v);
        else Cf[row * ldc + col] = v;
      }
    }
  }
}

// ---------------- xproj split-K reduce ----------------
__global__ __launch_bounds__(256) void xproj_reduce_kernel(
    const float* __restrict__ Pp, float* __restrict__ proj, u16* __restrict__ projb)
{
  const int idx = blockIdx.x * 256 + threadIdx.x;
  const int m = idx / 96, n = idx % 96;
  float s = 0.f;
  #pragma unroll
  for (int z = 0; z < 8; z++) s += Pp[(size_t)z * 2048 * 96 + idx];
  proj[idx] = s;
  if (n < 64) projb[(size_t)m * 64 + n] = f2b(s);
}

// ---------------- causal depthwise conv (D_CONV=4) + SiLU ----------------
__global__ __launch_bounds__(256) void conv_silu_kernel(
    const u16* __restrict__ xz, const void* __restrict__ cw, const void* __restrict__ cb,
    u16* __restrict__ u, const unsigned* __restrict__ Fg)
{
  const bool f32 = Fg[0] != 0;
  const int idx = blockIdx.x * 256 + threadIdx.x;
  const int c = idx & 2047;
  const int bt = idx >> 11;
  const int t = bt & 1023, b = bt >> 10;
  float acc = ldf(cb, c, f32);
  #pragma unroll
  for (int j = 0; j < 4; j++){
    int tt = t - 3 + j;
    if (tt >= 0) acc += b2f(xz[(size_t)(b * 1024 + tt) * 4096 + c]) * ldf(cw, c * 4 + j, f32);
  }
  u[(size_t)bt * 2048 + c] = f2b(acc * sigm(acc));
}

// ---------------- chunked selective scan ----------------
#define SCH 32
#define SNCH 32

__global__ __launch_bounds__(256) void scan_part1(
    const float* __restrict__ delta, const u16* __restrict__ u,
    const float* __restrict__ proj, const void* __restrict__ Alog,
    float* __restrict__ S, float* __restrict__ sumdl_o, const unsigned* __restrict__ Fg)
{
  const bool f32 = Fg[0] != 0;
  const int b = blockIdx.z, ch = blockIdx.y, d = blockIdx.x * 256 + threadIdx.x;
  float A[16], h[16];
  #pragma unroll
  for (int s = 0; s < 16; s++){ A[s] = -__expf(ldf(Alog, d * 16 + s, f32)); h[s] = 0.f; }
  __shared__ __align__(16) float Bsh[SCH][16];
  {
    int tc = threadIdx.x >> 3, j = (threadIdx.x & 7) * 2;
    *(float2*)&Bsh[tc][j] = *(const float2*)&proj[(size_t)(b * 1024 + ch * SCH + tc) * 96 + 64 + j];
  }
  __syncthreads();
  float sumdl = 0.f;
  for (int tt = 0; tt < SCH; tt++){
    const size_t m = (size_t)(b * 1024 + ch * SCH + tt);
    const float dl = delta[m * 2048 + d];
    const float du = dl * b2f(u[m * 2048 + d]);
    sumdl += dl;
    #pragma unroll
    for (int s = 0; s < 16; s++) h[s] = __expf(dl * A[s]) * h[s] + du * Bsh[tt][s];
  }
  #pragma unroll
  for (int s = 0; s < 16; s++) S[((size_t)(b * SNCH + ch) * 16 + s) * 2048 + d] = h[s];
  sumdl_o[(size_t)(b * SNCH + ch) * 2048 + d] = sumdl;
}

__global__ __launch_bounds__(256) void scan_combine(
    const float* __restrict__ S, const float* __restrict__ sumdl,
    const void* __restrict__ Alog, float* __restrict__ Hin, const unsigned* __restrict__ Fg)
{
  const bool f32 = Fg[0] != 0;
  const int idx = blockIdx.x * 256 + threadIdx.x;
  const int b = idx >> 11, d = idx & 2047;
  float A[16], h[16];
  #pragma unroll
  for (int s = 0; s < 16; s++){ A[s] = -__expf(ldf(Alog, d * 16 + s, f32)); h[s] = 0.f; }
  for (int ch = 0; ch < SNCH; ch++){
    const float sd = sumdl[(size_t)(b * SNCH + ch) * 2048 + d];
    #pragma unroll
    for (int s = 0; s < 16; s++){
      const size_t off = ((size_t)(b * SNCH + ch) * 16 + s) * 2048 + d;
      Hin[off] = h[s];
      h[s] = __expf(A[s] * sd) * h[s] + S[off];
    }
  }
}

__global__ __launch_bounds__(256) void scan_part2(
    const float* __restrict__ delta, const u16* __restrict__ u,
    const float* __restrict__ proj, const void* __restrict__ Alog,
    const void* __restrict__ Dp, const u16* __restrict__ xz,
    const float* __restrict__ Hin, u16* __restrict__ G, const unsigned* __restrict__ Fg)
{
  const bool f32 = Fg[0] != 0;
  const int b = blockIdx.z, ch = blockIdx.y, d = blockIdx.x * 256 + threadIdx.x;
  float A[16], h[16];
  #pragma unroll
  for (int s = 0; s < 16; s++){
    A[s] = -__expf(ldf(Alog, d * 16 + s, f32));
    h[s] = Hin[((size_t)(b * SNCH + ch) * 16 + s) * 2048 + d];
  }
  const float Dv = ldf(Dp, d, f32);
  __shared__ __align__(16) float BCs[SCH][32];
  {
    int tc = threadIdx.x >> 3, j = (threadIdx.x & 7) * 4;
    *(float4*)&BCs[tc][j] = *(const float4*)&proj[(size_t)(b * 1024 + ch * SCH + tc) * 96 + 64 + j];
  }
  __syncthreads();
  for (int tt = 0; tt < SCH; tt++){
    const size_t m = (size_t)(b * 1024 + ch * SCH + tt);
    const float dl = delta[m * 2048 + d];
    const float uv = b2f(u[m * 2048 + d]);
    const float du = dl * uv;
    float y = 0.f;
    #pragma unroll
    for (int s = 0; s < 16; s++){
      h[s] = __expf(dl * A[s]) * h[s] + du * BCs[tt][s];
      y += h[s] * BCs[tt][16 + s];
    }
    y += uv * Dv;
    const float r = b2f(xz[m * 4096 + 2048 + d]);
    G[m * 2048 + d] = f2b(y * (r * sigm(r)));
  }
}

// ---------------- V transpose: vb[token][1024ch] -> vtb[bh][64d][1024s] ----------------
__global__ __launch_bounds__(256) void vtrans_kernel(const u16* __restrict__ V, u16* __restrict__ Vt)
{
  __shared__ __align__(16) u16 T[64 * 64];
  const int bh = blockIdx.y, b = bh >> 4, hh = bh & 15;
  const int s0 = blockIdx.x * 64;
  const int tid = threadIdx.x;
  {
    int s = tid & 63, d0 = (tid >> 6) * 16;
    const u16* src = V + ((size_t)(b * 1024 + s0 + s)) * 1024 + hh * 64 + d0;
    u16x8 v0 = *(const u16x8*)src, v1 = *(const u16x8*)(src + 8);
    int byte0 = (s * 128 + d0 * 2) ^ ((s & 7) << 4);
    int byte1 = (s * 128 + d0 * 2 + 16) ^ ((s & 7) << 4);
    *(u16x8*)((char*)T + byte0) = v0;
    *(u16x8*)((char*)T + byte1) = v1;
  }
  __syncthreads();
  {
    int d = tid & 63, t0 = (tid >> 6) * 16;
    u16x8 w0, w1;
    #pragma unroll
    for (int j = 0; j < 8; j++){
      int r0 = t0 + j, r1 = t0 + 8 + j;
      w0[j] = *(const u16*)((char*)T + ((r0 * 128 + d * 2) ^ ((r0 & 7) << 4)));
      w1[j] = *(const u16*)((char*)T + ((r1 * 128 + d * 2) ^ ((r1 & 7) << 4)));
    }
    u16* dst = Vt + ((size_t)bh * 64 + d) * 1024 + s0 + t0;
    *(u16x8*)dst = w0;
    *(u16x8*)(dst + 8) = w1;
  }
}

// ---------------- multi-wave MFMA flash cross-attention, LDS-staged K/V ----------------
#define ASPL 2
__global__ __launch_bounds__(256) void attn_mw_kernel(
    const u16* __restrict__ Q, const u16* __restrict__ Kb, const u16* __restrict__ Vt,
    u16* __restrict__ Opart, float* __restrict__ Lpart)
{
  const int bh = blockIdx.y, b = bh >> 4, hh = bh & 15;
  const int z = blockIdx.z;
  const int tid = threadIdx.x, wave = tid >> 6, lane = tid & 63;
  const int fr = lane & 15, g = lane >> 4;
  const int q0 = blockIdx.x * 64 + wave * 16;
  __shared__ __align__(16) char Ks[64 * 128];
  __shared__ __align__(16) char Vs[64 * 128];
  __shared__ __align__(16) u16 Pl[4][1024];
  const u16* qp = Q + ((size_t)(b * 1024 + q0 + fr)) * 1024 + hh * 64 + g * 8;
  const bh8 aq0 = *(const bh8*)qp;
  const bh8 aq1 = *(const bh8*)(qp + 32);
  f32x4 oacc[4] = {};
  float lsum[4] = {};
  const u16* kbase = Kb + ((size_t)(b * 1024)) * 1024 + hh * 64;
  const u16* vbase = Vt + ((size_t)bh * 64) * 1024;
  const int srow = tid >> 2, sj = (tid & 3) * 2;
  for (int s0 = z * (1024 / ASPL); s0 < (z + 1) * (1024 / ASPL); s0 += 64){
    __syncthreads();
    {
      const u16* kr = kbase + (size_t)(s0 + srow) * 1024 + sj * 8;
      u16x8 k0 = *(const u16x8*)kr, k1 = *(const u16x8*)(kr + 8);
      *(u16x8*)&Ks[srow * 128 + ((sj * 16) ^ ((srow & 7) << 4))] = k0;
      *(u16x8*)&Ks[srow * 128 + (((sj + 1) * 16) ^ ((srow & 7) << 4))] = k1;
      const u16* vr = vbase + (size_t)srow * 1024 + s0 + sj * 8;
      u16x8 v0 = *(const u16x8*)vr, v1 = *(const u16x8*)(vr + 8);
      *(u16x8*)&Vs[srow * 128 + ((sj * 16) ^ ((srow & 7) << 4))] = v0;
      *(u16x8*)&Vs[srow * 128 + (((sj + 1) * 16) ^ ((srow & 7) << 4))] = v1;
    }
    __syncthreads();
    bh8 bk[4][2], bv[2][4];
    #pragma unroll
    for (int ct = 0; ct < 4; ct++){
      int row = 16 * ct + fr;
      #pragma unroll
      for (int ks = 0; ks < 2; ks++)
        bk[ct][ks] = *(const bh8*)&Ks[row * 128 + ((ks * 64 + g * 16) ^ ((row & 7) << 4))];
    }
    #pragma unroll
    for (int dt = 0; dt < 4; dt++){
      int row = 16 * dt + fr;
      #pragma unroll
      for (int ks = 0; ks < 2; ks++)
        bv[ks][dt] = *(const bh8*)&Vs[row * 128 + ((ks * 64 + g * 16) ^ ((row & 7) << 4))];
    }
    #pragma unroll
    for (int ct = 0; ct < 4; ct++){
      f32x4 zz = {};
      zz = __builtin_amdgcn_mfma_f32_16x16x32_bf16(aq0, bk[ct][0], zz, 0, 0, 0);
      zz = __builtin_amdgcn_mfma_f32_16x16x32_bf16(aq1, bk[ct][1], zz, 0, 0, 0);
      #pragma unroll
      for (int r = 0; r < 4; r++){
        float p = __expf(zz[r] * 0.125f);
        u16 pb = f2b(p);
        lsum[r] += b2f(pb);
        int row = 4 * g + r, col = 16 * ct + fr;
        *(u16*)((char*)&Pl[wave][0] + ((row * 128 + col * 2) ^ ((row & 7) << 4))) = pb;
      }
    }
    bh8 pa[2];
    #pragma unroll
    for (int ks = 0; ks < 2; ks++)
      pa[ks] = *(const bh8*)((char*)&Pl[wave][0] + ((fr * 128 + (ks * 32 + g * 8) * 2) ^ ((fr & 7) << 4)));
    #pragma unroll
    for (int dt = 0; dt < 4; dt++){
      oacc[dt] = __builtin_amdgcn_mfma_f32_16x16x32_bf16(pa[0], bv[0][dt], oacc[dt], 0, 0, 0);
      oacc[dt] = __builtin_amdgcn_mfma_f32_16x16x32_bf16(pa[1], bv[1][dt], oacc[dt], 0, 0, 0);
    }
  }
  #pragma unroll
  for (int r = 0; r < 4; r++){
    #pragma unroll
    for (int d2 = 1; d2 < 16; d2 <<= 1) lsum[r] += __shfl_xor(lsum[r], d2);
  }
  u16* opz = Opart + (size_t)z * 2097152;
  #pragma unroll
  for (int r = 0; r < 4; r++){
    const int tok = b * 1024 + q0 + 4 * g + r;
    #pragma unroll
    for (int dt = 0; dt < 4; dt++)
      opz[(size_t)tok * 1024 + hh * 64 + 16 * dt + fr] = f2b(oacc[dt][r]);
    if (fr == 0) Lpart[(size_t)z * 32768 + tok * 16 + hh] = lsum[r];
  }
}

__global__ __launch_bounds__(256) void attn_combine_kernel(
    const u16* __restrict__ Opart, const float* __restrict__ Lpart, u16* __restrict__ O)
{
  const int tok = blockIdx.x, tid = threadIdx.x;
  const int c = tid * 4, hh = c >> 6;
  float l = 0.f;
  #pragma unroll
  for (int z = 0; z < ASPL; z++) l += Lpart[(size_t)z * 32768 + tok * 16 + hh];
  float acc[4] = {};
  #pragma unroll
  for (int z = 0; z < ASPL; z++){
    u16x4 v = *(const u16x4*)&Opart[(size_t)z * 2097152 + (size_t)tok * 1024 + c];
    #pragma unroll
    for (int j = 0; j < 4; j++) acc[j] += b2f(v[j]);
  }
  const float inv = 1.f / l;
  u16x4 ov;
  #pragma unroll
  for (int j = 0; j < 4; j++) ov[j] = f2b(acc[j] * inv);
  *(u16x4*)&O[(size_t)tok * 1024 + c] = ov;
}

// ---------------- rmsnorm(a + b) * w ----------------
__global__ __launch_bounds__(256) void rmsnorm_kernel(
    const void* __restrict__ a, int aIn, const float* __restrict__ bsrc,
    const void* __restrict__ w, u16* __restrict__ outb, float* __restrict__ outf,
    void* __restrict__ dout, const unsigned* __restrict__ Fg)
{
  const bool f32 = Fg[0] != 0;
  const bool a32 = aIn ? f32 : true;
  const int row = blockIdx.x, tid = threadIdx.x;
  const size_t base = (size_t)row * 1024 + tid * 4;
  float v[4];
  if (a32){
    float4 t = *(const float4*)&((const float*)a)[base];
    v[0] = t.x; v[1] = t.y; v[2] = t.z; v[3] = t.w;
  } else {
    u16x4 t = *(const u16x4*)&((const u16*)a)[base];
    v[0] = b2f(t[0]); v[1] = b2f(t[1]); v[2] = b2f(t[2]); v[3] = b2f(t[3]);
  }
  float4 t2 = *(const float4*)&bsrc[base];
  v[0] += t2.x; v[1] += t2.y; v[2] += t2.z; v[3] += t2.w;
  float ss = v[0]*v[0] + v[1]*v[1] + v[2]*v[2] + v[3]*v[3];
  __shared__ float red[256];
  red[tid] = ss; __syncthreads();
  for (int s = 128; s > 0; s >>= 1){ if (tid < s) red[tid] += red[tid + s]; __syncthreads(); }
  const float scale = rsqrtf(red[0] * (1.f / 1024.f) + 1e-6f);
  float o[4];
  #pragma unroll
  for (int i = 0; i < 4; i++) o[i] = v[i] * scale * ldf(w, tid * 4 + i, f32);
  if (outb){
    u16x4 ov;
    #pragma unroll
    for (int i = 0; i < 4; i++) ov[i] = f2b(o[i]);
    *(u16x4*)&outb[base] = ov;
  }
  if (outf) *(float4*)&outf[base] = make_float4(o[0], o[1], o[2], o[3]);
  if (dout){
    if (f32) ((float*)dout)[base] = o[0], ((float*)dout)[base+1] = o[1], ((float*)dout)[base+2] = o[2], ((float*)dout)[base+3] = o[3];
    else {
      u16x4 ov;
      #pragma unroll
      for (int i = 0; i < 4; i++) ov[i] = f2b(o[i]);
      *(u16x4*)&((u16*)dout)[base] = ov;
    }
  }
}

// ---------------- per-token 8-bit absmax act quant ----------------
__global__ __launch_bounds__(256) void actquant_kernel(
    const void* __restrict__ in, int inF32, u16* __restrict__ q, float* __restrict__ srow, int N)
{
  const int row = blockIdx.x, tid = threadIdx.x;
  float amax = 0.f;
  for (int c = tid * 4; c < N; c += 1024){
    #pragma unroll
    for (int j = 0; j < 4; j++){
      float x = inF32 ? ((const float*)in)[(size_t)row * N + c + j] : b2f(((const u16*)in)[(size_t)row * N + c + j]);
      amax = fmaxf(amax, fabsf(x));
    }
  }
  __shared__ float red[256];
  red[tid] = amax; __syncthreads();
  for (int s = 128; s > 0; s >>= 1){ if (tid < s) red[tid] = fmaxf(red[tid], red[tid + s]); __syncthreads(); }
  const float s = fmaxf(red[0], 1e-5f) * (1.f / 127.f);
  if (tid == 0) srow[row] = s;
  for (int c = tid * 4; c < N; c += 1024){
    u16x4 ov;
    #pragma unroll
    for (int j = 0; j < 4; j++){
      float x = inF32 ? ((const float*)in)[(size_t)row * N + c + j] : b2f(((const u16*)in)[(size_t)row * N + c + j]);
      ov[j] = f2b(fminf(fmaxf(rintf(x / s), -128.f), 127.f));
    }
    *(u16x4*)&q[(size_t)row * N + c] = ov;
  }
}

// ---------------- BitNet weight quant ----------------
__global__ __launch_bounds__(256) void absmean_partial_kernel(
    const void* __restrict__ w, float* __restrict__ part, const unsigned* __restrict__ Fg)
{
  const bool f32 = Fg[0] != 0;
  const int tid = threadIdx.x;
  const size_t base = (size_t)blockIdx.x * 1024 + tid * 4;
  float ssum = 0.f;
  #pragma unroll
  for (int j = 0; j < 4; j++) ssum += fabsf(ldf(w, base + j, f32));
  __shared__ float red[256];
  red[tid] = ssum; __syncthreads();
  for (int s = 128; s > 0; s >>= 1){ if (tid < s) red[tid] += red[tid + s]; __syncthreads(); }
  if (tid == 0) part[blockIdx.x] = red[0];
}

__global__ __launch_bounds__(256) void absmean_final_kernel(
    const float* __restrict__ part, int n, float invc, float* __restrict__ out)
{
  const int tid = threadIdx.x;
  float ssum = 0.f;
  for (int i = tid; i < n; i += 256) ssum += part[i];
  __shared__ float red[256];
  red[tid] = ssum; __syncthreads();
  for (int s = 128; s > 0; s >>= 1){ if (tid < s) red[tid] += red[tid + s]; __syncthreads(); }
  if (tid == 0) out[0] = fmaxf(red[0] * invc, 1e-5f);
}

__global__ __launch_bounds__(256) void ternarize_kernel(
    const void* __restrict__ w, const float* __restrict__ sp, u16* __restrict__ t,
    const unsigned* __restrict__ Fg)
{
  const bool f32 = Fg[0] != 0;
  const float s = sp[0];
  const size_t base = ((size_t)blockIdx.x * 256 + threadIdx.x) * 4;
  u16x4 o;
  #pragma unroll
  for (int i = 0; i < 4; i++){
    float vv = fminf(fmaxf(rintf(ldf(w, base + i, f32) / s), -1.f), 1.f);
    o[i] = f2b(vv);
  }
  *(u16x4*)&t[base] = o;
}

extern "C" void kernel_launch(void* const* d_in, const int* in_sizes, int n_in,
                              void* d_out, int out_size, void* d_ws, size_t ws_size,
                              hipStream_t stream)
{
  const void* x      = d_in[0];
  const void* enc    = d_in[1];
  const void* in_w   = d_in[3];
  const void* conv_w = d_in[4];
  const void* conv_b = d_in[5];
  const void* xproj_w= d_in[6];
  const void* dt_w   = d_in[7];
  const void* dt_b   = d_in[8];
  const void* A_log  = d_in[9];
  const void* Dp     = d_in[10];
  const void* out_w  = d_in[11];
  const void* n1w    = d_in[12];
  const void* q_w = d_in[13]; const void* q_b = d_in[14];
  const void* k_w = d_in[15]; const void* k_b = d_in[16];
  const void* v_w = d_in[17]; const void* v_b = d_in[18];
  const void* o_w = d_in[19]; const void* o_b = d_in[20];
  const void* n2w = d_in[21];
  const void* w1  = d_in[22]; const void* b1 = d_in[23];
  const void* w2  = d_in[24]; const void* b2 = d_in[25];
  const void* n3w = d_in[26];

  char* ws = (char*)d_ws;
  const size_t MB = 1ull << 20;
  const size_t KB = 1024;
  float*    sw1  = (float*)(ws + 0);
  float*    sw2  = (float*)(ws + 16);
  unsigned* Fg   = (unsigned*)(ws + 64);
  float*    s1   = (float*)(ws + 4096);
  float*    s2   = (float*)(ws + 12288);
  float*    part = (float*)(ws + 20480);
  // phase A transients
  u16*   xz   = (u16*)  (ws + 1 * MB);    // 1-17
  u16*   u    = (u16*)  (ws + 17 * MB);   // 17-25
  float* proj = (float*)(ws + 25 * MB);   // 25-26
  float* delta= (float*)(ws + 26 * MB);   // 26-42
  float* Pp   = (float*)(ws + 42 * MB);   // 42-48
  u16*   projb= (u16*)  (ws + 48 * MB);   // 48-48.5
  u16*   G    = (u16*)  (ws + 42 * MB);   // 42-50
  float* Ssc  = (float*)(ws + 50 * MB);   // 50-58
  float* Hin  = (float*)(ws + 58 * MB);   // 58-66
  float* sdl  = (float*)(ws + 66 * MB);   // 66-66.5
  float* mout = (float*)(ws + 50 * MB);   // 50-58
  u16*   h1b  = (u16*)  (ws + 26 * MB);   // 26-30
  float* h1f  = (float*)(ws + 30 * MB);   // 30-38
  // phase B transients
  u16*   qb   = (u16*)  (ws + 1 * MB);    // 1-5
  u16*   kb   = (u16*)  (ws + 5 * MB);    // 5-9
  u16*   vb   = (u16*)  (ws + 9 * MB);    // 9-13
  u16*   vtb  = (u16*)  (ws + 38 * MB);   // 38-42
  u16*   Opart= (u16*)  (ws + 42 * MB);   // 42-50
  float* Lpart= (float*)(ws + 66 * MB);   // 66-66.25
  u16*   ao   = (u16*)  (ws + 13 * MB);   // 13-17
  float* aof  = (float*)(ws + 17 * MB);   // 17-25
  float* h2f  = (float*)(ws + 58 * MB);   // 58-66
  // phase C transients
  u16*   q1   = (u16*)  (ws + 1 * MB);    // 1-5
  u16*   t1   = (u16*)  (ws + 5 * MB);    // 5-13
  u16*   t2   = (u16*)  (ws + 50 * MB);   // 50-58
  u16*   gh   = (u16*)  (ws + 13 * MB);   // 13-29
  u16*   q2   = (u16*)  (ws + 29 * MB);   // 29-45
  float* fo   = (float*)(ws + 1 * MB);    // 1-9
  // persistent bf16 copies (68-97)
  u16* xb       = (u16*)(ws + 68 * MB);
  u16* encb     = (u16*)(ws + 72 * MB);
  u16* in_wb    = (u16*)(ws + 76 * MB);
  u16* out_wb   = (u16*)(ws + 84 * MB);
  u16* q_wb     = (u16*)(ws + 88 * MB);
  u16* k_wb     = (u16*)(ws + 90 * MB);
  u16* v_wb     = (u16*)(ws + 92 * MB);
  u16* o_wb     = (u16*)(ws + 94 * MB);
  u16* xproj_wb = (u16*)(ws + 96 * MB);
  u16* dt_wb    = (u16*)(ws + 96 * MB + 512 * KB);
  u16* dt_bb    = (u16*)(ws + 96 * MB + 768 * KB);
  u16* q_bb     = (u16*)(ws + 96 * MB + 776 * KB);
  u16* k_bb     = (u16*)(ws + 96 * MB + 780 * KB);
  u16* v_bb     = (u16*)(ws + 96 * MB + 784 * KB);
  u16* o_bb     = (u16*)(ws + 96 * MB + 788 * KB);
  u16* b1b      = (u16*)(ws + 96 * MB + 792 * KB);
  u16* b2b      = (u16*)(ws + 96 * MB + 808 * KB);

  dim3 blk(256);
  detect_kernel<<<dim3(1), blk, 0, stream>>>(x, Fg);

  // 0b. convert all GEMM-facing externals to bf16
  {
    CvtJobs jobs;
    const void* srcs[NCVT] = { x, enc, in_w, out_w, q_w, k_w, v_w, o_w, xproj_w, dt_w,
                               dt_b, q_b, k_b, v_b, o_b, b1, b2 };
    u16* dsts[NCVT] = { xb, encb, in_wb, out_wb, q_wb, k_wb, v_wb, o_wb, xproj_wb, dt_wb,
                        dt_bb, q_bb, k_bb, v_bb, o_bb, b1b, b2b };
    int ns[NCVT] = { 2097152, 2097152, 4194304, 2097152, 1048576, 1048576, 1048576, 1048576,
                     196608, 131072, 2048, 1024, 1024, 1024, 1024, 4096, 1024 };
    int bo = 0;
    for (int j = 0; j < NCVT; j++){
      jobs.src[j] = srcs[j]; jobs.dst[j] = dsts[j]; jobs.n[j] = ns[j];
      jobs.blk_off[j] = bo;
      bo += (ns[j] / 8 + 255) / 256;
    }
    jobs.blk_off[NCVT] = bo;
    convert_kernel<<<dim3(bo), blk, 0, stream>>>(jobs, Fg);
  }

  // 1. xz = x @ in_w^T  (gl, 128x128)
  gemm_gl<0,4,4><<<dim3(32, 16), blk, 0, stream>>>(xb, in_wb, xz, 2048, 4096, 1024, 1024, 1024, 4096, nullptr, nullptr, nullptr);
  // 2. conv + SiLU
  conv_silu_kernel<<<dim3(16384), blk, 0, stream>>>(xz, conv_w, conv_b, u, Fg);
  // 3. proj = u @ xproj_w^T (split-K=8) + reduce
  gemm16<3,2,3,2,2><<<dim3(1, 32, 8), blk, 0, stream>>>(u, xproj_wb, Pp, 2048, 96, 256, 2048, 2048, 96, nullptr, nullptr, nullptr);
  xproj_reduce_kernel<<<dim3(768), blk, 0, stream>>>(Pp, proj, projb);
  // 4. delta = softplus(projb @ dt_w^T + dt_b)
  gemm16<6,2,2,2,2><<<dim3(32, 32), blk, 0, stream>>>(projb, dt_wb, delta, 2048, 2048, 64, 64, 64, 2048, dt_bb, nullptr, nullptr);
  // 5. chunked scan
  scan_part1<<<dim3(8, SNCH, 2), blk, 0, stream>>>(delta, u, proj, A_log, Ssc, sdl, Fg);
  scan_combine<<<dim3(16), blk, 0, stream>>>(Ssc, sdl, A_log, Hin, Fg);
  scan_part2<<<dim3(8, SNCH, 2), blk, 0, stream>>>(delta, u, proj, A_log, Dp, xz, Hin, G, Fg);
  // 6. mamba_out = G @ out_w^T  (gl, 64x64)
  gemm_gl<3,2,2><<<dim3(16, 32), blk, 0, stream>>>(G, out_wb, mout, 2048, 1024, 2048, 2048, 2048, 1024, nullptr, nullptr, nullptr);
  // 7. h1 = rmsnorm(x + mamba_out)
  rmsnorm_kernel<<<dim3(2048), blk, 0, stream>>>(x, 1, mout, n1w, h1b, h1f, nullptr, Fg);
  // 8. q/k/v projections (gl, 64x64)
  gemm_gl<1,2,2><<<dim3(16, 32), blk, 0, stream>>>(h1b, q_wb, qb, 2048, 1024, 1024, 1024, 1024, 1024, q_bb, nullptr, nullptr);
  gemm_gl<1,2,2><<<dim3(16, 32), blk, 0, stream>>>(encb, k_wb, kb, 2048, 1024, 1024, 1024, 1024, 1024, k_bb, nullptr, nullptr);
  gemm_gl<1,2,2><<<dim3(16, 32), blk, 0, stream>>>(encb, v_wb, vb, 2048, 1024, 1024, 1024, 1024, 1024, v_bb, nullptr, nullptr);
  // 8b. V transpose
  vtrans_kernel<<<dim3(16, 32), blk, 0, stream>>>(vb, vtb);
  // 9. multi-wave LDS-staged flash attention + combine
  attn_mw_kernel<<<dim3(16, 32, ASPL), blk, 0, stream>>>(qb, kb, vtb, Opart, Lpart);
  attn_combine_kernel<<<dim3(2048), blk, 0, stream>>>(Opart, Lpart, ao);
  // 10. o projection (gl, 64x64)
  gemm_gl<2,2,2><<<dim3(16, 32), blk, 0, stream>>>(ao, o_wb, aof, 2048, 1024, 1024, 1024, 1024, 1024, o_bb, nullptr, nullptr);
  // 11. h2 = rmsnorm(h1 + attn)
  rmsnorm_kernel<<<dim3(2048), blk, 0, stream>>>(h1f, 0, aof, n2w, nullptr, h2f, nullptr, Fg);
  // 12. act_quant(h2)
  actquant_kernel<<<dim3(2048), blk, 0, stream>>>(h2f, 1, q1, s1, 1024);
  // 13. weight_quant(w1), weight_quant(w2)
  absmean_partial_kernel<<<dim3(4096), blk, 0, stream>>>(w1, part, Fg);
  absmean_final_kernel<<<dim3(1), blk, 0, stream>>>(part, 4096, 1.f / 4194304.f, sw1);
  ternarize_kernel<<<dim3(4096), blk, 0, stream>>>(w1, sw1, t1, Fg);
  absmean_partial_kernel<<<dim3(4096), blk, 0, stream>>>(w2, part, Fg);
  absmean_final_kernel<<<dim3(1), blk, 0, stream>>>(part, 4096, 1.f / 4194304.f, sw2);
  ternarize_kernel<<<dim3(4096), blk, 0, stream>>>(w2, sw2, t2, Fg);
  // 14. ffn hidden = gelu(q1 @ t1^T * s1*sw1 + b1) -> bf16  (gl, 128x128)
  gemm_gl<4,4,4><<<dim3(32, 16), blk, 0, stream>>>(q1, t1, gh, 2048, 4096, 1024, 1024, 1024, 4096, b1b, s1, sw1);
  // 15. act_quant(gh)
  actquant_kernel<<<dim3(2048), blk, 0, stream>>>(gh, 0, q2, s2, 4096);
  // 16. ffn out = q2 @ t2^T * s2*sw2 + b2  (gl, 64x64)
  gemm_gl<5,2,2><<<dim3(16, 32), blk, 0, stream>>>(q2, t2, fo, 2048, 1024, 4096, 4096, 4096, 1024, b2b, s2, sw2);
  // 17. out = rmsnorm(h2 + ffn) -> d_out
  rmsnorm_kernel<<<dim3(2048), blk, 0, stream>>>(h2f, 0, fo, n3w, nullptr, nullptr, d_out, Fg);
}

// Round 11
// 423.136 us; speedup vs baseline: 1.1923x; 1.0243x over previous
//
#include <hip/hip_runtime.h>
#include <math.h>

#define DEV __device__ __forceinline__
using u16 = unsigned short;
typedef __bf16 bh8 __attribute__((ext_vector_type(8)));
typedef float f32x4 __attribute__((ext_vector_type(4)));
typedef u16 u16x8 __attribute__((ext_vector_type(8)));
typedef u16 u16x4 __attribute__((ext_vector_type(4)));

DEV float b2f(u16 x){ unsigned u = ((unsigned)x) << 16; float f; __builtin_memcpy(&f, &u, 4); return f; }
DEV u16 f2b(float f){ unsigned u; __builtin_memcpy(&u, &f, 4); return (u16)((u + 0x7fffu + ((u >> 16) & 1u)) >> 16); }
DEV float sigm(float x){ return 1.f / (1.f + __expf(-x)); }
DEV float ldf(const void* p, size_t i, bool f32){ return f32 ? ((const float*)p)[i] : b2f(((const u16*)p)[i]); }

// ---------------- dtype detect ----------------
__global__ __launch_bounds__(256) void detect_kernel(const void* x, unsigned* flag)
{
  const int tid = threadIdx.x;
  const u16* p = (const u16*)x;
  int sane = 0;
  #pragma unroll
  for (int j = 0; j < 8; j++){
    u16 v = p[(size_t)(tid * 8 + j) * 2];
    int e = (v >> 7) & 0xFF;
    sane += (e >= 0x60 && e <= 0x8F) ? 1 : 0;
  }
  __shared__ int red[256];
  red[tid] = sane; __syncthreads();
  for (int s = 128; s > 0; s >>= 1){ if (tid < s) red[tid] += red[tid + s]; __syncthreads(); }
  if (tid == 0) flag[0] = (red[0] < 1200) ? 1u : 0u;
}

// ---------------- batch convert external -> bf16 ws ----------------
#define NCVT 17
struct CvtJobs {
  const void* src[NCVT];
  u16* dst[NCVT];
  int n[NCVT];
  int blk_off[NCVT + 1];
};
__global__ __launch_bounds__(256) void convert_kernel(CvtJobs jobs, const unsigned* __restrict__ Fg)
{
  const bool f32 = Fg[0] != 0;
  const int bx = blockIdx.x;
  int j = 0;
  while (bx >= jobs.blk_off[j + 1]) j++;
  const int e = (bx - jobs.blk_off[j]) * 2048 + threadIdx.x * 8;
  if (e >= jobs.n[j]) return;
  if (f32){
    const float* s = (const float*)jobs.src[j] + e;
    u16x8 o;
    #pragma unroll
    for (int i = 0; i < 8; i++) o[i] = f2b(s[i]);
    *(u16x8*)(jobs.dst[j] + e) = o;
  } else {
    *(u16x8*)(jobs.dst[j] + e) = *(const u16x8*)((const u16*)jobs.src[j] + e);
  }
}

// ---------------- reg-staged BK=64 swizzled MFMA GEMM (the proven workhorse) ----------------
// C[M,N] = A[M,K] @ W[N,K]^T. EPI: 0 bf16  1 bf16+bias  2 f32+bias  3 f32 (split-K partial)
// 4 bf16=gelu(acc*rs*ws+bias)  5 f32=acc*rs*ws+bias  6 f32=softplus(acc+bias)
// SPLITC: N=3072 fused QKV -> route 1024-col groups to Cv/Cv1/Cv2 (each ldc=1024).
template<int EPI, int FM, int FN, int WR, int WC, bool SPLITC>
__global__ __launch_bounds__(256) void gemm16(
    const u16* __restrict__ A, const u16* __restrict__ W, void* __restrict__ Cv,
    int M, int N, int K, int lda, int ldb, int ldc,
    const u16* __restrict__ bias, const float* __restrict__ rowscale,
    const float* __restrict__ wscale, void* __restrict__ Cv1, void* __restrict__ Cv2)
{
  constexpr int BM = WR * FM * 16, BN = WC * FN * 16;
  __shared__ __align__(16) char As[BM * 128];
  __shared__ __align__(16) char Bs[BN * 128];
  const int tid = threadIdx.x, wave = tid >> 6, lane = tid & 63;
  const int wr = wave / WC, wc = wave % WC, fr = lane & 15, g = lane >> 4;
  const size_t bm = (size_t)blockIdx.y * BM, bn = (size_t)blockIdx.x * BN;
  const int kbase = blockIdx.z * K;
  f32x4 acc[FM][FN] = {};
  constexpr int ACH = BM / 32, BCH = BN / 32;
  u16x8 areg[ACH], breg[BCH];
  auto fetch = [&](int k0){
    #pragma unroll
    for (int c = 0; c < ACH; c++){
      int li = tid + c * 256;
      areg[c] = *(const u16x8*)&A[(bm + (li >> 3)) * (size_t)lda + kbase + k0 + ((li & 7) << 3)];
    }
    #pragma unroll
    for (int c = 0; c < BCH; c++){
      int li = tid + c * 256;
      breg[c] = *(const u16x8*)&W[(bn + (li >> 3)) * (size_t)ldb + kbase + k0 + ((li & 7) << 3)];
    }
  };
  fetch(0);
  for (int k0 = 0; k0 < K; k0 += 64){
    __syncthreads();
    #pragma unroll
    for (int c = 0; c < ACH; c++){
      int li = tid + c * 256, row = li >> 3, j = li & 7;
      *(u16x8*)&As[row * 128 + ((j * 16) ^ ((row & 7) << 4))] = areg[c];
    }
    #pragma unroll
    for (int c = 0; c < BCH; c++){
      int li = tid + c * 256, row = li >> 3, j = li & 7;
      *(u16x8*)&Bs[row * 128 + ((j * 16) ^ ((row & 7) << 4))] = breg[c];
    }
    __syncthreads();
    if (k0 + 64 < K) fetch(k0 + 64);
    bh8 af[2][FM], bf[2][FN];
    #pragma unroll
    for (int ks = 0; ks < 2; ks++){
      #pragma unroll
      for (int i = 0; i < FM; i++){
        int row = wr * (FM * 16) + i * 16 + fr;
        af[ks][i] = *(const bh8*)&As[row * 128 + ((ks * 64 + g * 16) ^ ((row & 7) << 4))];
      }
      #pragma unroll
      for (int j = 0; j < FN; j++){
        int row = wc * (FN * 16) + j * 16 + fr;
        bf[ks][j] = *(const bh8*)&Bs[row * 128 + ((ks * 64 + g * 16) ^ ((row & 7) << 4))];
      }
    }
    #pragma unroll
    for (int ks = 0; ks < 2; ks++)
      #pragma unroll
      for (int i = 0; i < FM; i++)
        #pragma unroll
        for (int j = 0; j < FN; j++)
          acc[i][j] = __builtin_amdgcn_mfma_f32_16x16x32_bf16(af[ks][i], bf[ks][j], acc[i][j], 0, 0, 0);
  }
  float wsc = 0.f;
  if constexpr (EPI == 4 || EPI == 5) wsc = wscale[0];
  u16* Cb = (u16*)Cv;
  float* Cf = (float*)Cv + (size_t)blockIdx.z * M * ldc;
  #pragma unroll
  for (int i = 0; i < FM; i++){
    #pragma unroll
    for (int r = 0; r < 4; r++){
      const size_t row = bm + wr * (FM * 16) + i * 16 + g * 4 + r;
      float rs = 0.f;
      if constexpr (EPI == 4 || EPI == 5) rs = rowscale[row] * wsc;
      #pragma unroll
      for (int j = 0; j < FN; j++){
        const size_t col = bn + wc * (FN * 16) + j * 16 + fr;
        float v = acc[i][j][r];
        if constexpr (EPI == 1 || EPI == 2) v += b2f(bias[col]);
        if constexpr (EPI == 4 || EPI == 5) v = v * rs + b2f(bias[col]);
        if constexpr (EPI == 4){ float x = v; v = 0.5f * x * (1.f + tanhf(0.7978845608f * (x + 0.044715f * x * x * x))); }
        if constexpr (EPI == 6){ float x = v + b2f(bias[col]); v = fmaxf(x, 0.f) + log1pf(__expf(-fabsf(x))); }
        if constexpr (EPI == 0 || EPI == 1 || EPI == 4){
          u16* CbX = Cb; size_t cc = col;
          if constexpr (SPLITC){
            int wq = (int)(col >> 10);
            CbX = wq == 0 ? Cb : (wq == 1 ? (u16*)Cv1 : (u16*)Cv2);
            cc = col & 1023;
          }
          CbX[row * ldc + cc] = f2b(v);
        } else Cf[row * ldc + col] = v;
      }
    }
  }
}

// ---------------- split-K combines ----------------
__global__ __launch_bounds__(256) void add2_kernel(const float* __restrict__ P, float* __restrict__ out)
{
  const size_t i = ((size_t)blockIdx.x * 256 + threadIdx.x) * 4;
  float4 a = *(const float4*)&P[i];
  float4 b = *(const float4*)&P[2097152 + i];
  *(float4*)&out[i] = make_float4(a.x + b.x, a.y + b.y, a.z + b.z, a.w + b.w);
}

__global__ __launch_bounds__(256) void ffn2_combine_kernel(
    const float* __restrict__ P, const float* __restrict__ s2, const float* __restrict__ sw2,
    const u16* __restrict__ b2b, float* __restrict__ fo)
{
  const size_t i = ((size_t)blockIdx.x * 256 + threadIdx.x) * 4;
  const int row = (int)(i >> 10), col = (int)(i & 1023);
  float4 a = *(const float4*)&P[i];
  float4 b = *(const float4*)&P[2097152 + i];
  const float rs = s2[row] * sw2[0];
  float4 o;
  o.x = (a.x + b.x) * rs + b2f(b2b[col]);
  o.y = (a.y + b.y) * rs + b2f(b2b[col + 1]);
  o.z = (a.z + b.z) * rs + b2f(b2b[col + 2]);
  o.w = (a.w + b.w) * rs + b2f(b2b[col + 3]);
  *(float4*)&fo[i] = o;
}

// ---------------- xproj split-K reduce ----------------
__global__ __launch_bounds__(256) void xproj_reduce_kernel(
    const float* __restrict__ Pp, float* __restrict__ proj, u16* __restrict__ projb)
{
  const int idx = blockIdx.x * 256 + threadIdx.x;
  const int m = idx / 96, n = idx % 96;
  float s = 0.f;
  #pragma unroll
  for (int z = 0; z < 8; z++) s += Pp[(size_t)z * 2048 * 96 + idx];
  proj[idx] = s;
  if (n < 64) projb[(size_t)m * 64 + n] = f2b(s);
}

// ---------------- causal depthwise conv (D_CONV=4) + SiLU ----------------
__global__ __launch_bounds__(256) void conv_silu_kernel(
    const u16* __restrict__ xz, const void* __restrict__ cw, const void* __restrict__ cb,
    u16* __restrict__ u, const unsigned* __restrict__ Fg)
{
  const bool f32 = Fg[0] != 0;
  const int idx = blockIdx.x * 256 + threadIdx.x;
  const int c = idx & 2047;
  const int bt = idx >> 11;
  const int t = bt & 1023, b = bt >> 10;
  float acc = ldf(cb, c, f32);
  #pragma unroll
  for (int j = 0; j < 4; j++){
    int tt = t - 3 + j;
    if (tt >= 0) acc += b2f(xz[(size_t)(b * 1024 + tt) * 4096 + c]) * ldf(cw, c * 4 + j, f32);
  }
  u[(size_t)bt * 2048 + c] = f2b(acc * sigm(acc));
}

// ---------------- chunked selective scan ----------------
#define SCH 32
#define SNCH 32

__global__ __launch_bounds__(256) void scan_part1(
    const float* __restrict__ delta, const u16* __restrict__ u,
    const float* __restrict__ proj, const void* __restrict__ Alog,
    float* __restrict__ S, float* __restrict__ sumdl_o, const unsigned* __restrict__ Fg)
{
  const bool f32 = Fg[0] != 0;
  const int b = blockIdx.z, ch = blockIdx.y, d = blockIdx.x * 256 + threadIdx.x;
  float A[16], h[16];
  #pragma unroll
  for (int s = 0; s < 16; s++){ A[s] = -__expf(ldf(Alog, d * 16 + s, f32)); h[s] = 0.f; }
  __shared__ __align__(16) float Bsh[SCH][16];
  {
    int tc = threadIdx.x >> 3, j = (threadIdx.x & 7) * 2;
    *(float2*)&Bsh[tc][j] = *(const float2*)&proj[(size_t)(b * 1024 + ch * SCH + tc) * 96 + 64 + j];
  }
  __syncthreads();
  float sumdl = 0.f;
  for (int tt = 0; tt < SCH; tt++){
    const size_t m = (size_t)(b * 1024 + ch * SCH + tt);
    const float dl = delta[m * 2048 + d];
    const float du = dl * b2f(u[m * 2048 + d]);
    sumdl += dl;
    #pragma unroll
    for (int s = 0; s < 16; s++) h[s] = __expf(dl * A[s]) * h[s] + du * Bsh[tt][s];
  }
  #pragma unroll
  for (int s = 0; s < 16; s++) S[((size_t)(b * SNCH + ch) * 16 + s) * 2048 + d] = h[s];
  sumdl_o[(size_t)(b * SNCH + ch) * 2048 + d] = sumdl;
}

__global__ __launch_bounds__(256) void scan_combine(
    const float* __restrict__ S, const float* __restrict__ sumdl,
    const void* __restrict__ Alog, float* __restrict__ Hin, const unsigned* __restrict__ Fg)
{
  const bool f32 = Fg[0] != 0;
  const int idx = blockIdx.x * 256 + threadIdx.x;
  const int b = idx >> 11, d = idx & 2047;
  float A[16], h[16];
  #pragma unroll
  for (int s = 0; s < 16; s++){ A[s] = -__expf(ldf(Alog, d * 16 + s, f32)); h[s] = 0.f; }
  for (int ch = 0; ch < SNCH; ch++){
    const float sd = sumdl[(size_t)(b * SNCH + ch) * 2048 + d];
    #pragma unroll
    for (int s = 0; s < 16; s++){
      const size_t off = ((size_t)(b * SNCH + ch) * 16 + s) * 2048 + d;
      Hin[off] = h[s];
      h[s] = __expf(A[s] * sd) * h[s] + S[off];
    }
  }
}

__global__ __launch_bounds__(256) void scan_part2(
    const float* __restrict__ delta, const u16* __restrict__ u,
    const float* __restrict__ proj, const void* __restrict__ Alog,
    const void* __restrict__ Dp, const u16* __restrict__ xz,
    const float* __restrict__ Hin, u16* __restrict__ G, const unsigned* __restrict__ Fg)
{
  const bool f32 = Fg[0] != 0;
  const int b = blockIdx.z, ch = blockIdx.y, d = blockIdx.x * 256 + threadIdx.x;
  float A[16], h[16];
  #pragma unroll
  for (int s = 0; s < 16; s++){
    A[s] = -__expf(ldf(Alog, d * 16 + s, f32));
    h[s] = Hin[((size_t)(b * SNCH + ch) * 16 + s) * 2048 + d];
  }
  const float Dv = ldf(Dp, d, f32);
  __shared__ __align__(16) float BCs[SCH][32];
  {
    int tc = threadIdx.x >> 3, j = (threadIdx.x & 7) * 4;
    *(float4*)&BCs[tc][j] = *(const float4*)&proj[(size_t)(b * 1024 + ch * SCH + tc) * 96 + 64 + j];
  }
  __syncthreads();
  for (int tt = 0; tt < SCH; tt++){
    const size_t m = (size_t)(b * 1024 + ch * SCH + tt);
    const float dl = delta[m * 2048 + d];
    const float uv = b2f(u[m * 2048 + d]);
    const float du = dl * uv;
    float y = 0.f;
    #pragma unroll
    for (int s = 0; s < 16; s++){
      h[s] = __expf(dl * A[s]) * h[s] + du * BCs[tt][s];
      y += h[s] * BCs[tt][16 + s];
    }
    y += uv * Dv;
    const float r = b2f(xz[m * 4096 + 2048 + d]);
    G[m * 2048 + d] = f2b(y * (r * sigm(r)));
  }
}

// ---------------- V transpose: vb[token][1024ch] -> vtb[bh][64d][1024s] ----------------
__global__ __launch_bounds__(256) void vtrans_kernel(const u16* __restrict__ V, u16* __restrict__ Vt)
{
  __shared__ __align__(16) u16 T[64 * 64];
  const int bh = blockIdx.y, b = bh >> 4, hh = bh & 15;
  const int s0 = blockIdx.x * 64;
  const int tid = threadIdx.x;
  {
    int s = tid & 63, d0 = (tid >> 6) * 16;
    const u16* src = V + ((size_t)(b * 1024 + s0 + s)) * 1024 + hh * 64 + d0;
    u16x8 v0 = *(const u16x8*)src, v1 = *(const u16x8*)(src + 8);
    int byte0 = (s * 128 + d0 * 2) ^ ((s & 7) << 4);
    int byte1 = (s * 128 + d0 * 2 + 16) ^ ((s & 7) << 4);
    *(u16x8*)((char*)T + byte0) = v0;
    *(u16x8*)((char*)T + byte1) = v1;
  }
  __syncthreads();
  {
    int d = tid & 63, t0 = (tid >> 6) * 16;
    u16x8 w0, w1;
    #pragma unroll
    for (int j = 0; j < 8; j++){
      int r0 = t0 + j, r1 = t0 + 8 + j;
      w0[j] = *(const u16*)((char*)T + ((r0 * 128 + d * 2) ^ ((r0 & 7) << 4)));
      w1[j] = *(const u16*)((char*)T + ((r1 * 128 + d * 2) ^ ((r1 & 7) << 4)));
    }
    u16* dst = Vt + ((size_t)bh * 64 + d) * 1024 + s0 + t0;
    *(u16x8*)dst = w0;
    *(u16x8*)(dst + 8) = w1;
  }
}

// ---------------- multi-wave MFMA flash cross-attention, LDS-staged K/V ----------------
#define ASPL 2
__global__ __launch_bounds__(256) void attn_mw_kernel(
    const u16* __restrict__ Q, const u16* __restrict__ Kb, const u16* __restrict__ Vt,
    u16* __restrict__ Opart, float* __restrict__ Lpart)
{
  const int bh = blockIdx.y, b = bh >> 4, hh = bh & 15;
  const int z = blockIdx.z;
  const int tid = threadIdx.x, wave = tid >> 6, lane = tid & 63;
  const int fr = lane & 15, g = lane >> 4;
  const int q0 = blockIdx.x * 64 + wave * 16;
  __shared__ __align__(16) char Ks[64 * 128];
  __shared__ __align__(16) char Vs[64 * 128];
  __shared__ __align__(16) u16 Pl[4][1024];
  const u16* qp = Q + ((size_t)(b * 1024 + q0 + fr)) * 1024 + hh * 64 + g * 8;
  const bh8 aq0 = *(const bh8*)qp;
  const bh8 aq1 = *(const bh8*)(qp + 32);
  f32x4 oacc[4] = {};
  float lsum[4] = {};
  const u16* kbase = Kb + ((size_t)(b * 1024)) * 1024 + hh * 64;
  const u16* vbase = Vt + ((size_t)bh * 64) * 1024;
  const int srow = tid >> 2, sj = (tid & 3) * 2;
  for (int s0 = z * (1024 / ASPL); s0 < (z + 1) * (1024 / ASPL); s0 += 64){
    __syncthreads();
    {
      const u16* kr = kbase + (size_t)(s0 + srow) * 1024 + sj * 8;
      u16x8 k0 = *(const u16x8*)kr, k1 = *(const u16x8*)(kr + 8);
      *(u16x8*)&Ks[srow * 128 + ((sj * 16) ^ ((srow & 7) << 4))] = k0;
      *(u16x8*)&Ks[srow * 128 + (((sj + 1) * 16) ^ ((srow & 7) << 4))] = k1;
      const u16* vr = vbase + (size_t)srow * 1024 + s0 + sj * 8;
      u16x8 v0 = *(const u16x8*)vr, v1 = *(const u16x8*)(vr + 8);
      *(u16x8*)&Vs[srow * 128 + ((sj * 16) ^ ((srow & 7) << 4))] = v0;
      *(u16x8*)&Vs[srow * 128 + (((sj + 1) * 16) ^ ((srow & 7) << 4))] = v1;
    }
    __syncthreads();
    bh8 bk[4][2], bv[2][4];
    #pragma unroll
    for (int ct = 0; ct < 4; ct++){
      int row = 16 * ct + fr;
      #pragma unroll
      for (int ks = 0; ks < 2; ks++)
        bk[ct][ks] = *(const bh8*)&Ks[row * 128 + ((ks * 64 + g * 16) ^ ((row & 7) << 4))];
    }
    #pragma unroll
    for (int dt = 0; dt < 4; dt++){
      int row = 16 * dt + fr;
      #pragma unroll
      for (int ks = 0; ks < 2; ks++)
        bv[ks][dt] = *(const bh8*)&Vs[row * 128 + ((ks * 64 + g * 16) ^ ((row & 7) << 4))];
    }
    #pragma unroll
    for (int ct = 0; ct < 4; ct++){
      f32x4 zz = {};
      zz = __builtin_amdgcn_mfma_f32_16x16x32_bf16(aq0, bk[ct][0], zz, 0, 0, 0);
      zz = __builtin_amdgcn_mfma_f32_16x16x32_bf16(aq1, bk[ct][1], zz, 0, 0, 0);
      #pragma unroll
      for (int r = 0; r < 4; r++){
        float p = __expf(zz[r] * 0.125f);
        u16 pb = f2b(p);
        lsum[r] += b2f(pb);
        int row = 4 * g + r, col = 16 * ct + fr;
        *(u16*)((char*)&Pl[wave][0] + ((row * 128 + col * 2) ^ ((row & 7) << 4))) = pb;
      }
    }
    bh8 pa[2];
    #pragma unroll
    for (int ks = 0; ks < 2; ks++)
      pa[ks] = *(const bh8*)((char*)&Pl[wave][0] + ((fr * 128 + (ks * 32 + g * 8) * 2) ^ ((fr & 7) << 4)));
    #pragma unroll
    for (int dt = 0; dt < 4; dt++){
      oacc[dt] = __builtin_amdgcn_mfma_f32_16x16x32_bf16(pa[0], bv[0][dt], oacc[dt], 0, 0, 0);
      oacc[dt] = __builtin_amdgcn_mfma_f32_16x16x32_bf16(pa[1], bv[1][dt], oacc[dt], 0, 0, 0);
    }
  }
  #pragma unroll
  for (int r = 0; r < 4; r++){
    #pragma unroll
    for (int d2 = 1; d2 < 16; d2 <<= 1) lsum[r] += __shfl_xor(lsum[r], d2);
  }
  u16* opz = Opart + (size_t)z * 2097152;
  #pragma unroll
  for (int r = 0; r < 4; r++){
    const int tok = b * 1024 + q0 + 4 * g + r;
    #pragma unroll
    for (int dt = 0; dt < 4; dt++)
      opz[(size_t)tok * 1024 + hh * 64 + 16 * dt + fr] = f2b(oacc[dt][r]);
    if (fr == 0) Lpart[(size_t)z * 32768 + tok * 16 + hh] = lsum[r];
  }
}

__global__ __launch_bounds__(256) void attn_combine_kernel(
    const u16* __restrict__ Opart, const float* __restrict__ Lpart, u16* __restrict__ O)
{
  const int tok = blockIdx.x, tid = threadIdx.x;
  const int c = tid * 4, hh = c >> 6;
  float l = 0.f;
  #pragma unroll
  for (int z = 0; z < ASPL; z++) l += Lpart[(size_t)z * 32768 + tok * 16 + hh];
  float acc[4] = {};
  #pragma unroll
  for (int z = 0; z < ASPL; z++){
    u16x4 v = *(const u16x4*)&Opart[(size_t)z * 2097152 + (size_t)tok * 1024 + c];
    #pragma unroll
    for (int j = 0; j < 4; j++) acc[j] += b2f(v[j]);
  }
  const float inv = 1.f / l;
  u16x4 ov;
  #pragma unroll
  for (int j = 0; j < 4; j++) ov[j] = f2b(acc[j] * inv);
  *(u16x4*)&O[(size_t)tok * 1024 + c] = ov;
}

// ---------------- rmsnorm(a + b) * w ----------------
__global__ __launch_bounds__(256) void rmsnorm_kernel(
    const void* __restrict__ a, int aIn, const float* __restrict__ bsrc,
    const void* __restrict__ w, u16* __restrict__ outb, float* __restrict__ outf,
    void* __restrict__ dout, const unsigned* __restrict__ Fg)
{
  const bool f32 = Fg[0] != 0;
  const bool a32 = aIn ? f32 : true;
  const int row = blockIdx.x, tid = threadIdx.x;
  const size_t base = (size_t)row * 1024 + tid * 4;
  float v[4];
  if (a32){
    float4 t = *(const float4*)&((const float*)a)[base];
    v[0] = t.x; v[1] = t.y; v[2] = t.z; v[3] = t.w;
  } else {
    u16x4 t = *(const u16x4*)&((const u16*)a)[base];
    v[0] = b2f(t[0]); v[1] = b2f(t[1]); v[2] = b2f(t[2]); v[3] = b2f(t[3]);
  }
  float4 t2 = *(const float4*)&bsrc[base];
  v[0] += t2.x; v[1] += t2.y; v[2] += t2.z; v[3] += t2.w;
  float ss = v[0]*v[0] + v[1]*v[1] + v[2]*v[2] + v[3]*v[3];
  __shared__ float red[256];
  red[tid] = ss; __syncthreads();
  for (int s = 128; s > 0; s >>= 1){ if (tid < s) red[tid] += red[tid + s]; __syncthreads(); }
  const float scale = rsqrtf(red[0] * (1.f / 1024.f) + 1e-6f);
  float o[4];
  #pragma unroll
  for (int i = 0; i < 4; i++) o[i] = v[i] * scale * ldf(w, tid * 4 + i, f32);
  if (outb){
    u16x4 ov;
    #pragma unroll
    for (int i = 0; i < 4; i++) ov[i] = f2b(o[i]);
    *(u16x4*)&outb[base] = ov;
  }
  if (outf) *(float4*)&outf[base] = make_float4(o[0], o[1], o[2], o[3]);
  if (dout){
    if (f32) ((float*)dout)[base] = o[0], ((float*)dout)[base+1] = o[1], ((float*)dout)[base+2] = o[2], ((float*)dout)[base+3] = o[3];
    else {
      u16x4 ov;
      #pragma unroll
      for (int i = 0; i < 4; i++) ov[i] = f2b(o[i]);
      *(u16x4*)&((u16*)dout)[base] = ov;
    }
  }
}

// ---------------- per-token 8-bit absmax act quant ----------------
__global__ __launch_bounds__(256) void actquant_kernel(
    const void* __restrict__ in, int inF32, u16* __restrict__ q, float* __restrict__ srow, int N)
{
  const int row = blockIdx.x, tid = threadIdx.x;
  float amax = 0.f;
  for (int c = tid * 4; c < N; c += 1024){
    #pragma unroll
    for (int j = 0; j < 4; j++){
      float x = inF32 ? ((const float*)in)[(size_t)row * N + c + j] : b2f(((const u16*)in)[(size_t)row * N + c + j]);
      amax = fmaxf(amax, fabsf(x));
    }
  }
  __shared__ float red[256];
  red[tid] = amax; __syncthreads();
  for (int s = 128; s > 0; s >>= 1){ if (tid < s) red[tid] = fmaxf(red[tid], red[tid + s]); __syncthreads(); }
  const float s = fmaxf(red[0], 1e-5f) * (1.f / 127.f);
  if (tid == 0) srow[row] = s;
  for (int c = tid * 4; c < N; c += 1024){
    u16x4 ov;
    #pragma unroll
    for (int j = 0; j < 4; j++){
      float x = inF32 ? ((const float*)in)[(size_t)row * N + c + j] : b2f(((const u16*)in)[(size_t)row * N + c + j]);
      ov[j] = f2b(fminf(fmaxf(rintf(x / s), -128.f), 127.f));
    }
    *(u16x4*)&q[(size_t)row * N + c] = ov;
  }
}

// ---------------- BitNet weight quant ----------------
__global__ __launch_bounds__(256) void absmean_partial_kernel(
    const void* __restrict__ w, float* __restrict__ part, const unsigned* __restrict__ Fg)
{
  const bool f32 = Fg[0] != 0;
  const int tid = threadIdx.x;
  const size_t base = (size_t)blockIdx.x * 1024 + tid * 4;
  float ssum = 0.f;
  #pragma unroll
  for (int j = 0; j < 4; j++) ssum += fabsf(ldf(w, base + j, f32));
  __shared__ float red[256];
  red[tid] = ssum; __syncthreads();
  for (int s = 128; s > 0; s >>= 1){ if (tid < s) red[tid] += red[tid + s]; __syncthreads(); }
  if (tid == 0) part[blockIdx.x] = red[0];
}

__global__ __launch_bounds__(256) void absmean_final_kernel(
    const float* __restrict__ part, int n, float invc, float* __restrict__ out)
{
  const int tid = threadIdx.x;
  float ssum = 0.f;
  for (int i = tid; i < n; i += 256) ssum += part[i];
  __shared__ float red[256];
  red[tid] = ssum; __syncthreads();
  for (int s = 128; s > 0; s >>= 1){ if (tid < s) red[tid] += red[tid + s]; __syncthreads(); }
  if (tid == 0) out[0] = fmaxf(red[0] * invc, 1e-5f);
}

__global__ __launch_bounds__(256) void ternarize_kernel(
    const void* __restrict__ w, const float* __restrict__ sp, u16* __restrict__ t,
    const unsigned* __restrict__ Fg)
{
  const bool f32 = Fg[0] != 0;
  const float s = sp[0];
  const size_t base = ((size_t)blockIdx.x * 256 + threadIdx.x) * 4;
  u16x4 o;
  #pragma unroll
  for (int i = 0; i < 4; i++){
    float vv = fminf(fmaxf(rintf(ldf(w, base + i, f32) / s), -1.f), 1.f);
    o[i] = f2b(vv);
  }
  *(u16x4*)&t[base] = o;
}

extern "C" void kernel_launch(void* const* d_in, const int* in_sizes, int n_in,
                              void* d_out, int out_size, void* d_ws, size_t ws_size,
                              hipStream_t stream)
{
  const void* x      = d_in[0];
  const void* enc    = d_in[1];
  const void* in_w   = d_in[3];
  const void* conv_w = d_in[4];
  const void* conv_b = d_in[5];
  const void* xproj_w= d_in[6];
  const void* dt_w   = d_in[7];
  const void* dt_b   = d_in[8];
  const void* A_log  = d_in[9];
  const void* Dp     = d_in[10];
  const void* out_w  = d_in[11];
  const void* n1w    = d_in[12];
  const void* q_w = d_in[13]; const void* q_b = d_in[14];
  const void* k_w = d_in[15]; const void* k_b = d_in[16];
  const void* v_w = d_in[17]; const void* v_b = d_in[18];
  const void* o_w = d_in[19]; const void* o_b = d_in[20];
  const void* n2w = d_in[21];
  const void* w1  = d_in[22]; const void* b1 = d_in[23];
  const void* w2  = d_in[24]; const void* b2 = d_in[25];
  const void* n3w = d_in[26];

  char* ws = (char*)d_ws;
  const size_t MB = 1ull << 20;
  const size_t KB = 1024;
  float*    sw1  = (float*)(ws + 0);
  float*    sw2  = (float*)(ws + 16);
  unsigned* Fg   = (unsigned*)(ws + 64);
  float*    s1   = (float*)(ws + 4096);
  float*    s2   = (float*)(ws + 12288);
  float*    part = (float*)(ws + 20480);
  // phase A transients
  u16*   xz   = (u16*)  (ws + 1 * MB);    // 1-17
  u16*   u    = (u16*)  (ws + 17 * MB);   // 17-25
  float* proj = (float*)(ws + 25 * MB);   // 25-26
  float* delta= (float*)(ws + 26 * MB);   // 26-42
  float* Pp   = (float*)(ws + 42 * MB);   // 42-48
  u16*   projb= (u16*)  (ws + 48 * MB);   // 48-48.5
  u16*   G    = (u16*)  (ws + 42 * MB);   // 42-50
  float* Ssc  = (float*)(ws + 50 * MB);   // 50-58
  float* Hin  = (float*)(ws + 58 * MB);   // 58-66
  float* sdl  = (float*)(ws + 66 * MB);   // 66-66.5
  float* Pm   = (float*)(ws + 50 * MB);   // 50-66 mout split-K partials (Ssc/Hin dead)
  float* mout = (float*)(ws + 50 * MB);   // 50-58 (combine aliases partial 0)
  u16*   h1b  = (u16*)  (ws + 26 * MB);   // 26-30
  float* h1f  = (float*)(ws + 30 * MB);   // 30-38
  // phase B transients
  u16*   qb   = (u16*)  (ws + 1 * MB);    // 1-5
  u16*   kb   = (u16*)  (ws + 5 * MB);    // 5-9
  u16*   vb   = (u16*)  (ws + 9 * MB);    // 9-13
  u16*   vtb  = (u16*)  (ws + 38 * MB);   // 38-42
  u16*   Opart= (u16*)  (ws + 42 * MB);   // 42-50
  float* Lpart= (float*)(ws + 66 * MB);   // 66-66.25
  u16*   ao   = (u16*)  (ws + 13 * MB);   // 13-17
  float* aof  = (float*)(ws + 17 * MB);   // 17-25
  float* h2f  = (float*)(ws + 58 * MB);   // 58-66
  // phase C transients
  u16*   q1   = (u16*)  (ws + 1 * MB);    // 1-5
  u16*   t1   = (u16*)  (ws + 5 * MB);    // 5-13
  u16*   t2   = (u16*)  (ws + 50 * MB);   // 50-58
  u16*   gh   = (u16*)  (ws + 13 * MB);   // 13-29
  u16*   q2   = (u16*)  (ws + 29 * MB);   // 29-45
  float* Pf2  = (float*)(ws + 98 * MB);   // 98-114 FFN2 split-K partials
  float* fo   = (float*)(ws + 1 * MB);    // 1-9
  // persistent bf16 copies (68-97)
  u16* xb       = (u16*)(ws + 68 * MB);
  u16* encb     = (u16*)(ws + 72 * MB);
  u16* in_wb    = (u16*)(ws + 76 * MB);
  u16* out_wb   = (u16*)(ws + 84 * MB);
  u16* q_wb     = (u16*)(ws + 88 * MB);   // q/k/v contiguous -> fused [3072][1024]
  u16* k_wb     = (u16*)(ws + 90 * MB);
  u16* v_wb     = (u16*)(ws + 92 * MB);
  u16* o_wb     = (u16*)(ws + 94 * MB);
  u16* xproj_wb = (u16*)(ws + 96 * MB);
  u16* dt_wb    = (u16*)(ws + 96 * MB + 512 * KB);
  u16* dt_bb    = (u16*)(ws + 96 * MB + 768 * KB);
  u16* q_bb     = (u16*)(ws + 96 * MB + 776 * KB);  // q/k/v biases contiguous
  u16* k_bb     = (u16*)(ws + 96 * MB + 778 * KB);
  u16* v_bb     = (u16*)(ws + 96 * MB + 780 * KB);
  u16* o_bb     = (u16*)(ws + 96 * MB + 788 * KB);
  u16* b1b      = (u16*)(ws + 96 * MB + 792 * KB);
  u16* b2b      = (u16*)(ws + 96 * MB + 808 * KB);
  u16* qkvw     = q_wb;
  u16* qkvb     = q_bb;

  dim3 blk(256);
  detect_kernel<<<dim3(1), blk, 0, stream>>>(x, Fg);

  // 0b. convert all GEMM-facing externals to bf16
  {
    CvtJobs jobs;
    const void* srcs[NCVT] = { x, enc, in_w, out_w, q_w, k_w, v_w, o_w, xproj_w, dt_w,
                               dt_b, q_b, k_b, v_b, o_b, b1, b2 };
    u16* dsts[NCVT] = { xb, encb, in_wb, out_wb, q_wb, k_wb, v_wb, o_wb, xproj_wb, dt_wb,
                        dt_bb, q_bb, k_bb, v_bb, o_bb, b1b, b2b };
    int ns[NCVT] = { 2097152, 2097152, 4194304, 2097152, 1048576, 1048576, 1048576, 1048576,
                     196608, 131072, 2048, 1024, 1024, 1024, 1024, 4096, 1024 };
    int bo = 0;
    for (int j = 0; j < NCVT; j++){
      jobs.src[j] = srcs[j]; jobs.dst[j] = dsts[j]; jobs.n[j] = ns[j];
      jobs.blk_off[j] = bo;
      bo += (ns[j] / 8 + 255) / 256;
    }
    jobs.blk_off[NCVT] = bo;
    convert_kernel<<<dim3(bo), blk, 0, stream>>>(jobs, Fg);
  }

  // 1. xz = x @ in_w^T  (128x128)
  gemm16<0,4,4,2,2,false><<<dim3(32, 16), blk, 0, stream>>>(xb, in_wb, xz, 2048, 4096, 1024, 1024, 1024, 4096, nullptr, nullptr, nullptr, nullptr, nullptr);
  // 2. conv + SiLU
  conv_silu_kernel<<<dim3(16384), blk, 0, stream>>>(xz, conv_w, conv_b, u, Fg);
  // 3. proj = u @ xproj_w^T (split-K=8) + reduce
  gemm16<3,2,3,2,2,false><<<dim3(1, 32, 8), blk, 0, stream>>>(u, xproj_wb, Pp, 2048, 96, 256, 2048, 2048, 96, nullptr, nullptr, nullptr, nullptr, nullptr);
  xproj_reduce_kernel<<<dim3(768), blk, 0, stream>>>(Pp, proj, projb);
  // 4. delta = softplus(projb @ dt_w^T + dt_b)
  gemm16<6,2,2,2,2,false><<<dim3(32, 32), blk, 0, stream>>>(projb, dt_wb, delta, 2048, 2048, 64, 64, 64, 2048, dt_bb, nullptr, nullptr, nullptr, nullptr);
  // 5. chunked scan
  scan_part1<<<dim3(8, SNCH, 2), blk, 0, stream>>>(delta, u, proj, A_log, Ssc, sdl, Fg);
  scan_combine<<<dim3(16), blk, 0, stream>>>(Ssc, sdl, A_log, Hin, Fg);
  scan_part2<<<dim3(8, SNCH, 2), blk, 0, stream>>>(delta, u, proj, A_log, Dp, xz, Hin, G, Fg);
  // 6. mamba_out = G @ out_w^T  (split-K=2 -> 1024 blocks) + combine
  gemm16<3,2,2,2,2,false><<<dim3(16, 32, 2), blk, 0, stream>>>(G, out_wb, Pm, 2048, 1024, 1024, 2048, 2048, 1024, nullptr, nullptr, nullptr, nullptr, nullptr);
  add2_kernel<<<dim3(2048), blk, 0, stream>>>(Pm, mout);
  // 7. h1 = rmsnorm(x + mamba_out)
  rmsnorm_kernel<<<dim3(2048), blk, 0, stream>>>(x, 1, mout, n1w, h1b, h1f, nullptr, Fg);
  // 8. fused q/k/v projection (N=3072 -> three outputs)
  gemm16<1,2,2,2,2,true><<<dim3(48, 32), blk, 0, stream>>>(h1b, qkvw, qb, 2048, 3072, 1024, 1024, 1024, 1024, qkvb, nullptr, nullptr, kb, vb);
  // note: k/v rows come from enc, q from h1b -> must use separate A! fix below.
  // (overwritten by correct calls)
  gemm16<1,2,2,2,2,false><<<dim3(16, 32), blk, 0, stream>>>(encb, k_wb, kb, 2048, 1024, 1024, 1024, 1024, 1024, k_bb, nullptr, nullptr, nullptr, nullptr);
  gemm16<1,2,2,2,2,false><<<dim3(16, 32), blk, 0, stream>>>(encb, v_wb, vb, 2048, 1024, 1024, 1024, 1024, 1024, v_bb, nullptr, nullptr, nullptr, nullptr);
  // 8b. V transpose
  vtrans_kernel<<<dim3(16, 32), blk, 0, stream>>>(vb, vtb);
  // 9. multi-wave LDS-staged flash attention + combine
  attn_mw_kernel<<<dim3(16, 32, ASPL), blk, 0, stream>>>(qb, kb, vtb, Opart, Lpart);
  attn_combine_kernel<<<dim3(2048), blk, 0, stream>>>(Opart, Lpart, ao);
  // 10. o projection
  gemm16<2,2,2,2,2,false><<<dim3(16, 32), blk, 0, stream>>>(ao, o_wb, aof, 2048, 1024, 1024, 1024, 1024, 1024, o_bb, nullptr, nullptr, nullptr, nullptr);
  // 11. h2 = rmsnorm(h1 + attn)
  rmsnorm_kernel<<<dim3(2048), blk, 0, stream>>>(h1f, 0, aof, n2w, nullptr, h2f, nullptr, Fg);
  // 12. act_quant(h2)
  actquant_kernel<<<dim3(2048), blk, 0, stream>>>(h2f, 1, q1, s1, 1024);
  // 13. weight_quant(w1), weight_quant(w2)
  absmean_partial_kernel<<<dim3(4096), blk, 0, stream>>>(w1, part, Fg);
  absmean_final_kernel<<<dim3(1), blk, 0, stream>>>(part, 4096, 1.f / 4194304.f, sw1);
  ternarize_kernel<<<dim3(4096), blk, 0, stream>>>(w1, sw1, t1, Fg);
  absmean_partial_kernel<<<dim3(4096), blk, 0, stream>>>(w2, part, Fg);
  absmean_final_kernel<<<dim3(1), blk, 0, stream>>>(part, 4096, 1.f / 4194304.f, sw2);
  ternarize_kernel<<<dim3(4096), blk, 0, stream>>>(w2, sw2, t2, Fg);
  // 14. ffn hidden = gelu(q1 @ t1^T * s1*sw1 + b1) -> bf16  (128x128)
  gemm16<4,4,4,2,2,false><<<dim3(32, 16), blk, 0, stream>>>(q1, t1, gh, 2048, 4096, 1024, 1024, 1024, 4096, b1b, s1, sw1, nullptr, nullptr);
  // 15. act_quant(gh)
  actquant_kernel<<<dim3(2048), blk, 0, stream>>>(gh, 0, q2, s2, 4096);
  // 16. ffn out (split-K=2 -> 1024 blocks) + scaled combine
  gemm16<3,2,2,2,2,false><<<dim3(16, 32, 2), blk, 0, stream>>>(q2, t2, Pf2, 2048, 1024, 2048, 4096, 4096, 1024, nullptr, nullptr, nullptr, nullptr, nullptr);
  ffn2_combine_kernel<<<dim3(2048), blk, 0, stream>>>(Pf2, s2, sw2, b2b, fo);
  // 17. out = rmsnorm(h2 + ffn) -> d_out
  rmsnorm_kernel<<<dim3(2048), blk, 0, stream>>>(h2f, 0, fo, n3w, nullptr, nullptr, d_out, Fg);
}

// Round 12
// 396.965 us; speedup vs baseline: 1.2709x; 1.0659x over previous
//
#include <hip/hip_runtime.h>
#include <math.h>

#define DEV __device__ __forceinline__
using u16 = unsigned short;
typedef __bf16 bh8 __attribute__((ext_vector_type(8)));
typedef float f32x4 __attribute__((ext_vector_type(4)));
typedef u16 u16x8 __attribute__((ext_vector_type(8)));
typedef u16 u16x4 __attribute__((ext_vector_type(4)));

DEV float b2f(u16 x){ unsigned u = ((unsigned)x) << 16; float f; __builtin_memcpy(&f, &u, 4); return f; }
DEV u16 f2b(float f){ unsigned u; __builtin_memcpy(&u, &f, 4); return (u16)((u + 0x7fffu + ((u >> 16) & 1u)) >> 16); }
DEV float sigm(float x){ return 1.f / (1.f + __expf(-x)); }
DEV float ldf(const void* p, size_t i, bool f32){ return f32 ? ((const float*)p)[i] : b2f(((const u16*)p)[i]); }

// ---------------- dtype detect ----------------
__global__ __launch_bounds__(256) void detect_kernel(const void* x, unsigned* flag)
{
  const int tid = threadIdx.x;
  const u16* p = (const u16*)x;
  int sane = 0;
  #pragma unroll
  for (int j = 0; j < 8; j++){
    u16 v = p[(size_t)(tid * 8 + j) * 2];
    int e = (v >> 7) & 0xFF;
    sane += (e >= 0x60 && e <= 0x8F) ? 1 : 0;
  }
  __shared__ int red[256];
  red[tid] = sane; __syncthreads();
  for (int s = 128; s > 0; s >>= 1){ if (tid < s) red[tid] += red[tid + s]; __syncthreads(); }
  if (tid == 0) flag[0] = (red[0] < 1200) ? 1u : 0u;
}

// ---------------- batch convert external -> bf16 ws ----------------
#define NCVT 17
struct CvtJobs {
  const void* src[NCVT];
  u16* dst[NCVT];
  int n[NCVT];
  int blk_off[NCVT + 1];
};
__global__ __launch_bounds__(256) void convert_kernel(CvtJobs jobs, const unsigned* __restrict__ Fg)
{
  const bool f32 = Fg[0] != 0;
  const int bx = blockIdx.x;
  int j = 0;
  while (bx >= jobs.blk_off[j + 1]) j++;
  const int e = (bx - jobs.blk_off[j]) * 2048 + threadIdx.x * 8;
  if (e >= jobs.n[j]) return;
  if (f32){
    const float* s = (const float*)jobs.src[j] + e;
    u16x8 o;
    #pragma unroll
    for (int i = 0; i < 8; i++) o[i] = f2b(s[i]);
    *(u16x8*)(jobs.dst[j] + e) = o;
  } else {
    *(u16x8*)(jobs.dst[j] + e) = *(const u16x8*)((const u16*)jobs.src[j] + e);
  }
}

// ---------------- reg-staged BK=64 swizzled MFMA GEMM ----------------
// EPI: 0 bf16  1 bf16+bias  2 f32+bias  3 f32 (split-K partial)
// 4 bf16=gelu(acc*rs*ws+bias)  5 f32=acc*rs*ws+bias  6 f32=softplus(acc+bias)
// SPLITC: route 1024-col groups to Cv/Cv1/Cv2 (each ldc=1024).
template<int EPI, int FM, int FN, int WR, int WC, bool SPLITC>
__global__ __launch_bounds__(256) void gemm16(
    const u16* __restrict__ A, const u16* __restrict__ W, void* __restrict__ Cv,
    int M, int N, int K, int lda, int ldb, int ldc,
    const u16* __restrict__ bias, const float* __restrict__ rowscale,
    const float* __restrict__ wscale, void* __restrict__ Cv1, void* __restrict__ Cv2)
{
  constexpr int BM = WR * FM * 16, BN = WC * FN * 16;
  __shared__ __align__(16) char As[BM * 128];
  __shared__ __align__(16) char Bs[BN * 128];
  const int tid = threadIdx.x, wave = tid >> 6, lane = tid & 63;
  const int wr = wave / WC, wc = wave % WC, fr = lane & 15, g = lane >> 4;
  const size_t bm = (size_t)blockIdx.y * BM, bn = (size_t)blockIdx.x * BN;
  const int kbase = blockIdx.z * K;
  f32x4 acc[FM][FN] = {};
  constexpr int ACH = BM / 32, BCH = BN / 32;
  u16x8 areg[ACH], breg[BCH];
  auto fetch = [&](int k0){
    #pragma unroll
    for (int c = 0; c < ACH; c++){
      int li = tid + c * 256;
      areg[c] = *(const u16x8*)&A[(bm + (li >> 3)) * (size_t)lda + kbase + k0 + ((li & 7) << 3)];
    }
    #pragma unroll
    for (int c = 0; c < BCH; c++){
      int li = tid + c * 256;
      breg[c] = *(const u16x8*)&W[(bn + (li >> 3)) * (size_t)ldb + kbase + k0 + ((li & 7) << 3)];
    }
  };
  fetch(0);
  for (int k0 = 0; k0 < K; k0 += 64){
    __syncthreads();
    #pragma unroll
    for (int c = 0; c < ACH; c++){
      int li = tid + c * 256, row = li >> 3, j = li & 7;
      *(u16x8*)&As[row * 128 + ((j * 16) ^ ((row & 7) << 4))] = areg[c];
    }
    #pragma unroll
    for (int c = 0; c < BCH; c++){
      int li = tid + c * 256, row = li >> 3, j = li & 7;
      *(u16x8*)&Bs[row * 128 + ((j * 16) ^ ((row & 7) << 4))] = breg[c];
    }
    __syncthreads();
    if (k0 + 64 < K) fetch(k0 + 64);
    bh8 af[2][FM], bf[2][FN];
    #pragma unroll
    for (int ks = 0; ks < 2; ks++){
      #pragma unroll
      for (int i = 0; i < FM; i++){
        int row = wr * (FM * 16) + i * 16 + fr;
        af[ks][i] = *(const bh8*)&As[row * 128 + ((ks * 64 + g * 16) ^ ((row & 7) << 4))];
      }
      #pragma unroll
      for (int j = 0; j < FN; j++){
        int row = wc * (FN * 16) + j * 16 + fr;
        bf[ks][j] = *(const bh8*)&Bs[row * 128 + ((ks * 64 + g * 16) ^ ((row & 7) << 4))];
      }
    }
    #pragma unroll
    for (int ks = 0; ks < 2; ks++)
      #pragma unroll
      for (int i = 0; i < FM; i++)
        #pragma unroll
        for (int j = 0; j < FN; j++)
          acc[i][j] = __builtin_amdgcn_mfma_f32_16x16x32_bf16(af[ks][i], bf[ks][j], acc[i][j], 0, 0, 0);
  }
  float wsc = 0.f;
  if constexpr (EPI == 4 || EPI == 5) wsc = wscale[0];
  u16* Cb = (u16*)Cv;
  float* Cf = (float*)Cv + (size_t)blockIdx.z * M * ldc;
  #pragma unroll
  for (int i = 0; i < FM; i++){
    #pragma unroll
    for (int r = 0; r < 4; r++){
      const size_t row = bm + wr * (FM * 16) + i * 16 + g * 4 + r;
      float rs = 0.f;
      if constexpr (EPI == 4 || EPI == 5) rs = rowscale[row] * wsc;
      #pragma unroll
      for (int j = 0; j < FN; j++){
        const size_t col = bn + wc * (FN * 16) + j * 16 + fr;
        float v = acc[i][j][r];
        if constexpr (EPI == 1 || EPI == 2) v += b2f(bias[col]);
        if constexpr (EPI == 4 || EPI == 5) v = v * rs + b2f(bias[col]);
        if constexpr (EPI == 4){ float x = v; v = 0.5f * x * (1.f + tanhf(0.7978845608f * (x + 0.044715f * x * x * x))); }
        if constexpr (EPI == 6){ float x = v + b2f(bias[col]); v = fmaxf(x, 0.f) + log1pf(__expf(-fabsf(x))); }
        if constexpr (EPI == 0 || EPI == 1 || EPI == 4){
          u16* CbX = Cb; size_t cc = col;
          if constexpr (SPLITC){
            int wq = (int)(col >> 10);
            CbX = wq == 0 ? Cb : (wq == 1 ? (u16*)Cv1 : (u16*)Cv2);
            cc = col & 1023;
          }
          CbX[row * ldc + cc] = f2b(v);
        } else Cf[row * ldc + col] = v;
      }
    }
  }
}

// ---------------- xproj split-K reduce ----------------
__global__ __launch_bounds__(256) void xproj_reduce_kernel(
    const float* __restrict__ Pp, float* __restrict__ proj, u16* __restrict__ projb)
{
  const int idx = blockIdx.x * 256 + threadIdx.x;
  const int m = idx / 96, n = idx % 96;
  float s = 0.f;
  #pragma unroll
  for (int z = 0; z < 8; z++) s += Pp[(size_t)z * 2048 * 96 + idx];
  proj[idx] = s;
  if (n < 64) projb[(size_t)m * 64 + n] = f2b(s);
}

// ---------------- causal depthwise conv (D_CONV=4) + SiLU ----------------
__global__ __launch_bounds__(256) void conv_silu_kernel(
    const u16* __restrict__ xz, const void* __restrict__ cw, const void* __restrict__ cb,
    u16* __restrict__ u, const unsigned* __restrict__ Fg)
{
  const bool f32 = Fg[0] != 0;
  const int idx = blockIdx.x * 256 + threadIdx.x;
  const int c = idx & 2047;
  const int bt = idx >> 11;
  const int t = bt & 1023, b = bt >> 10;
  float acc = ldf(cb, c, f32);
  #pragma unroll
  for (int j = 0; j < 4; j++){
    int tt = t - 3 + j;
    if (tt >= 0) acc += b2f(xz[(size_t)(b * 1024 + tt) * 4096 + c]) * ldf(cw, c * 4 + j, f32);
  }
  u[(size_t)bt * 2048 + c] = f2b(acc * sigm(acc));
}

// ---------------- chunked selective scan ----------------
#define SCH 32
#define SNCH 32

__global__ __launch_bounds__(256) void scan_part1(
    const float* __restrict__ delta, const u16* __restrict__ u,
    const float* __restrict__ proj, const void* __restrict__ Alog,
    float* __restrict__ S, float* __restrict__ sumdl_o, const unsigned* __restrict__ Fg)
{
  const bool f32 = Fg[0] != 0;
  const int b = blockIdx.z, ch = blockIdx.y, d = blockIdx.x * 256 + threadIdx.x;
  float A[16], h[16];
  #pragma unroll
  for (int s = 0; s < 16; s++){ A[s] = -__expf(ldf(Alog, d * 16 + s, f32)); h[s] = 0.f; }
  __shared__ __align__(16) float Bsh[SCH][16];
  {
    int tc = threadIdx.x >> 3, j = (threadIdx.x & 7) * 2;
    *(float2*)&Bsh[tc][j] = *(const float2*)&proj[(size_t)(b * 1024 + ch * SCH + tc) * 96 + 64 + j];
  }
  __syncthreads();
  float sumdl = 0.f;
  for (int tt = 0; tt < SCH; tt++){
    const size_t m = (size_t)(b * 1024 + ch * SCH + tt);
    const float dl = delta[m * 2048 + d];
    const float du = dl * b2f(u[m * 2048 + d]);
    sumdl += dl;
    #pragma unroll
    for (int s = 0; s < 16; s++) h[s] = __expf(dl * A[s]) * h[s] + du * Bsh[tt][s];
  }
  #pragma unroll
  for (int s = 0; s < 16; s++) S[((size_t)(b * SNCH + ch) * 16 + s) * 2048 + d] = h[s];
  sumdl_o[(size_t)(b * SNCH + ch) * 2048 + d] = sumdl;
}

__global__ __launch_bounds__(256) void scan_combine(
    const float* __restrict__ S, const float* __restrict__ sumdl,
    const void* __restrict__ Alog, float* __restrict__ Hin, const unsigned* __restrict__ Fg)
{
  const bool f32 = Fg[0] != 0;
  const int idx = blockIdx.x * 256 + threadIdx.x;
  const int b = idx >> 11, d = idx & 2047;
  float A[16], h[16];
  #pragma unroll
  for (int s = 0; s < 16; s++){ A[s] = -__expf(ldf(Alog, d * 16 + s, f32)); h[s] = 0.f; }
  for (int ch = 0; ch < SNCH; ch++){
    const float sd = sumdl[(size_t)(b * SNCH + ch) * 2048 + d];
    #pragma unroll
    for (int s = 0; s < 16; s++){
      const size_t off = ((size_t)(b * SNCH + ch) * 16 + s) * 2048 + d;
      Hin[off] = h[s];
      h[s] = __expf(A[s] * sd) * h[s] + S[off];
    }
  }
}

__global__ __launch_bounds__(256) void scan_part2(
    const float* __restrict__ delta, const u16* __restrict__ u,
    const float* __restrict__ proj, const void* __restrict__ Alog,
    const void* __restrict__ Dp, const u16* __restrict__ xz,
    const float* __restrict__ Hin, u16* __restrict__ G, const unsigned* __restrict__ Fg)
{
  const bool f32 = Fg[0] != 0;
  const int b = blockIdx.z, ch = blockIdx.y, d = blockIdx.x * 256 + threadIdx.x;
  float A[16], h[16];
  #pragma unroll
  for (int s = 0; s < 16; s++){
    A[s] = -__expf(ldf(Alog, d * 16 + s, f32));
    h[s] = Hin[((size_t)(b * SNCH + ch) * 16 + s) * 2048 + d];
  }
  const float Dv = ldf(Dp, d, f32);
  __shared__ __align__(16) float BCs[SCH][32];
  {
    int tc = threadIdx.x >> 3, j = (threadIdx.x & 7) * 4;
    *(float4*)&BCs[tc][j] = *(const float4*)&proj[(size_t)(b * 1024 + ch * SCH + tc) * 96 + 64 + j];
  }
  __syncthreads();
  for (int tt = 0; tt < SCH; tt++){
    const size_t m = (size_t)(b * 1024 + ch * SCH + tt);
    const float dl = delta[m * 2048 + d];
    const float uv = b2f(u[m * 2048 + d]);
    const float du = dl * uv;
    float y = 0.f;
    #pragma unroll
    for (int s = 0; s < 16; s++){
      h[s] = __expf(dl * A[s]) * h[s] + du * BCs[tt][s];
      y += h[s] * BCs[tt][16 + s];
    }
    y += uv * Dv;
    const float r = b2f(xz[m * 4096 + 2048 + d]);
    G[m * 2048 + d] = f2b(y * (r * sigm(r)));
  }
}

// ---------------- V transpose ----------------
__global__ __launch_bounds__(256) void vtrans_kernel(const u16* __restrict__ V, u16* __restrict__ Vt)
{
  __shared__ __align__(16) u16 T[64 * 64];
  const int bh = blockIdx.y, b = bh >> 4, hh = bh & 15;
  const int s0 = blockIdx.x * 64;
  const int tid = threadIdx.x;
  {
    int s = tid & 63, d0 = (tid >> 6) * 16;
    const u16* src = V + ((size_t)(b * 1024 + s0 + s)) * 1024 + hh * 64 + d0;
    u16x8 v0 = *(const u16x8*)src, v1 = *(const u16x8*)(src + 8);
    int byte0 = (s * 128 + d0 * 2) ^ ((s & 7) << 4);
    int byte1 = (s * 128 + d0 * 2 + 16) ^ ((s & 7) << 4);
    *(u16x8*)((char*)T + byte0) = v0;
    *(u16x8*)((char*)T + byte1) = v1;
  }
  __syncthreads();
  {
    int d = tid & 63, t0 = (tid >> 6) * 16;
    u16x8 w0, w1;
    #pragma unroll
    for (int j = 0; j < 8; j++){
      int r0 = t0 + j, r1 = t0 + 8 + j;
      w0[j] = *(const u16*)((char*)T + ((r0 * 128 + d * 2) ^ ((r0 & 7) << 4)));
      w1[j] = *(const u16*)((char*)T + ((r1 * 128 + d * 2) ^ ((r1 & 7) << 4)));
    }
    u16* dst = Vt + ((size_t)bh * 64 + d) * 1024 + s0 + t0;
    *(u16x8*)dst = w0;
    *(u16x8*)(dst + 8) = w1;
  }
}

// ---------------- multi-wave MFMA flash cross-attention, LDS-staged K/V ----------------
#define ASPL 2
__global__ __launch_bounds__(256) void attn_mw_kernel(
    const u16* __restrict__ Q, const u16* __restrict__ Kb, const u16* __restrict__ Vt,
    u16* __restrict__ Opart, float* __restrict__ Lpart)
{
  const int bh = blockIdx.y, b = bh >> 4, hh = bh & 15;
  const int z = blockIdx.z;
  const int tid = threadIdx.x, wave = tid >> 6, lane = tid & 63;
  const int fr = lane & 15, g = lane >> 4;
  const int q0 = blockIdx.x * 64 + wave * 16;
  __shared__ __align__(16) char Ks[64 * 128];
  __shared__ __align__(16) char Vs[64 * 128];
  __shared__ __align__(16) u16 Pl[4][1024];
  const u16* qp = Q + ((size_t)(b * 1024 + q0 + fr)) * 1024 + hh * 64 + g * 8;
  const bh8 aq0 = *(const bh8*)qp;
  const bh8 aq1 = *(const bh8*)(qp + 32);
  f32x4 oacc[4] = {};
  float lsum[4] = {};
  const u16* kbase = Kb + ((size_t)(b * 1024)) * 1024 + hh * 64;
  const u16* vbase = Vt + ((size_t)bh * 64) * 1024;
  const int srow = tid >> 2, sj = (tid & 3) * 2;
  for (int s0 = z * (1024 / ASPL); s0 < (z + 1) * (1024 / ASPL); s0 += 64){
    __syncthreads();
    {
      const u16* kr = kbase + (size_t)(s0 + srow) * 1024 + sj * 8;
      u16x8 k0 = *(const u16x8*)kr, k1 = *(const u16x8*)(kr + 8);
      *(u16x8*)&Ks[srow * 128 + ((sj * 16) ^ ((srow & 7) << 4))] = k0;
      *(u16x8*)&Ks[srow * 128 + (((sj + 1) * 16) ^ ((srow & 7) << 4))] = k1;
      const u16* vr = vbase + (size_t)srow * 1024 + s0 + sj * 8;
      u16x8 v0 = *(const u16x8*)vr, v1 = *(const u16x8*)(vr + 8);
      *(u16x8*)&Vs[srow * 128 + ((sj * 16) ^ ((srow & 7) << 4))] = v0;
      *(u16x8*)&Vs[srow * 128 + (((sj + 1) * 16) ^ ((srow & 7) << 4))] = v1;
    }
    __syncthreads();
    bh8 bk[4][2], bv[2][4];
    #pragma unroll
    for (int ct = 0; ct < 4; ct++){
      int row = 16 * ct + fr;
      #pragma unroll
      for (int ks = 0; ks < 2; ks++)
        bk[ct][ks] = *(const bh8*)&Ks[row * 128 + ((ks * 64 + g * 16) ^ ((row & 7) << 4))];
    }
    #pragma unroll
    for (int dt = 0; dt < 4; dt++){
      int row = 16 * dt + fr;
      #pragma unroll
      for (int ks = 0; ks < 2; ks++)
        bv[ks][dt] = *(const bh8*)&Vs[row * 128 + ((ks * 64 + g * 16) ^ ((row & 7) << 4))];
    }
    #pragma unroll
    for (int ct = 0; ct < 4; ct++){
      f32x4 zz = {};
      zz = __builtin_amdgcn_mfma_f32_16x16x32_bf16(aq0, bk[ct][0], zz, 0, 0, 0);
      zz = __builtin_amdgcn_mfma_f32_16x16x32_bf16(aq1, bk[ct][1], zz, 0, 0, 0);
      #pragma unroll
      for (int r = 0; r < 4; r++){
        float p = __expf(zz[r] * 0.125f);
        u16 pb = f2b(p);
        lsum[r] += b2f(pb);
        int row = 4 * g + r, col = 16 * ct + fr;
        *(u16*)((char*)&Pl[wave][0] + ((row * 128 + col * 2) ^ ((row & 7) << 4))) = pb;
      }
    }
    bh8 pa[2];
    #pragma unroll
    for (int ks = 0; ks < 2; ks++)
      pa[ks] = *(const bh8*)((char*)&Pl[wave][0] + ((fr * 128 + (ks * 32 + g * 8) * 2) ^ ((fr & 7) << 4)));
    #pragma unroll
    for (int dt = 0; dt < 4; dt++){
      oacc[dt] = __builtin_amdgcn_mfma_f32_16x16x32_bf16(pa[0], bv[0][dt], oacc[dt], 0, 0, 0);
      oacc[dt] = __builtin_amdgcn_mfma_f32_16x16x32_bf16(pa[1], bv[1][dt], oacc[dt], 0, 0, 0);
    }
  }
  #pragma unroll
  for (int r = 0; r < 4; r++){
    #pragma unroll
    for (int d2 = 1; d2 < 16; d2 <<= 1) lsum[r] += __shfl_xor(lsum[r], d2);
  }
  u16* opz = Opart + (size_t)z * 2097152;
  #pragma unroll
  for (int r = 0; r < 4; r++){
    const int tok = b * 1024 + q0 + 4 * g + r;
    #pragma unroll
    for (int dt = 0; dt < 4; dt++)
      opz[(size_t)tok * 1024 + hh * 64 + 16 * dt + fr] = f2b(oacc[dt][r]);
    if (fr == 0) Lpart[(size_t)z * 32768 + tok * 16 + hh] = lsum[r];
  }
}

__global__ __launch_bounds__(256) void attn_combine_kernel(
    const u16* __restrict__ Opart, const float* __restrict__ Lpart, u16* __restrict__ O)
{
  const int tok = blockIdx.x, tid = threadIdx.x;
  const int c = tid * 4, hh = c >> 6;
  float l = 0.f;
  #pragma unroll
  for (int z = 0; z < ASPL; z++) l += Lpart[(size_t)z * 32768 + tok * 16 + hh];
  float acc[4] = {};
  #pragma unroll
  for (int z = 0; z < ASPL; z++){
    u16x4 v = *(const u16x4*)&Opart[(size_t)z * 2097152 + (size_t)tok * 1024 + c];
    #pragma unroll
    for (int j = 0; j < 4; j++) acc[j] += b2f(v[j]);
  }
  const float inv = 1.f / l;
  u16x4 ov;
  #pragma unroll
  for (int j = 0; j < 4; j++) ov[j] = f2b(acc[j] * inv);
  *(u16x4*)&O[(size_t)tok * 1024 + c] = ov;
}

// ---------------- fused rmsnorm ----------------
// MODE 0: v = a + bsrc              (+ optional act-quant of output -> qout,srow)
// MODE 1: v = a + P0 + P1           (mout split-K combine folded in)
// MODE 2: v = a + (P0+P1)*s2[row]*sw2 + bias2[col]   (FFN2 combine folded in)
template<int MODE>
__global__ __launch_bounds__(256) void rmsnorm_fused(
    const void* __restrict__ a, int aIn, const float* __restrict__ bsrc,
    const void* __restrict__ w, u16* __restrict__ outb, float* __restrict__ outf,
    void* __restrict__ dout, const unsigned* __restrict__ Fg,
    u16* __restrict__ qout, float* __restrict__ srow,
    const float* __restrict__ s2, const float* __restrict__ sw2, const u16* __restrict__ bias2)
{
  const bool f32 = Fg[0] != 0;
  const bool a32 = aIn ? f32 : true;
  const int row = blockIdx.x, tid = threadIdx.x;
  const size_t base = (size_t)row * 1024 + tid * 4;
  float v[4];
  if (a32){
    float4 t = *(const float4*)&((const float*)a)[base];
    v[0] = t.x; v[1] = t.y; v[2] = t.z; v[3] = t.w;
  } else {
    u16x4 t = *(const u16x4*)&((const u16*)a)[base];
    v[0] = b2f(t[0]); v[1] = b2f(t[1]); v[2] = b2f(t[2]); v[3] = b2f(t[3]);
  }
  if constexpr (MODE == 0){
    float4 t2 = *(const float4*)&bsrc[base];
    v[0] += t2.x; v[1] += t2.y; v[2] += t2.z; v[3] += t2.w;
  }
  if constexpr (MODE == 1){
    float4 p0 = *(const float4*)&bsrc[base];
    float4 p1 = *(const float4*)&bsrc[2097152 + base];
    v[0] += p0.x + p1.x; v[1] += p0.y + p1.y; v[2] += p0.z + p1.z; v[3] += p0.w + p1.w;
  }
  if constexpr (MODE == 2){
    const float rs = s2[row] * sw2[0];
    float4 p0 = *(const float4*)&bsrc[base];
    float4 p1 = *(const float4*)&bsrc[2097152 + base];
    u16x4 bb = *(const u16x4*)&bias2[tid * 4];
    v[0] += (p0.x + p1.x) * rs + b2f(bb[0]);
    v[1] += (p0.y + p1.y) * rs + b2f(bb[1]);
    v[2] += (p0.z + p1.z) * rs + b2f(bb[2]);
    v[3] += (p0.w + p1.w) * rs + b2f(bb[3]);
  }
  float ss = v[0]*v[0] + v[1]*v[1] + v[2]*v[2] + v[3]*v[3];
  __shared__ float red[256];
  red[tid] = ss; __syncthreads();
  for (int s = 128; s > 0; s >>= 1){ if (tid < s) red[tid] += red[tid + s]; __syncthreads(); }
  const float scale = rsqrtf(red[0] * (1.f / 1024.f) + 1e-6f);
  float o[4];
  #pragma unroll
  for (int i = 0; i < 4; i++) o[i] = v[i] * scale * ldf(w, tid * 4 + i, f32);
  if (outb){
    u16x4 ov;
    #pragma unroll
    for (int i = 0; i < 4; i++) ov[i] = f2b(o[i]);
    *(u16x4*)&outb[base] = ov;
  }
  if (outf) *(float4*)&outf[base] = make_float4(o[0], o[1], o[2], o[3]);
  if (dout){
    if (f32) ((float*)dout)[base] = o[0], ((float*)dout)[base+1] = o[1], ((float*)dout)[base+2] = o[2], ((float*)dout)[base+3] = o[3];
    else {
      u16x4 ov;
      #pragma unroll
      for (int i = 0; i < 4; i++) ov[i] = f2b(o[i]);
      *(u16x4*)&((u16*)dout)[base] = ov;
    }
  }
  if (qout){
    float amax = fmaxf(fmaxf(fabsf(o[0]), fabsf(o[1])), fmaxf(fabsf(o[2]), fabsf(o[3])));
    __syncthreads();
    red[tid] = amax; __syncthreads();
    for (int s = 128; s > 0; s >>= 1){ if (tid < s) red[tid] = fmaxf(red[tid], red[tid + s]); __syncthreads(); }
    const float s = fmaxf(red[0], 1e-5f) * (1.f / 127.f);
    if (tid == 0) srow[row] = s;
    u16x4 qv;
    #pragma unroll
    for (int i = 0; i < 4; i++) qv[i] = f2b(fminf(fmaxf(rintf(o[i] / s), -128.f), 127.f));
    *(u16x4*)&qout[base] = qv;
  }
}

// ---------------- per-token 8-bit absmax act quant (gh path only) ----------------
__global__ __launch_bounds__(256) void actquant_kernel(
    const void* __restrict__ in, int inF32, u16* __restrict__ q, float* __restrict__ srow, int N)
{
  const int row = blockIdx.x, tid = threadIdx.x;
  float amax = 0.f;
  for (int c = tid * 4; c < N; c += 1024){
    #pragma unroll
    for (int j = 0; j < 4; j++){
      float x = inF32 ? ((const float*)in)[(size_t)row * N + c + j] : b2f(((const u16*)in)[(size_t)row * N + c + j]);
      amax = fmaxf(amax, fabsf(x));
    }
  }
  __shared__ float red[256];
  red[tid] = amax; __syncthreads();
  for (int s = 128; s > 0; s >>= 1){ if (tid < s) red[tid] = fmaxf(red[tid], red[tid + s]); __syncthreads(); }
  const float s = fmaxf(red[0], 1e-5f) * (1.f / 127.f);
  if (tid == 0) srow[row] = s;
  for (int c = tid * 4; c < N; c += 1024){
    u16x4 ov;
    #pragma unroll
    for (int j = 0; j < 4; j++){
      float x = inF32 ? ((const float*)in)[(size_t)row * N + c + j] : b2f(((const u16*)in)[(size_t)row * N + c + j]);
      ov[j] = f2b(fminf(fmaxf(rintf(x / s), -128.f), 127.f));
    }
    *(u16x4*)&q[(size_t)row * N + c] = ov;
  }
}

// ---------------- BitNet weight quant ----------------
__global__ __launch_bounds__(256) void absmean_partial_kernel(
    const void* __restrict__ w, float* __restrict__ part, const unsigned* __restrict__ Fg)
{
  const bool f32 = Fg[0] != 0;
  const int tid = threadIdx.x;
  const size_t base = (size_t)blockIdx.x * 1024 + tid * 4;
  float ssum = 0.f;
  #pragma unroll
  for (int j = 0; j < 4; j++) ssum += fabsf(ldf(w, base + j, f32));
  __shared__ float red[256];
  red[tid] = ssum; __syncthreads();
  for (int s = 128; s > 0; s >>= 1){ if (tid < s) red[tid] += red[tid + s]; __syncthreads(); }
  if (tid == 0) part[blockIdx.x] = red[0];
}

__global__ __launch_bounds__(256) void absmean_final_kernel(
    const float* __restrict__ part, int n, float invc, float* __restrict__ out)
{
  const int tid = threadIdx.x;
  float ssum = 0.f;
  for (int i = tid; i < n; i += 256) ssum += part[i];
  __shared__ float red[256];
  red[tid] = ssum; __syncthreads();
  for (int s = 128; s > 0; s >>= 1){ if (tid < s) red[tid] += red[tid + s]; __syncthreads(); }
  if (tid == 0) out[0] = fmaxf(red[0] * invc, 1e-5f);
}

__global__ __launch_bounds__(256) void ternarize_kernel(
    const void* __restrict__ w, const float* __restrict__ sp, u16* __restrict__ t,
    const unsigned* __restrict__ Fg)
{
  const bool f32 = Fg[0] != 0;
  const float s = sp[0];
  const size_t base = ((size_t)blockIdx.x * 256 + threadIdx.x) * 4;
  u16x4 o;
  #pragma unroll
  for (int i = 0; i < 4; i++){
    float vv = fminf(fmaxf(rintf(ldf(w, base + i, f32) / s), -1.f), 1.f);
    o[i] = f2b(vv);
  }
  *(u16x4*)&t[base] = o;
}

extern "C" void kernel_launch(void* const* d_in, const int* in_sizes, int n_in,
                              void* d_out, int out_size, void* d_ws, size_t ws_size,
                              hipStream_t stream)
{
  const void* x      = d_in[0];
  const void* enc    = d_in[1];
  const void* in_w   = d_in[3];
  const void* conv_w = d_in[4];
  const void* conv_b = d_in[5];
  const void* xproj_w= d_in[6];
  const void* dt_w   = d_in[7];
  const void* dt_b   = d_in[8];
  const void* A_log  = d_in[9];
  const void* Dp     = d_in[10];
  const void* out_w  = d_in[11];
  const void* n1w    = d_in[12];
  const void* q_w = d_in[13]; const void* q_b = d_in[14];
  const void* k_w = d_in[15]; const void* k_b = d_in[16];
  const void* v_w = d_in[17]; const void* v_b = d_in[18];
  const void* o_w = d_in[19]; const void* o_b = d_in[20];
  const void* n2w = d_in[21];
  const void* w1  = d_in[22]; const void* b1 = d_in[23];
  const void* w2  = d_in[24]; const void* b2 = d_in[25];
  const void* n3w = d_in[26];

  char* ws = (char*)d_ws;
  const size_t MB = 1ull << 20;
  const size_t KB = 1024;
  float*    sw1  = (float*)(ws + 0);
  float*    sw2  = (float*)(ws + 16);
  unsigned* Fg   = (unsigned*)(ws + 64);
  float*    s1   = (float*)(ws + 4096);
  float*    s2   = (float*)(ws + 12288);
  float*    part = (float*)(ws + 20480);
  // phase A transients
  u16*   xz   = (u16*)  (ws + 1 * MB);    // 1-17
  u16*   u    = (u16*)  (ws + 17 * MB);   // 17-25
  float* proj = (float*)(ws + 25 * MB);   // 25-26
  float* delta= (float*)(ws + 26 * MB);   // 26-42
  float* Pp   = (float*)(ws + 42 * MB);   // 42-48
  u16*   projb= (u16*)  (ws + 48 * MB);   // 48-48.5
  u16*   G    = (u16*)  (ws + 42 * MB);   // 42-50
  float* Ssc  = (float*)(ws + 50 * MB);   // 50-58
  float* Hin  = (float*)(ws + 58 * MB);   // 58-66
  float* sdl  = (float*)(ws + 66 * MB);   // 66-66.5
  float* Pm   = (float*)(ws + 50 * MB);   // 50-66 mout split-K partials
  u16*   h1b  = (u16*)  (ws + 26 * MB);   // 26-30
  float* h1f  = (float*)(ws + 30 * MB);   // 30-38
  // phase B transients
  u16*   qb   = (u16*)  (ws + 1 * MB);    // 1-5
  u16*   kb   = (u16*)  (ws + 5 * MB);    // 5-9
  u16*   vb   = (u16*)  (ws + 9 * MB);    // 9-13
  u16*   vtb  = (u16*)  (ws + 38 * MB);   // 38-42
  u16*   Opart= (u16*)  (ws + 42 * MB);   // 42-50
  float* Lpart= (float*)(ws + 66 * MB);   // 66-66.25
  u16*   ao   = (u16*)  (ws + 13 * MB);   // 13-17
  float* aof  = (float*)(ws + 17 * MB);   // 17-25
  float* h2f  = (float*)(ws + 58 * MB);   // 58-66
  // phase C transients
  u16*   q1   = (u16*)  (ws + 1 * MB);    // 1-5
  u16*   t1   = (u16*)  (ws + 5 * MB);    // 5-13
  u16*   t2   = (u16*)  (ws + 50 * MB);   // 50-58
  u16*   gh   = (u16*)  (ws + 13 * MB);   // 13-29
  u16*   q2   = (u16*)  (ws + 29 * MB);   // 29-45
  float* Pf2  = (float*)(ws + 98 * MB);   // 98-114 FFN2 split-K partials
  // persistent bf16 copies (68-97)
  u16* xb       = (u16*)(ws + 68 * MB);
  u16* encb     = (u16*)(ws + 72 * MB);
  u16* in_wb    = (u16*)(ws + 76 * MB);
  u16* out_wb   = (u16*)(ws + 84 * MB);
  u16* q_wb     = (u16*)(ws + 88 * MB);
  u16* k_wb     = (u16*)(ws + 90 * MB);   // k|v contiguous -> fused [2048][1024]
  u16* v_wb     = (u16*)(ws + 92 * MB);
  u16* o_wb     = (u16*)(ws + 94 * MB);
  u16* xproj_wb = (u16*)(ws + 96 * MB);
  u16* dt_wb    = (u16*)(ws + 96 * MB + 512 * KB);
  u16* dt_bb    = (u16*)(ws + 96 * MB + 768 * KB);
  u16* q_bb     = (u16*)(ws + 96 * MB + 776 * KB);
  u16* k_bb     = (u16*)(ws + 96 * MB + 778 * KB);  // k|v biases contiguous
  u16* v_bb     = (u16*)(ws + 96 * MB + 780 * KB);
  u16* o_bb     = (u16*)(ws + 96 * MB + 788 * KB);
  u16* b1b      = (u16*)(ws + 96 * MB + 792 * KB);
  u16* b2b      = (u16*)(ws + 96 * MB + 808 * KB);

  dim3 blk(256);
  detect_kernel<<<dim3(1), blk, 0, stream>>>(x, Fg);

  // 0b. convert all GEMM-facing externals to bf16
  {
    CvtJobs jobs;
    const void* srcs[NCVT] = { x, enc, in_w, out_w, q_w, k_w, v_w, o_w, xproj_w, dt_w,
                               dt_b, q_b, k_b, v_b, o_b, b1, b2 };
    u16* dsts[NCVT] = { xb, encb, in_wb, out_wb, q_wb, k_wb, v_wb, o_wb, xproj_wb, dt_wb,
                        dt_bb, q_bb, k_bb, v_bb, o_bb, b1b, b2b };
    int ns[NCVT] = { 2097152, 2097152, 4194304, 2097152, 1048576, 1048576, 1048576, 1048576,
                     196608, 131072, 2048, 1024, 1024, 1024, 1024, 4096, 1024 };
    int bo = 0;
    for (int j = 0; j < NCVT; j++){
      jobs.src[j] = srcs[j]; jobs.dst[j] = dsts[j]; jobs.n[j] = ns[j];
      jobs.blk_off[j] = bo;
      bo += (ns[j] / 8 + 255) / 256;
    }
    jobs.blk_off[NCVT] = bo;
    convert_kernel<<<dim3(bo), blk, 0, stream>>>(jobs, Fg);
  }

  // 1. xz = x @ in_w^T  (128x128)
  gemm16<0,4,4,2,2,false><<<dim3(32, 16), blk, 0, stream>>>(xb, in_wb, xz, 2048, 4096, 1024, 1024, 1024, 4096, nullptr, nullptr, nullptr, nullptr, nullptr);
  // 2. conv + SiLU
  conv_silu_kernel<<<dim3(16384), blk, 0, stream>>>(xz, conv_w, conv_b, u, Fg);
  // 3. proj = u @ xproj_w^T (split-K=8) + reduce
  gemm16<3,2,3,2,2,false><<<dim3(1, 32, 8), blk, 0, stream>>>(u, xproj_wb, Pp, 2048, 96, 256, 2048, 2048, 96, nullptr, nullptr, nullptr, nullptr, nullptr);
  xproj_reduce_kernel<<<dim3(768), blk, 0, stream>>>(Pp, proj, projb);
  // 4. delta = softplus(projb @ dt_w^T + dt_b)
  gemm16<6,2,2,2,2,false><<<dim3(32, 32), blk, 0, stream>>>(projb, dt_wb, delta, 2048, 2048, 64, 64, 64, 2048, dt_bb, nullptr, nullptr, nullptr, nullptr);
  // 5. chunked scan
  scan_part1<<<dim3(8, SNCH, 2), blk, 0, stream>>>(delta, u, proj, A_log, Ssc, sdl, Fg);
  scan_combine<<<dim3(16), blk, 0, stream>>>(Ssc, sdl, A_log, Hin, Fg);
  scan_part2<<<dim3(8, SNCH, 2), blk, 0, stream>>>(delta, u, proj, A_log, Dp, xz, Hin, G, Fg);
  // 6. mamba_out = G @ out_w^T  (split-K=2 -> 1024 blocks)
  gemm16<3,2,2,2,2,false><<<dim3(16, 32, 2), blk, 0, stream>>>(G, out_wb, Pm, 2048, 1024, 1024, 2048, 2048, 1024, nullptr, nullptr, nullptr, nullptr, nullptr);
  // 7. h1 = rmsnorm(x + P0 + P1)  (split-K combine fused)
  rmsnorm_fused<1><<<dim3(2048), blk, 0, stream>>>(x, 1, Pm, n1w, h1b, h1f, nullptr, Fg, nullptr, nullptr, nullptr, nullptr, nullptr);
  // 8. q projection + fused k|v projection (N=2048, SPLITC)
  gemm16<1,2,2,2,2,false><<<dim3(16, 32), blk, 0, stream>>>(h1b, q_wb, qb, 2048, 1024, 1024, 1024, 1024, 1024, q_bb, nullptr, nullptr, nullptr, nullptr);
  gemm16<1,2,2,2,2,true><<<dim3(32, 32), blk, 0, stream>>>(encb, k_wb, kb, 2048, 2048, 1024, 1024, 1024, 1024, k_bb, nullptr, nullptr, vb, nullptr);
  // 8b. V transpose
  vtrans_kernel<<<dim3(16, 32), blk, 0, stream>>>(vb, vtb);
  // 9. multi-wave LDS-staged flash attention + combine
  attn_mw_kernel<<<dim3(16, 32, ASPL), blk, 0, stream>>>(qb, kb, vtb, Opart, Lpart);
  attn_combine_kernel<<<dim3(2048), blk, 0, stream>>>(Opart, Lpart, ao);
  // 10. o projection
  gemm16<2,2,2,2,2,false><<<dim3(16, 32), blk, 0, stream>>>(ao, o_wb, aof, 2048, 1024, 1024, 1024, 1024, 1024, o_bb, nullptr, nullptr, nullptr, nullptr);
  // 11+12. h2 = rmsnorm(h1 + attn), act_quant fused -> q1,s1
  rmsnorm_fused<0><<<dim3(2048), blk, 0, stream>>>(h1f, 0, aof, n2w, nullptr, h2f, nullptr, Fg, q1, s1, nullptr, nullptr, nullptr);
  // 13. weight_quant(w1), weight_quant(w2)
  absmean_partial_kernel<<<dim3(4096), blk, 0, stream>>>(w1, part, Fg);
  absmean_final_kernel<<<dim3(1), blk, 0, stream>>>(part, 4096, 1.f / 4194304.f, sw1);
  ternarize_kernel<<<dim3(4096), blk, 0, stream>>>(w1, sw1, t1, Fg);
  absmean_partial_kernel<<<dim3(4096), blk, 0, stream>>>(w2, part, Fg);
  absmean_final_kernel<<<dim3(1), blk, 0, stream>>>(part, 4096, 1.f / 4194304.f, sw2);
  ternarize_kernel<<<dim3(4096), blk, 0, stream>>>(w2, sw2, t2, Fg);
  // 14. ffn hidden = gelu(q1 @ t1^T * s1*sw1 + b1) -> bf16  (128x128)
  gemm16<4,4,4,2,2,false><<<dim3(32, 16), blk, 0, stream>>>(q1, t1, gh, 2048, 4096, 1024, 1024, 1024, 4096, b1b, s1, sw1, nullptr, nullptr);
  // 15. act_quant(gh)
  actquant_kernel<<<dim3(2048), blk, 0, stream>>>(gh, 0, q2, s2, 4096);
  // 16. ffn out partials (split-K=2 -> 1024 blocks)
  gemm16<3,2,2,2,2,false><<<dim3(16, 32, 2), blk, 0, stream>>>(q2, t2, Pf2, 2048, 1024, 2048, 4096, 4096, 1024, nullptr, nullptr, nullptr, nullptr, nullptr);
  // 17. out = rmsnorm(h2 + (P0+P1)*s2*sw2 + b2) -> d_out  (combine fused)
  rmsnorm_fused<2><<<dim3(2048), blk, 0, stream>>>(h2f, 0, Pf2, n3w, nullptr, nullptr, d_out, Fg, nullptr, nullptr, s2, sw2, b2b);
}

// Round 13
// 386.222 us; speedup vs baseline: 1.3062x; 1.0278x over previous
//
#include <hip/hip_runtime.h>
#include <math.h>

#define DEV __device__ __forceinline__
using u16 = unsigned short;
typedef __bf16 bh8 __attribute__((ext_vector_type(8)));
typedef float f32x4 __attribute__((ext_vector_type(4)));
typedef u16 u16x8 __attribute__((ext_vector_type(8)));
typedef u16 u16x4 __attribute__((ext_vector_type(4)));

DEV float b2f(u16 x){ unsigned u = ((unsigned)x) << 16; float f; __builtin_memcpy(&f, &u, 4); return f; }
DEV u16 f2b(float f){ unsigned u; __builtin_memcpy(&u, &f, 4); return (u16)((u + 0x7fffu + ((u >> 16) & 1u)) >> 16); }
DEV float sigm(float x){ return 1.f / (1.f + __expf(-x)); }
DEV float ldf(const void* p, size_t i, bool f32){ return f32 ? ((const float*)p)[i] : b2f(((const u16*)p)[i]); }

// ---------------- dtype detect ----------------
__global__ __launch_bounds__(256) void detect_kernel(const void* x, unsigned* flag)
{
  const int tid = threadIdx.x;
  const u16* p = (const u16*)x;
  int sane = 0;
  #pragma unroll
  for (int j = 0; j < 8; j++){
    u16 v = p[(size_t)(tid * 8 + j) * 2];
    int e = (v >> 7) & 0xFF;
    sane += (e >= 0x60 && e <= 0x8F) ? 1 : 0;
  }
  __shared__ int red[256];
  red[tid] = sane; __syncthreads();
  for (int s = 128; s > 0; s >>= 1){ if (tid < s) red[tid] += red[tid + s]; __syncthreads(); }
  if (tid == 0) flag[0] = (red[0] < 1200) ? 1u : 0u;
}

// ---------------- batch convert external -> bf16 ws ----------------
#define NCVT 17
struct CvtJobs {
  const void* src[NCVT];
  u16* dst[NCVT];
  int n[NCVT];
  int blk_off[NCVT + 1];
};
__global__ __launch_bounds__(256) void convert_kernel(CvtJobs jobs, const unsigned* __restrict__ Fg)
{
  const bool f32 = Fg[0] != 0;
  const int bx = blockIdx.x;
  int j = 0;
  while (bx >= jobs.blk_off[j + 1]) j++;
  const int e = (bx - jobs.blk_off[j]) * 2048 + threadIdx.x * 8;
  if (e >= jobs.n[j]) return;
  if (f32){
    const float* s = (const float*)jobs.src[j] + e;
    u16x8 o;
    #pragma unroll
    for (int i = 0; i < 8; i++) o[i] = f2b(s[i]);
    *(u16x8*)(jobs.dst[j] + e) = o;
  } else {
    *(u16x8*)(jobs.dst[j] + e) = *(const u16x8*)((const u16*)jobs.src[j] + e);
  }
}

// ---------------- reg-staged BK=64 swizzled MFMA GEMM, XCD-aware block remap ----------------
// EPI: 0 bf16  1 bf16+bias  2 f32+bias  3 f32 (split-K partial)
// 4 bf16=gelu(acc*rs*ws+bias)  5 f32=acc*rs*ws+bias  6 f32=softplus(acc+bias)
// SPLITC: route 1024-col groups to Cv/Cv1/Cv2 (each ldc=1024).
template<int EPI, int FM, int FN, int WR, int WC, bool SPLITC>
__global__ __launch_bounds__(256) void gemm16(
    const u16* __restrict__ A, const u16* __restrict__ W, void* __restrict__ Cv,
    int M, int N, int K, int lda, int ldb, int ldc,
    const u16* __restrict__ bias, const float* __restrict__ rowscale,
    const float* __restrict__ wscale, void* __restrict__ Cv1, void* __restrict__ Cv2)
{
  constexpr int BM = WR * FM * 16, BN = WC * FN * 16;
  __shared__ __align__(16) char As[BM * 128];
  __shared__ __align__(16) char Bs[BN * 128];
  const int tid = threadIdx.x, wave = tid >> 6, lane = tid & 63;
  const int wr = wave / WC, wc = wave % WC, fr = lane & 15, g = lane >> 4;
  // XCD-aware bijective remap (T1): HW round-robins dispatch index over 8 XCDs;
  // give each XCD a contiguous chunk of work so shared A-panels stay in its L2.
  int bix = blockIdx.x, biy = blockIdx.y, biz = blockIdx.z;
  {
    const int gx = gridDim.x, gy = gridDim.y;
    const int nwg = gx * gy * gridDim.z;
    if ((nwg & 7) == 0){
      int flat = bix + gx * (biy + gy * biz);
      int swz = (flat & 7) * (nwg >> 3) + (flat >> 3);
      bix = swz % gx; swz /= gx;
      biy = swz % gy; biz = swz / gy;
    }
  }
  const size_t bm = (size_t)biy * BM, bn = (size_t)bix * BN;
  const int kbase = biz * K;
  f32x4 acc[FM][FN] = {};
  constexpr int ACH = BM / 32, BCH = BN / 32;
  u16x8 areg[ACH], breg[BCH];
  auto fetch = [&](int k0){
    #pragma unroll
    for (int c = 0; c < ACH; c++){
      int li = tid + c * 256;
      areg[c] = *(const u16x8*)&A[(bm + (li >> 3)) * (size_t)lda + kbase + k0 + ((li & 7) << 3)];
    }
    #pragma unroll
    for (int c = 0; c < BCH; c++){
      int li = tid + c * 256;
      breg[c] = *(const u16x8*)&W[(bn + (li >> 3)) * (size_t)ldb + kbase + k0 + ((li & 7) << 3)];
    }
  };
  fetch(0);
  for (int k0 = 0; k0 < K; k0 += 64){
    __syncthreads();
    #pragma unroll
    for (int c = 0; c < ACH; c++){
      int li = tid + c * 256, row = li >> 3, j = li & 7;
      *(u16x8*)&As[row * 128 + ((j * 16) ^ ((row & 7) << 4))] = areg[c];
    }
    #pragma unroll
    for (int c = 0; c < BCH; c++){
      int li = tid + c * 256, row = li >> 3, j = li & 7;
      *(u16x8*)&Bs[row * 128 + ((j * 16) ^ ((row & 7) << 4))] = breg[c];
    }
    __syncthreads();
    if (k0 + 64 < K) fetch(k0 + 64);
    bh8 af[2][FM], bf[2][FN];
    #pragma unroll
    for (int ks = 0; ks < 2; ks++){
      #pragma unroll
      for (int i = 0; i < FM; i++){
        int row = wr * (FM * 16) + i * 16 + fr;
        af[ks][i] = *(const bh8*)&As[row * 128 + ((ks * 64 + g * 16) ^ ((row & 7) << 4))];
      }
      #pragma unroll
      for (int j = 0; j < FN; j++){
        int row = wc * (FN * 16) + j * 16 + fr;
        bf[ks][j] = *(const bh8*)&Bs[row * 128 + ((ks * 64 + g * 16) ^ ((row & 7) << 4))];
      }
    }
    #pragma unroll
    for (int ks = 0; ks < 2; ks++)
      #pragma unroll
      for (int i = 0; i < FM; i++)
        #pragma unroll
        for (int j = 0; j < FN; j++)
          acc[i][j] = __builtin_amdgcn_mfma_f32_16x16x32_bf16(af[ks][i], bf[ks][j], acc[i][j], 0, 0, 0);
  }
  float wsc = 0.f;
  if constexpr (EPI == 4 || EPI == 5) wsc = wscale[0];
  u16* Cb = (u16*)Cv;
  float* Cf = (float*)Cv + (size_t)biz * M * ldc;
  #pragma unroll
  for (int i = 0; i < FM; i++){
    #pragma unroll
    for (int r = 0; r < 4; r++){
      const size_t row = bm + wr * (FM * 16) + i * 16 + g * 4 + r;
      float rs = 0.f;
      if constexpr (EPI == 4 || EPI == 5) rs = rowscale[row] * wsc;
      #pragma unroll
      for (int j = 0; j < FN; j++){
        const size_t col = bn + wc * (FN * 16) + j * 16 + fr;
        float v = acc[i][j][r];
        if constexpr (EPI == 1 || EPI == 2) v += b2f(bias[col]);
        if constexpr (EPI == 4 || EPI == 5) v = v * rs + b2f(bias[col]);
        if constexpr (EPI == 4){ float x = v; v = 0.5f * x * (1.f + tanhf(0.7978845608f * (x + 0.044715f * x * x * x))); }
        if constexpr (EPI == 6){ float x = v + b2f(bias[col]); v = fmaxf(x, 0.f) + log1pf(__expf(-fabsf(x))); }
        if constexpr (EPI == 0 || EPI == 1 || EPI == 4){
          u16* CbX = Cb; size_t cc = col;
          if constexpr (SPLITC){
            int wq = (int)(col >> 10);
            CbX = wq == 0 ? Cb : (wq == 1 ? (u16*)Cv1 : (u16*)Cv2);
            cc = col & 1023;
          }
          CbX[row * ldc + cc] = f2b(v);
        } else Cf[row * ldc + col] = v;
      }
    }
  }
}

// ---------------- xproj split-K reduce ----------------
__global__ __launch_bounds__(256) void xproj_reduce_kernel(
    const float* __restrict__ Pp, float* __restrict__ proj, u16* __restrict__ projb)
{
  const int idx = blockIdx.x * 256 + threadIdx.x;
  const int m = idx / 96, n = idx % 96;
  float s = 0.f;
  #pragma unroll
  for (int z = 0; z < 8; z++) s += Pp[(size_t)z * 2048 * 96 + idx];
  proj[idx] = s;
  if (n < 64) projb[(size_t)m * 64 + n] = f2b(s);
}

// ---------------- causal depthwise conv (D_CONV=4) + SiLU ----------------
__global__ __launch_bounds__(256) void conv_silu_kernel(
    const u16* __restrict__ xz, const void* __restrict__ cw, const void* __restrict__ cb,
    u16* __restrict__ u, const unsigned* __restrict__ Fg)
{
  const bool f32 = Fg[0] != 0;
  const int idx = blockIdx.x * 256 + threadIdx.x;
  const int c = idx & 2047;
  const int bt = idx >> 11;
  const int t = bt & 1023, b = bt >> 10;
  float acc = ldf(cb, c, f32);
  #pragma unroll
  for (int j = 0; j < 4; j++){
    int tt = t - 3 + j;
    if (tt >= 0) acc += b2f(xz[(size_t)(b * 1024 + tt) * 4096 + c]) * ldf(cw, c * 4 + j, f32);
  }
  u[(size_t)bt * 2048 + c] = f2b(acc * sigm(acc));
}

// ---------------- chunked selective scan ----------------
#define SCH 32
#define SNCH 32

__global__ __launch_bounds__(256) void scan_part1(
    const float* __restrict__ delta, const u16* __restrict__ u,
    const float* __restrict__ proj, const void* __restrict__ Alog,
    float* __restrict__ S, float* __restrict__ sumdl_o, const unsigned* __restrict__ Fg)
{
  const bool f32 = Fg[0] != 0;
  const int b = blockIdx.z, ch = blockIdx.y, d = blockIdx.x * 256 + threadIdx.x;
  float A[16], h[16];
  #pragma unroll
  for (int s = 0; s < 16; s++){ A[s] = -__expf(ldf(Alog, d * 16 + s, f32)); h[s] = 0.f; }
  __shared__ __align__(16) float Bsh[SCH][16];
  {
    int tc = threadIdx.x >> 3, j = (threadIdx.x & 7) * 2;
    *(float2*)&Bsh[tc][j] = *(const float2*)&proj[(size_t)(b * 1024 + ch * SCH + tc) * 96 + 64 + j];
  }
  __syncthreads();
  float sumdl = 0.f;
  for (int tt = 0; tt < SCH; tt++){
    const size_t m = (size_t)(b * 1024 + ch * SCH + tt);
    const float dl = delta[m * 2048 + d];
    const float du = dl * b2f(u[m * 2048 + d]);
    sumdl += dl;
    #pragma unroll
    for (int s = 0; s < 16; s++) h[s] = __expf(dl * A[s]) * h[s] + du * Bsh[tt][s];
  }
  #pragma unroll
  for (int s = 0; s < 16; s++) S[((size_t)(b * SNCH + ch) * 16 + s) * 2048 + d] = h[s];
  sumdl_o[(size_t)(b * SNCH + ch) * 2048 + d] = sumdl;
}

__global__ __launch_bounds__(256) void scan_combine(
    const float* __restrict__ S, const float* __restrict__ sumdl,
    const void* __restrict__ Alog, float* __restrict__ Hin, const unsigned* __restrict__ Fg)
{
  const bool f32 = Fg[0] != 0;
  const int idx = blockIdx.x * 256 + threadIdx.x;
  const int b = idx >> 11, d = idx & 2047;
  float A[16], h[16];
  #pragma unroll
  for (int s = 0; s < 16; s++){ A[s] = -__expf(ldf(Alog, d * 16 + s, f32)); h[s] = 0.f; }
  for (int ch = 0; ch < SNCH; ch++){
    const float sd = sumdl[(size_t)(b * SNCH + ch) * 2048 + d];
    #pragma unroll
    for (int s = 0; s < 16; s++){
      const size_t off = ((size_t)(b * SNCH + ch) * 16 + s) * 2048 + d;
      Hin[off] = h[s];
      h[s] = __expf(A[s] * sd) * h[s] + S[off];
    }
  }
}

__global__ __launch_bounds__(256) void scan_part2(
    const float* __restrict__ delta, const u16* __restrict__ u,
    const float* __restrict__ proj, const void* __restrict__ Alog,
    const void* __restrict__ Dp, const u16* __restrict__ xz,
    const float* __restrict__ Hin, u16* __restrict__ G, const unsigned* __restrict__ Fg)
{
  const bool f32 = Fg[0] != 0;
  const int b = blockIdx.z, ch = blockIdx.y, d = blockIdx.x * 256 + threadIdx.x;
  float A[16], h[16];
  #pragma unroll
  for (int s = 0; s < 16; s++){
    A[s] = -__expf(ldf(Alog, d * 16 + s, f32));
    h[s] = Hin[((size_t)(b * SNCH + ch) * 16 + s) * 2048 + d];
  }
  const float Dv = ldf(Dp, d, f32);
  __shared__ __align__(16) float BCs[SCH][32];
  {
    int tc = threadIdx.x >> 3, j = (threadIdx.x & 7) * 4;
    *(float4*)&BCs[tc][j] = *(const float4*)&proj[(size_t)(b * 1024 + ch * SCH + tc) * 96 + 64 + j];
  }
  __syncthreads();
  for (int tt = 0; tt < SCH; tt++){
    const size_t m = (size_t)(b * 1024 + ch * SCH + tt);
    const float dl = delta[m * 2048 + d];
    const float uv = b2f(u[m * 2048 + d]);
    const float du = dl * uv;
    float y = 0.f;
    #pragma unroll
    for (int s = 0; s < 16; s++){
      h[s] = __expf(dl * A[s]) * h[s] + du * BCs[tt][s];
      y += h[s] * BCs[tt][16 + s];
    }
    y += uv * Dv;
    const float r = b2f(xz[m * 4096 + 2048 + d]);
    G[m * 2048 + d] = f2b(y * (r * sigm(r)));
  }
}

// ---------------- V transpose ----------------
__global__ __launch_bounds__(256) void vtrans_kernel(const u16* __restrict__ V, u16* __restrict__ Vt)
{
  __shared__ __align__(16) u16 T[64 * 64];
  const int bh = blockIdx.y, b = bh >> 4, hh = bh & 15;
  const int s0 = blockIdx.x * 64;
  const int tid = threadIdx.x;
  {
    int s = tid & 63, d0 = (tid >> 6) * 16;
    const u16* src = V + ((size_t)(b * 1024 + s0 + s)) * 1024 + hh * 64 + d0;
    u16x8 v0 = *(const u16x8*)src, v1 = *(const u16x8*)(src + 8);
    int byte0 = (s * 128 + d0 * 2) ^ ((s & 7) << 4);
    int byte1 = (s * 128 + d0 * 2 + 16) ^ ((s & 7) << 4);
    *(u16x8*)((char*)T + byte0) = v0;
    *(u16x8*)((char*)T + byte1) = v1;
  }
  __syncthreads();
  {
    int d = tid & 63, t0 = (tid >> 6) * 16;
    u16x8 w0, w1;
    #pragma unroll
    for (int j = 0; j < 8; j++){
      int r0 = t0 + j, r1 = t0 + 8 + j;
      w0[j] = *(const u16*)((char*)T + ((r0 * 128 + d * 2) ^ ((r0 & 7) << 4)));
      w1[j] = *(const u16*)((char*)T + ((r1 * 128 + d * 2) ^ ((r1 & 7) << 4)));
    }
    u16* dst = Vt + ((size_t)bh * 64 + d) * 1024 + s0 + t0;
    *(u16x8*)dst = w0;
    *(u16x8*)(dst + 8) = w1;
  }
}

// ---------------- multi-wave MFMA flash cross-attention, LDS-staged K/V ----------------
#define ASPL 2
__global__ __launch_bounds__(256) void attn_mw_kernel(
    const u16* __restrict__ Q, const u16* __restrict__ Kb, const u16* __restrict__ Vt,
    u16* __restrict__ Opart, float* __restrict__ Lpart)
{
  const int bh = blockIdx.y, b = bh >> 4, hh = bh & 15;
  const int z = blockIdx.z;
  const int tid = threadIdx.x, wave = tid >> 6, lane = tid & 63;
  const int fr = lane & 15, g = lane >> 4;
  const int q0 = blockIdx.x * 64 + wave * 16;
  __shared__ __align__(16) char Ks[64 * 128];
  __shared__ __align__(16) char Vs[64 * 128];
  __shared__ __align__(16) u16 Pl[4][1024];
  const u16* qp = Q + ((size_t)(b * 1024 + q0 + fr)) * 1024 + hh * 64 + g * 8;
  const bh8 aq0 = *(const bh8*)qp;
  const bh8 aq1 = *(const bh8*)(qp + 32);
  f32x4 oacc[4] = {};
  float lsum[4] = {};
  const u16* kbase = Kb + ((size_t)(b * 1024)) * 1024 + hh * 64;
  const u16* vbase = Vt + ((size_t)bh * 64) * 1024;
  const int srow = tid >> 2, sj = (tid & 3) * 2;
  for (int s0 = z * (1024 / ASPL); s0 < (z + 1) * (1024 / ASPL); s0 += 64){
    __syncthreads();
    {
      const u16* kr = kbase + (size_t)(s0 + srow) * 1024 + sj * 8;
      u16x8 k0 = *(const u16x8*)kr, k1 = *(const u16x8*)(kr + 8);
      *(u16x8*)&Ks[srow * 128 + ((sj * 16) ^ ((srow & 7) << 4))] = k0;
      *(u16x8*)&Ks[srow * 128 + (((sj + 1) * 16) ^ ((srow & 7) << 4))] = k1;
      const u16* vr = vbase + (size_t)srow * 1024 + s0 + sj * 8;
      u16x8 v0 = *(const u16x8*)vr, v1 = *(const u16x8*)(vr + 8);
      *(u16x8*)&Vs[srow * 128 + ((sj * 16) ^ ((srow & 7) << 4))] = v0;
      *(u16x8*)&Vs[srow * 128 + (((sj + 1) * 16) ^ ((srow & 7) << 4))] = v1;
    }
    __syncthreads();
    bh8 bk[4][2], bv[2][4];
    #pragma unroll
    for (int ct = 0; ct < 4; ct++){
      int row = 16 * ct + fr;
      #pragma unroll
      for (int ks = 0; ks < 2; ks++)
        bk[ct][ks] = *(const bh8*)&Ks[row * 128 + ((ks * 64 + g * 16) ^ ((row & 7) << 4))];
    }
    #pragma unroll
    for (int dt = 0; dt < 4; dt++){
      int row = 16 * dt + fr;
      #pragma unroll
      for (int ks = 0; ks < 2; ks++)
        bv[ks][dt] = *(const bh8*)&Vs[row * 128 + ((ks * 64 + g * 16) ^ ((row & 7) << 4))];
    }
    #pragma unroll
    for (int ct = 0; ct < 4; ct++){
      f32x4 zz = {};
      zz = __builtin_amdgcn_mfma_f32_16x16x32_bf16(aq0, bk[ct][0], zz, 0, 0, 0);
      zz = __builtin_amdgcn_mfma_f32_16x16x32_bf16(aq1, bk[ct][1], zz, 0, 0, 0);
      #pragma unroll
      for (int r = 0; r < 4; r++){
        float p = __expf(zz[r] * 0.125f);
        u16 pb = f2b(p);
        lsum[r] += b2f(pb);
        int row = 4 * g + r, col = 16 * ct + fr;
        *(u16*)((char*)&Pl[wave][0] + ((row * 128 + col * 2) ^ ((row & 7) << 4))) = pb;
      }
    }
    bh8 pa[2];
    #pragma unroll
    for (int ks = 0; ks < 2; ks++)
      pa[ks] = *(const bh8*)((char*)&Pl[wave][0] + ((fr * 128 + (ks * 32 + g * 8) * 2) ^ ((fr & 7) << 4)));
    #pragma unroll
    for (int dt = 0; dt < 4; dt++){
      oacc[dt] = __builtin_amdgcn_mfma_f32_16x16x32_bf16(pa[0], bv[0][dt], oacc[dt], 0, 0, 0);
      oacc[dt] = __builtin_amdgcn_mfma_f32_16x16x32_bf16(pa[1], bv[1][dt], oacc[dt], 0, 0, 0);
    }
  }
  #pragma unroll
  for (int r = 0; r < 4; r++){
    #pragma unroll
    for (int d2 = 1; d2 < 16; d2 <<= 1) lsum[r] += __shfl_xor(lsum[r], d2);
  }
  u16* opz = Opart + (size_t)z * 2097152;
  #pragma unroll
  for (int r = 0; r < 4; r++){
    const int tok = b * 1024 + q0 + 4 * g + r;
    #pragma unroll
    for (int dt = 0; dt < 4; dt++)
      opz[(size_t)tok * 1024 + hh * 64 + 16 * dt + fr] = f2b(oacc[dt][r]);
    if (fr == 0) Lpart[(size_t)z * 32768 + tok * 16 + hh] = lsum[r];
  }
}

__global__ __launch_bounds__(256) void attn_combine_kernel(
    const u16* __restrict__ Opart, const float* __restrict__ Lpart, u16* __restrict__ O)
{
  const int tok = blockIdx.x, tid = threadIdx.x;
  const int c = tid * 4, hh = c >> 6;
  float l = 0.f;
  #pragma unroll
  for (int z = 0; z < ASPL; z++) l += Lpart[(size_t)z * 32768 + tok * 16 + hh];
  float acc[4] = {};
  #pragma unroll
  for (int z = 0; z < ASPL; z++){
    u16x4 v = *(const u16x4*)&Opart[(size_t)z * 2097152 + (size_t)tok * 1024 + c];
    #pragma unroll
    for (int j = 0; j < 4; j++) acc[j] += b2f(v[j]);
  }
  const float inv = 1.f / l;
  u16x4 ov;
  #pragma unroll
  for (int j = 0; j < 4; j++) ov[j] = f2b(acc[j] * inv);
  *(u16x4*)&O[(size_t)tok * 1024 + c] = ov;
}

// ---------------- fused rmsnorm ----------------
// MODE 0: v = a + bsrc              (+ optional act-quant of output -> qout,srow)
// MODE 1: v = a + P0 + P1           (mout split-K combine folded in)
// MODE 2: v = a + (P0+P1)*s2[row]*sw2 + bias2[col]   (FFN2 combine folded in)
template<int MODE>
__global__ __launch_bounds__(256) void rmsnorm_fused(
    const void* __restrict__ a, int aIn, const float* __restrict__ bsrc,
    const void* __restrict__ w, u16* __restrict__ outb, float* __restrict__ outf,
    void* __restrict__ dout, const unsigned* __restrict__ Fg,
    u16* __restrict__ qout, float* __restrict__ srow,
    const float* __restrict__ s2, const float* __restrict__ sw2, const u16* __restrict__ bias2)
{
  const bool f32 = Fg[0] != 0;
  const bool a32 = aIn ? f32 : true;
  const int row = blockIdx.x, tid = threadIdx.x;
  const size_t base = (size_t)row * 1024 + tid * 4;
  float v[4];
  if (a32){
    float4 t = *(const float4*)&((const float*)a)[base];
    v[0] = t.x; v[1] = t.y; v[2] = t.z; v[3] = t.w;
  } else {
    u16x4 t = *(const u16x4*)&((const u16*)a)[base];
    v[0] = b2f(t[0]); v[1] = b2f(t[1]); v[2] = b2f(t[2]); v[3] = b2f(t[3]);
  }
  if constexpr (MODE == 0){
    float4 t2 = *(const float4*)&bsrc[base];
    v[0] += t2.x; v[1] += t2.y; v[2] += t2.z; v[3] += t2.w;
  }
  if constexpr (MODE == 1){
    float4 p0 = *(const float4*)&bsrc[base];
    float4 p1 = *(const float4*)&bsrc[2097152 + base];
    v[0] += p0.x + p1.x; v[1] += p0.y + p1.y; v[2] += p0.z + p1.z; v[3] += p0.w + p1.w;
  }
  if constexpr (MODE == 2){
    const float rs = s2[row] * sw2[0];
    float4 p0 = *(const float4*)&bsrc[base];
    float4 p1 = *(const float4*)&bsrc[2097152 + base];
    u16x4 bb = *(const u16x4*)&bias2[tid * 4];
    v[0] += (p0.x + p1.x) * rs + b2f(bb[0]);
    v[1] += (p0.y + p1.y) * rs + b2f(bb[1]);
    v[2] += (p0.z + p1.z) * rs + b2f(bb[2]);
    v[3] += (p0.w + p1.w) * rs + b2f(bb[3]);
  }
  float ss = v[0]*v[0] + v[1]*v[1] + v[2]*v[2] + v[3]*v[3];
  __shared__ float red[256];
  red[tid] = ss; __syncthreads();
  for (int s = 128; s > 0; s >>= 1){ if (tid < s) red[tid] += red[tid + s]; __syncthreads(); }
  const float scale = rsqrtf(red[0] * (1.f / 1024.f) + 1e-6f);
  float o[4];
  #pragma unroll
  for (int i = 0; i < 4; i++) o[i] = v[i] * scale * ldf(w, tid * 4 + i, f32);
  if (outb){
    u16x4 ov;
    #pragma unroll
    for (int i = 0; i < 4; i++) ov[i] = f2b(o[i]);
    *(u16x4*)&outb[base] = ov;
  }
  if (outf) *(float4*)&outf[base] = make_float4(o[0], o[1], o[2], o[3]);
  if (dout){
    if (f32) ((float*)dout)[base] = o[0], ((float*)dout)[base+1] = o[1], ((float*)dout)[base+2] = o[2], ((float*)dout)[base+3] = o[3];
    else {
      u16x4 ov;
      #pragma unroll
      for (int i = 0; i < 4; i++) ov[i] = f2b(o[i]);
      *(u16x4*)&((u16*)dout)[base] = ov;
    }
  }
  if (qout){
    float amax = fmaxf(fmaxf(fabsf(o[0]), fabsf(o[1])), fmaxf(fabsf(o[2]), fabsf(o[3])));
    __syncthreads();
    red[tid] = amax; __syncthreads();
    for (int s = 128; s > 0; s >>= 1){ if (tid < s) red[tid] = fmaxf(red[tid], red[tid + s]); __syncthreads(); }
    const float s = fmaxf(red[0], 1e-5f) * (1.f / 127.f);
    if (tid == 0) srow[row] = s;
    u16x4 qv;
    #pragma unroll
    for (int i = 0; i < 4; i++) qv[i] = f2b(fminf(fmaxf(rintf(o[i] / s), -128.f), 127.f));
    *(u16x4*)&qout[base] = qv;
  }
}

// ---------------- per-token 8-bit absmax act quant (gh path only) ----------------
__global__ __launch_bounds__(256) void actquant_kernel(
    const void* __restrict__ in, int inF32, u16* __restrict__ q, float* __restrict__ srow, int N)
{
  const int row = blockIdx.x, tid = threadIdx.x;
  float amax = 0.f;
  for (int c = tid * 4; c < N; c += 1024){
    #pragma unroll
    for (int j = 0; j < 4; j++){
      float x = inF32 ? ((const float*)in)[(size_t)row * N + c + j] : b2f(((const u16*)in)[(size_t)row * N + c + j]);
      amax = fmaxf(amax, fabsf(x));
    }
  }
  __shared__ float red[256];
  red[tid] = amax; __syncthreads();
  for (int s = 128; s > 0; s >>= 1){ if (tid < s) red[tid] = fmaxf(red[tid], red[tid + s]); __syncthreads(); }
  const float s = fmaxf(red[0], 1e-5f) * (1.f / 127.f);
  if (tid == 0) srow[row] = s;
  for (int c = tid * 4; c < N; c += 1024){
    u16x4 ov;
    #pragma unroll
    for (int j = 0; j < 4; j++){
      float x = inF32 ? ((const float*)in)[(size_t)row * N + c + j] : b2f(((const u16*)in)[(size_t)row * N + c + j]);
      ov[j] = f2b(fminf(fmaxf(rintf(x / s), -128.f), 127.f));
    }
    *(u16x4*)&q[(size_t)row * N + c] = ov;
  }
}

// ---------------- BitNet weight quant (both weights per launch) ----------------
__global__ __launch_bounds__(256) void absmean_partial2_kernel(
    const void* __restrict__ w1, const void* __restrict__ w2,
    float* __restrict__ part, const unsigned* __restrict__ Fg)
{
  const bool f32 = Fg[0] != 0;
  const int tid = threadIdx.x;
  const int bid = blockIdx.x;
  const void* w = (bid < 4096) ? w1 : w2;
  const size_t base = (size_t)(bid & 4095) * 1024 + tid * 4;
  float ssum = 0.f;
  #pragma unroll
  for (int j = 0; j < 4; j++) ssum += fabsf(ldf(w, base + j, f32));
  __shared__ float red[256];
  red[tid] = ssum; __syncthreads();
  for (int s = 128; s > 0; s >>= 1){ if (tid < s) red[tid] += red[tid + s]; __syncthreads(); }
  if (tid == 0) part[bid] = red[0];
}

__global__ __launch_bounds__(256) void absmean_final2_kernel(
    const float* __restrict__ part, float* __restrict__ sw1, float* __restrict__ sw2)
{
  const int tid = threadIdx.x;
  const int off = blockIdx.x * 4096;
  float ssum = 0.f;
  for (int i = tid; i < 4096; i += 256) ssum += part[off + i];
  __shared__ float red[256];
  red[tid] = ssum; __syncthreads();
  for (int s = 128; s > 0; s >>= 1){ if (tid < s) red[tid] += red[tid + s]; __syncthreads(); }
  if (tid == 0){
    float* out = blockIdx.x == 0 ? sw1 : sw2;
    out[0] = fmaxf(red[0] * (1.f / 4194304.f), 1e-5f);
  }
}

__global__ __launch_bounds__(256) void ternarize2_kernel(
    const void* __restrict__ w1, const void* __restrict__ w2,
    const float* __restrict__ sp1, const float* __restrict__ sp2,
    u16* __restrict__ t1, u16* __restrict__ t2, const unsigned* __restrict__ Fg)
{
  const bool f32 = Fg[0] != 0;
  const int bid = blockIdx.x;
  const bool second = bid >= 4096;
  const void* w = second ? w2 : w1;
  u16* t = second ? t2 : t1;
  const float s = (second ? sp2 : sp1)[0];
  const size_t base = ((size_t)(bid & 4095) * 256 + threadIdx.x) * 4;
  u16x4 o;
  #pragma unroll
  for (int i = 0; i < 4; i++){
    float vv = fminf(fmaxf(rintf(ldf(w, base + i, f32) / s), -1.f), 1.f);
    o[i] = f2b(vv);
  }
  *(u16x4*)&t[base] = o;
}

extern "C" void kernel_launch(void* const* d_in, const int* in_sizes, int n_in,
                              void* d_out, int out_size, void* d_ws, size_t ws_size,
                              hipStream_t stream)
{
  const void* x      = d_in[0];
  const void* enc    = d_in[1];
  const void* in_w   = d_in[3];
  const void* conv_w = d_in[4];
  const void* conv_b = d_in[5];
  const void* xproj_w= d_in[6];
  const void* dt_w   = d_in[7];
  const void* dt_b   = d_in[8];
  const void* A_log  = d_in[9];
  const void* Dp     = d_in[10];
  const void* out_w  = d_in[11];
  const void* n1w    = d_in[12];
  const void* q_w = d_in[13]; const void* q_b = d_in[14];
  const void* k_w = d_in[15]; const void* k_b = d_in[16];
  const void* v_w = d_in[17]; const void* v_b = d_in[18];
  const void* o_w = d_in[19]; const void* o_b = d_in[20];
  const void* n2w = d_in[21];
  const void* w1  = d_in[22]; const void* b1 = d_in[23];
  const void* w2  = d_in[24]; const void* b2 = d_in[25];
  const void* n3w = d_in[26];

  char* ws = (char*)d_ws;
  const size_t MB = 1ull << 20;
  const size_t KB = 1024;
  float*    sw1  = (float*)(ws + 0);
  float*    sw2  = (float*)(ws + 16);
  unsigned* Fg   = (unsigned*)(ws + 64);
  float*    s1   = (float*)(ws + 4096);
  float*    s2   = (float*)(ws + 12288);
  float*    part = (float*)(ws + 20480);   // 8192 floats = 32 KB, ends < 1 MB
  // phase A transients
  u16*   xz   = (u16*)  (ws + 1 * MB);    // 1-17
  u16*   u    = (u16*)  (ws + 17 * MB);   // 17-25
  float* proj = (float*)(ws + 25 * MB);   // 25-26
  float* delta= (float*)(ws + 26 * MB);   // 26-42
  float* Pp   = (float*)(ws + 42 * MB);   // 42-48
  u16*   projb= (u16*)  (ws + 48 * MB);   // 48-48.5
  u16*   G    = (u16*)  (ws + 42 * MB);   // 42-50
  float* Ssc  = (float*)(ws + 50 * MB);   // 50-58
  float* Hin  = (float*)(ws + 58 * MB);   // 58-66
  float* sdl  = (float*)(ws + 66 * MB);   // 66-66.5
  float* Pm   = (float*)(ws + 50 * MB);   // 50-66 mout split-K partials
  u16*   h1b  = (u16*)  (ws + 26 * MB);   // 26-30
  float* h1f  = (float*)(ws + 30 * MB);   // 30-38
  // phase B transients
  u16*   qb   = (u16*)  (ws + 1 * MB);    // 1-5
  u16*   kb   = (u16*)  (ws + 5 * MB);    // 5-9
  u16*   vb   = (u16*)  (ws + 9 * MB);    // 9-13
  u16*   vtb  = (u16*)  (ws + 38 * MB);   // 38-42
  u16*   Opart= (u16*)  (ws + 42 * MB);   // 42-50
  float* Lpart= (float*)(ws + 66 * MB);   // 66-66.25
  u16*   ao   = (u16*)  (ws + 13 * MB);   // 13-17
  float* aof  = (float*)(ws + 17 * MB);   // 17-25
  float* h2f  = (float*)(ws + 58 * MB);   // 58-66
  // phase C transients
  u16*   q1   = (u16*)  (ws + 1 * MB);    // 1-5
  u16*   t1   = (u16*)  (ws + 5 * MB);    // 5-13
  u16*   t2   = (u16*)  (ws + 50 * MB);   // 50-58
  u16*   gh   = (u16*)  (ws + 13 * MB);   // 13-29
  u16*   q2   = (u16*)  (ws + 29 * MB);   // 29-45
  float* Pf2  = (float*)(ws + 98 * MB);   // 98-114 FFN2 split-K partials
  // persistent bf16 copies (68-97)
  u16* xb       = (u16*)(ws + 68 * MB);
  u16* encb     = (u16*)(ws + 72 * MB);
  u16* in_wb    = (u16*)(ws + 76 * MB);
  u16* out_wb   = (u16*)(ws + 84 * MB);
  u16* q_wb     = (u16*)(ws + 88 * MB);
  u16* k_wb     = (u16*)(ws + 90 * MB);   // k|v contiguous -> fused [2048][1024]
  u16* v_wb     = (u16*)(ws + 92 * MB);
  u16* o_wb     = (u16*)(ws + 94 * MB);
  u16* xproj_wb = (u16*)(ws + 96 * MB);
  u16* dt_wb    = (u16*)(ws + 96 * MB + 512 * KB);
  u16* dt_bb    = (u16*)(ws + 96 * MB + 768 * KB);
  u16* q_bb     = (u16*)(ws + 96 * MB + 776 * KB);
  u16* k_bb     = (u16*)(ws + 96 * MB + 778 * KB);  // k|v biases contiguous
  u16* v_bb     = (u16*)(ws + 96 * MB + 780 * KB);
  u16* o_bb     = (u16*)(ws + 96 * MB + 788 * KB);
  u16* b1b      = (u16*)(ws + 96 * MB + 792 * KB);
  u16* b2b      = (u16*)(ws + 96 * MB + 808 * KB);

  dim3 blk(256);
  detect_kernel<<<dim3(1), blk, 0, stream>>>(x, Fg);

  // 0b. convert all GEMM-facing externals to bf16
  {
    CvtJobs jobs;
    const void* srcs[NCVT] = { x, enc, in_w, out_w, q_w, k_w, v_w, o_w, xproj_w, dt_w,
                               dt_b, q_b, k_b, v_b, o_b, b1, b2 };
    u16* dsts[NCVT] = { xb, encb, in_wb, out_wb, q_wb, k_wb, v_wb, o_wb, xproj_wb, dt_wb,
                        dt_bb, q_bb, k_bb, v_bb, o_bb, b1b, b2b };
    int ns[NCVT] = { 2097152, 2097152, 4194304, 2097152, 1048576, 1048576, 1048576, 1048576,
                     196608, 131072, 2048, 1024, 1024, 1024, 1024, 4096, 1024 };
    int bo = 0;
    for (int j = 0; j < NCVT; j++){
      jobs.src[j] = srcs[j]; jobs.dst[j] = dsts[j]; jobs.n[j] = ns[j];
      jobs.blk_off[j] = bo;
      bo += (ns[j] / 8 + 255) / 256;
    }
    jobs.blk_off[NCVT] = bo;
    convert_kernel<<<dim3(bo), blk, 0, stream>>>(jobs, Fg);
  }

  // 1. xz = x @ in_w^T  (128x128)
  gemm16<0,4,4,2,2,false><<<dim3(32, 16), blk, 0, stream>>>(xb, in_wb, xz, 2048, 4096, 1024, 1024, 1024, 4096, nullptr, nullptr, nullptr, nullptr, nullptr);
  // 2. conv + SiLU
  conv_silu_kernel<<<dim3(16384), blk, 0, stream>>>(xz, conv_w, conv_b, u, Fg);
  // 3. proj = u @ xproj_w^T (split-K=8) + reduce
  gemm16<3,2,3,2,2,false><<<dim3(1, 32, 8), blk, 0, stream>>>(u, xproj_wb, Pp, 2048, 96, 256, 2048, 2048, 96, nullptr, nullptr, nullptr, nullptr, nullptr);
  xproj_reduce_kernel<<<dim3(768), blk, 0, stream>>>(Pp, proj, projb);
  // 4. delta = softplus(projb @ dt_w^T + dt_b)
  gemm16<6,2,2,2,2,false><<<dim3(32, 32), blk, 0, stream>>>(projb, dt_wb, delta, 2048, 2048, 64, 64, 64, 2048, dt_bb, nullptr, nullptr, nullptr, nullptr);
  // 5. chunked scan
  scan_part1<<<dim3(8, SNCH, 2), blk, 0, stream>>>(delta, u, proj, A_log, Ssc, sdl, Fg);
  scan_combine<<<dim3(16), blk, 0, stream>>>(Ssc, sdl, A_log, Hin, Fg);
  scan_part2<<<dim3(8, SNCH, 2), blk, 0, stream>>>(delta, u, proj, A_log, Dp, xz, Hin, G, Fg);
  // 6. mamba_out = G @ out_w^T  (split-K=2 -> 1024 blocks)
  gemm16<3,2,2,2,2,false><<<dim3(16, 32, 2), blk, 0, stream>>>(G, out_wb, Pm, 2048, 1024, 1024, 2048, 2048, 1024, nullptr, nullptr, nullptr, nullptr, nullptr);
  // 7. h1 = rmsnorm(x + P0 + P1)  (split-K combine fused)
  rmsnorm_fused<1><<<dim3(2048), blk, 0, stream>>>(x, 1, Pm, n1w, h1b, h1f, nullptr, Fg, nullptr, nullptr, nullptr, nullptr, nullptr);
  // 8. q projection + fused k|v projection (N=2048, SPLITC)
  gemm16<1,2,2,2,2,false><<<dim3(16, 32), blk, 0, stream>>>(h1b, q_wb, qb, 2048, 1024, 1024, 1024, 1024, 1024, q_bb, nullptr, nullptr, nullptr, nullptr);
  gemm16<1,2,2,2,2,true><<<dim3(32, 32), blk, 0, stream>>>(encb, k_wb, kb, 2048, 2048, 1024, 1024, 1024, 1024, k_bb, nullptr, nullptr, vb, nullptr);
  // 8b. V transpose
  vtrans_kernel<<<dim3(16, 32), blk, 0, stream>>>(vb, vtb);
  // 9. multi-wave LDS-staged flash attention + combine
  attn_mw_kernel<<<dim3(16, 32, ASPL), blk, 0, stream>>>(qb, kb, vtb, Opart, Lpart);
  attn_combine_kernel<<<dim3(2048), blk, 0, stream>>>(Opart, Lpart, ao);
  // 10. o projection
  gemm16<2,2,2,2,2,false><<<dim3(16, 32), blk, 0, stream>>>(ao, o_wb, aof, 2048, 1024, 1024, 1024, 1024, 1024, o_bb, nullptr, nullptr, nullptr, nullptr);
  // 11+12. h2 = rmsnorm(h1 + attn), act_quant fused -> q1,s1
  rmsnorm_fused<0><<<dim3(2048), blk, 0, stream>>>(h1f, 0, aof, n2w, nullptr, h2f, nullptr, Fg, q1, s1, nullptr, nullptr, nullptr);
  // 13. weight_quant(w1,w2): fused two-weight pipeline
  absmean_partial2_kernel<<<dim3(8192), blk, 0, stream>>>(w1, w2, part, Fg);
  absmean_final2_kernel<<<dim3(2), blk, 0, stream>>>(part, sw1, sw2);
  ternarize2_kernel<<<dim3(8192), blk, 0, stream>>>(w1, w2, sw1, sw2, t1, t2, Fg);
  // 14. ffn hidden = gelu(q1 @ t1^T * s1*sw1 + b1) -> bf16  (128x128)
  gemm16<4,4,4,2,2,false><<<dim3(32, 16), blk, 0, stream>>>(q1, t1, gh, 2048, 4096, 1024, 1024, 1024, 4096, b1b, s1, sw1, nullptr, nullptr);
  // 15. act_quant(gh)
  actquant_kernel<<<dim3(2048), blk, 0, stream>>>(gh, 0, q2, s2, 4096);
  // 16. ffn out partials (split-K=2 -> 1024 blocks)
  gemm16<3,2,2,2,2,false><<<dim3(16, 32, 2), blk, 0, stream>>>(q2, t2, Pf2, 2048, 1024, 2048, 4096, 4096, 1024, nullptr, nullptr, nullptr, nullptr, nullptr);
  // 17. out = rmsnorm(h2 + (P0+P1)*s2*sw2 + b2) -> d_out  (combine fused)
  rmsnorm_fused<2><<<dim3(2048), blk, 0, stream>>>(h2f, 0, Pf2, n3w, nullptr, nullptr, d_out, Fg, nullptr, nullptr, s2, sw2, b2b);
}